// Round 1
// baseline (763.612 us; speedup 1.0000x reference)
//
#include <hip/hip_runtime.h>
#include <hip/hip_bf16.h>
#include <math.h>

// GQA forward, round 6:
//  - flash: 512-thread blocks (8 waves = 2 qg x 4 k-quarters) -> 100% occupancy
//    cap (was 50%); exp2-domain softmax (log2e folded into Q scale in
//    norm_rope); defer-max rescale skip (THR=11 in log2 units); max3 trees;
//    s_setprio around MFMA. Merge = 2-round LDS tree over 4 partials.
//  - gemm: staging via __builtin_amdgcn_global_load_lds width=16 (m97
//    structure), linear LDS [128][32], 2 barriers/K-step.

#define N_SEQ 2048
#define EMB   1024
#define NH    16
#define NKV   4
#define HD    64
#define BATCH 2
#define M_TOT 4096
#define QKV_N 1536

typedef __attribute__((ext_vector_type(8)))  short short8;   // 8 bf16
typedef __attribute__((ext_vector_type(4)))  float f32x4;
typedef __attribute__((ext_vector_type(16))) float f32x16;

__device__ __forceinline__ ushort f2bf(float f) {
    union { __hip_bfloat16 h; ushort u; } cv;
    cv.h = __float2bfloat16(f);
    return cv.u;
}
__device__ __forceinline__ float bf2f(ushort u) {
    union { __hip_bfloat16 h; ushort u; } cv;
    cv.u = u;
    return __bfloat162float(cv.h);
}
__device__ __forceinline__ uint pack2bf(float a, float b) {
    union { __hip_bfloat162 h; uint u; } cv;
    cv.h = __float22bfloat162_rn(float2{a, b});   // a -> low 16, b -> high 16
    return cv.u;
}

// async global->LDS, 16B per lane. lds base must be wave-uniform; HW writes
// ldsbase + lane*16; global address is per-lane.
__device__ __forceinline__ void g2lds16(const ushort* g, ushort* l) {
    __builtin_amdgcn_global_load_lds(
        (const __attribute__((address_space(1))) unsigned int*)g,
        (__attribute__((address_space(3))) unsigned int*)l, 16, 0, 0);
}

// ---------------------------------------------------------------------------
// Fused prep (unchanged)
// ---------------------------------------------------------------------------
__device__ __forceinline__ void cvt4(const float* __restrict__ s,
                                     ushort* __restrict__ d, long g, long gd) {
    const float4 v = ((const float4*)s)[g];
    ushort4 o;
    o.x = f2bf(v.x); o.y = f2bf(v.y); o.z = f2bf(v.z); o.w = f2bf(v.w);
    ((ushort4*)d)[gd] = o;
}

__global__ __launch_bounds__(256) void prep_kernel(
    const float* __restrict__ x,  const float* __restrict__ wq,
    const float* __restrict__ wk, const float* __restrict__ wv,
    const float* __restrict__ wp, const float* __restrict__ bq,
    const float* __restrict__ bk, const float* __restrict__ bv,
    ushort* __restrict__ xb, ushort* __restrict__ Wqkv,
    ushort* __restrict__ Wproj, float* __restrict__ bqkv)
{
    const long i = (long)blockIdx.x * 256 + threadIdx.x;
    if (i < 1048576) {
        cvt4(x, xb, i, i);
    } else if (i < 1310720) {
        const long g = i - 1048576;
        cvt4(wq, Wqkv, g, g);
    } else if (i < 1376256) {
        const long g = i - 1310720;
        cvt4(wk, Wqkv, g, 262144 + g);
    } else if (i < 1441792) {
        const long g = i - 1376256;
        cvt4(wv, Wqkv, g, 327680 + g);
    } else if (i < 1703936) {
        const long g = i - 1441792;
        cvt4(wp, Wproj, g, g);
    } else if (i < 1704320) {
        const long j = i - 1703936;
        float4 v;
        if (j < 256)      v = ((const float4*)bq)[j];
        else if (j < 320) v = ((const float4*)bk)[j - 256];
        else              v = ((const float4*)bv)[j - 320];
        ((float4*)bqkv)[j] = v;
    }
}

// ---------------------------------------------------------------------------
// bf16 MFMA GEMM, global_load_lds staging (m97 structure).
// C[m][n] = sum_k A[m][k] W[n][k] + b[n]
// ---------------------------------------------------------------------------
template <bool BF16OUT>
__global__ __launch_bounds__(256) void gemm_mfma_kernel(
    const ushort* __restrict__ A, const ushort* __restrict__ W,
    const float* __restrict__ bias, void* __restrict__ Cout,
    int K, int ldc)
{
    __shared__ ushort As[128 * 32];   // linear [row][32], row stride 64B
    __shared__ ushort Bs[128 * 32];

    const int tid = threadIdx.x;
    const int m0 = blockIdx.y * 128, n0 = blockIdx.x * 128;
    const int w = tid >> 6, lane = tid & 63;
    const int quad = lane >> 4, l16 = lane & 15;
    const int wm = (w & 1) * 64, wn = (w >> 1) * 64;

    f32x4 acc[4][4] = {};

    float bb[4];
#pragma unroll
    for (int j = 0; j < 4; ++j) bb[j] = bias[n0 + wn + j * 16 + l16];

    // staging map: lane covers global row r0 = tid>>2 (+64 for 2nd inst),
    // 16B chunk (tid&3). LDS offset (shorts) = tid*8 + inst*2048
    //   = wave-uniform (w*512 + inst*2048) + lane*8.
    const int r0 = tid >> 2;
    const int c8 = (tid & 3) * 8;
    const ushort* Ap = A + (size_t)(m0 + r0) * K + c8;
    const ushort* Wp = W + (size_t)(n0 + r0) * K + c8;
    ushort* AsW = As + w * 512;
    ushort* BsW = Bs + w * 512;

    for (int k0 = 0; k0 < K; k0 += 32) {
        __syncthreads();                       // prev tile's ds_reads done
        g2lds16(Ap + k0, AsW);
        g2lds16(Ap + (size_t)64 * K + k0, AsW + 2048);
        g2lds16(Wp + k0, BsW);
        g2lds16(Wp + (size_t)64 * K + k0, BsW + 2048);
        __syncthreads();                       // vmcnt(0) drain -> LDS visible

        short8 aF[4], bF[4];
#pragma unroll
        for (int i = 0; i < 4; ++i)
            aF[i] = *(const short8*)&As[(wm + i * 16 + l16) * 32 + quad * 8];
#pragma unroll
        for (int j = 0; j < 4; ++j)
            bF[j] = *(const short8*)&Bs[(wn + j * 16 + l16) * 32 + quad * 8];
        __builtin_amdgcn_s_setprio(1);
#pragma unroll
        for (int i = 0; i < 4; ++i)
#pragma unroll
            for (int j = 0; j < 4; ++j)
                acc[i][j] = __builtin_amdgcn_mfma_f32_16x16x32_bf16(
                    aF[i], bF[j], acc[i][j], 0, 0, 0);
        __builtin_amdgcn_s_setprio(0);
    }

#pragma unroll
    for (int i = 0; i < 4; ++i) {
        const int rowb = m0 + wm + i * 16 + quad * 4;
#pragma unroll
        for (int j = 0; j < 4; ++j) {
            const int col = n0 + wn + j * 16 + l16;
#pragma unroll
            for (int r = 0; r < 4; ++r) {
                const float vv = acc[i][j][r] + bb[j];
                if (BF16OUT)
                    ((ushort*)Cout)[(size_t)(rowb + r) * ldc + col] = f2bf(vv);
                else
                    ((float*)Cout)[(size_t)(rowb + r) * ldc + col] = vv;
            }
        }
    }
}

// ---------------------------------------------------------------------------
// Fused RMSNorm + RoPE. Q scale now folds log2(e) so flash softmax runs in
// exp2 domain (saves one v_mul per exp).
// ---------------------------------------------------------------------------
__global__ __launch_bounds__(256) void norm_rope_kernel(
    const ushort* __restrict__ Tq, const float* __restrict__ qn_w,
    const float* __restrict__ kn_w, const float* __restrict__ sinp,
    const float* __restrict__ cosp, ushort* __restrict__ Qb,
    ushort* __restrict__ Kf)
{
    const int gw = (int)(((long)blockIdx.x * 256 + threadIdx.x) >> 6);
    const int lane = threadIdx.x & 63;

    const bool isQ = (gw < 65536);
    const int vec = isQ ? gw : gw - 65536;
    const int hshift = isQ ? 4 : 2;
    const int colBase = isQ ? 0 : EMB;
    const float* nw = isQ ? qn_w : kn_w;
    const float outScale = isQ ? 0.125f * 1.44269504f : 1.0f;   // 1/sqrt(64)*log2(e)

    const int m = vec >> hshift;
    const int h = vec & ((1 << hshift) - 1);
    const int n = m & (N_SEQ - 1);
    const int b = m >> 11;

    const float t = bf2f(Tq[(size_t)m * QKV_N + colBase + h * HD + lane]);
    float s = t * t;
#pragma unroll
    for (int mask = 32; mask; mask >>= 1) s += __shfl_xor(s, mask, 64);
    const float r = rsqrtf(s * (1.0f / 64.0f) + 1e-6f);

    const float tn = t * r * nw[lane];
    const float partner = __shfl_xor(tn, 32, 64);
    const float rot = (lane < 32) ? -partner : partner;
    const float val = (tn * cosp[n * HD + lane] + rot * sinp[n * HD + lane]) * outScale;

    if (isQ) {
        Qb[((size_t)((b << 4) + h) * N_SEQ + n) * HD + lane] = f2bf(val);
    } else {
        const int kt = n >> 6, rr = n & 63, ss = rr >> 5, l32k = rr & 31;
        const int c = lane >> 4, l5k = (lane >> 3) & 1, j = lane & 7;
        Kf[((size_t)(b * NKV + h) * 32 + kt) * 4096
           + (ss * 4 + c) * 512 + l32k * 16 + l5k * 8 + j] = f2bf(val);
    }
}

// ---------------------------------------------------------------------------
// V -> fragment-order Vf (unchanged)
// ---------------------------------------------------------------------------
__global__ __launch_bounds__(256) void transpose_v_kernel(
    const ushort* __restrict__ Tq, ushort* __restrict__ Vf)
{
    __shared__ ushort L[64 * 72];
    const int kt = blockIdx.x;
    const int n0 = kt * 64;
    const int bkv = blockIdx.y;
    const int b = bkv >> 2, kv = bkv & 3;
    const int tid = threadIdx.x;

#pragma unroll
    for (int it = 0; it < 2; ++it) {
        const int j = tid + it * 256;
        const int r = j >> 3, c = j & 7;
        const short8 v = *(const short8*)&Tq[(size_t)(b * N_SEQ + n0 + r) * QKV_N
                                             + 1280 + kv * HD + c * 8];
        *(short8*)&L[r * 72 + c * 8] = v;
    }
    __syncthreads();
#pragma unroll
    for (int it = 0; it < 2; ++it) {
        const int j = tid + it * 256;
        const int d = j >> 3, c8 = j & 7;
        short8 o;
#pragma unroll
        for (int e = 0; e < 8; ++e) o[e] = (short)L[(c8 * 8 + e) * 72 + d];
        const int ss = c8 >> 2, tt = (c8 >> 1) & 1, l5v = c8 & 1;
        const int d2 = d >> 5, l32v = d & 31;
        *(short8*)&Vf[((size_t)bkv * 32 + kt) * 4096
                      + ((ss * 2 + tt) * 2 + d2) * 512 + l32v * 16 + l5v * 8] = o;
    }
}

// ---------------------------------------------------------------------------
// Barrier-free flash, 8 waves = 2 q-groups x 4 k-quarters (8 k-tiles each).
// Grid (32,32) x 512 thr = 8192 waves = 100% occupancy cap (VGPR<=64 via
// __launch_bounds__(512,8)). exp2-domain softmax; defer-max rescale skip.
// End: 2-round LDS tree merge of the 4 k-partials per q-group.
// ---------------------------------------------------------------------------
__global__ __launch_bounds__(512, 8) void flash_mfma32_kernel(
    const ushort* __restrict__ Qb, const ushort* __restrict__ Kf,
    const ushort* __restrict__ Vf, ushort* __restrict__ Ob)
{
    __shared__ float fsm[8704];            // 2 bufs x 2 qg x 2176 = 34.8 KB

    const int qt = blockIdx.x;
    const int bh = blockIdx.y;
    const int b = bh >> 4, h = bh & 15;
    const int kvh = h >> 2;
    const int tid = threadIdx.x;
    const int w = tid >> 6, lane = tid & 63;
    const int l32 = lane & 31, l5 = lane >> 5;
    const int qg = w & 1;                  // q-group (32 rows)
    const int kh = w >> 1;                 // k-quarter 0..3

    const ushort* Qg = Qb + ((size_t)bh * N_SEQ + qt * 64 + qg * 32) * HD;
    const size_t kvbase = (size_t)(b * NKV + kvh) * (32 * 4096);
    const ushort* Kp = Kf + kvbase;
    const ushort* Vp = Vf + kvbase;
    const int loff = l32 * 16 + l5 * 8;

    short8 qF[4];
#pragma unroll
    for (int c = 0; c < 4; ++c)
        qF[c] = *(const short8*)&Qg[(size_t)l32 * HD + c * 16 + l5 * 8];

    f32x16 Oa[2] = {};                     // O^T d-tiles (d 0-31, 32-63)
    float mrow = -3.0e38f, lrow = 0.0f;

    for (int i = 0; i < 8; ++i) {
        const int kt = kh * 8 + i;
        const ushort* Kt = Kp + kt * 4096;
        const ushort* Vt = Vp + kt * 4096;

        short8 kT[2][4];
#pragma unroll
        for (int s = 0; s < 2; ++s)
#pragma unroll
            for (int c = 0; c < 4; ++c)
                kT[s][c] = *(const short8*)&Kt[(s * 4 + c) * 512 + loff];
        short8 vT[2][2][2];
#pragma unroll
        for (int s = 0; s < 2; ++s)
#pragma unroll
            for (int t = 0; t < 2; ++t)
#pragma unroll
                for (int d2 = 0; d2 < 2; ++d2)
                    vT[s][t][d2] = *(const short8*)&Vt[((s * 2 + t) * 2 + d2) * 512 + loff];

        f32x16 Sv[2] = {};
        __builtin_amdgcn_s_setprio(1);
#pragma unroll
        for (int s = 0; s < 2; ++s)
#pragma unroll
            for (int c = 0; c < 4; ++c)
                Sv[s] = __builtin_amdgcn_mfma_f32_32x32x16_bf16(kT[s][c], qF[c], Sv[s], 0, 0, 0);
        __builtin_amdgcn_s_setprio(0);

        // row max via max3 trees (+1 partner shuffle across l5 halves)
        float mx = fmaxf(Sv[0][0], Sv[0][1]);
#pragma unroll
        for (int r = 2; r < 16; r += 2) mx = fmaxf(mx, fmaxf(Sv[0][r], Sv[0][r + 1]));
#pragma unroll
        for (int r = 0; r < 16; r += 2) mx = fmaxf(mx, fmaxf(Sv[1][r], Sv[1][r + 1]));
        mx = fmaxf(mx, __shfl_xor(mx, 32, 64));

        // defer-max: skip O/l rescale while growth <= 2^11 (log2 domain)
        if (!__all(mx <= mrow + 11.0f)) {
            const float mnew = fmaxf(mrow, mx);
            const float alpha = exp2f(mrow - mnew);
            mrow = mnew;
            lrow *= alpha;
#pragma unroll
            for (int t = 0; t < 2; ++t)
#pragma unroll
                for (int r = 0; r < 16; ++r) Oa[t][r] *= alpha;
        }

        float rs = 0.0f;
#pragma unroll
        for (int s = 0; s < 2; ++s)
#pragma unroll
            for (int r = 0; r < 16; ++r) {
                Sv[s][r] = exp2f(Sv[s][r] - mrow);
                rs += Sv[s][r];
            }
        rs += __shfl_xor(rs, 32, 64);
        lrow += rs;

        // pack P pairs: P2[s][2g+hh] = keys 8g+4*l5+2hh+{0,1} of subtile s
        uint P2[2][8];
#pragma unroll
        for (int s = 0; s < 2; ++s)
#pragma unroll
            for (int g = 0; g < 4; ++g)
#pragma unroll
                for (int hh = 0; hh < 2; ++hh)
                    P2[s][g * 2 + hh] =
                        pack2bf(Sv[s][4 * g + 2 * hh], Sv[s][4 * g + 2 * hh + 1]);

        // P^T B-frags in-register + PV mfma
        __builtin_amdgcn_s_setprio(1);
#pragma unroll
        for (int s = 0; s < 2; ++s)
#pragma unroll
            for (int t = 0; t < 2; ++t) {
                const uint snd0 = l5 ? P2[s][4 * t + 0] : P2[s][4 * t + 2];
                const uint snd1 = l5 ? P2[s][4 * t + 1] : P2[s][4 * t + 3];
                const uint kp0  = l5 ? P2[s][4 * t + 2] : P2[s][4 * t + 0];
                const uint kp1  = l5 ? P2[s][4 * t + 3] : P2[s][4 * t + 1];
                const uint rcv0 = __shfl_xor(snd0, 32, 64);
                const uint rcv1 = __shfl_xor(snd1, 32, 64);
                union { uint u[4]; short8 s8; } pb;
                pb.u[0] = l5 ? rcv0 : kp0;
                pb.u[1] = l5 ? rcv1 : kp1;
                pb.u[2] = l5 ? kp0 : rcv0;
                pb.u[3] = l5 ? kp1 : rcv1;
#pragma unroll
                for (int d2 = 0; d2 < 2; ++d2)
                    Oa[d2] = __builtin_amdgcn_mfma_f32_32x32x16_bf16(
                        vT[s][t][d2], pb.s8, Oa[d2], 0, 0, 0);
            }
        __builtin_amdgcn_s_setprio(0);
    }

    // ---- merge 4 k-partials per q-group (2-round tree) ----
    auto write_part = [&](float* buf) {
#pragma unroll
        for (int d2 = 0; d2 < 2; ++d2)
#pragma unroll
            for (int r = 0; r < 16; ++r)
                buf[(d2 * 16 + r) * 64 + lane] = Oa[d2][r];
        buf[2048 + lane] = mrow;
        buf[2112 + lane] = lrow;
    };
    auto merge_part = [&](const float* buf) {
        const float mb = buf[2048 + lane];
        const float lb = buf[2112 + lane];
        const float M = fmaxf(mrow, mb);
        const float ea = exp2f(mrow - M), eb = exp2f(mb - M);
        mrow = M;
        lrow = lrow * ea + lb * eb;
#pragma unroll
        for (int d2 = 0; d2 < 2; ++d2)
#pragma unroll
            for (int r = 0; r < 16; ++r)
                Oa[d2][r] = Oa[d2][r] * ea + buf[(d2 * 16 + r) * 64 + lane] * eb;
    };

    float* B0 = fsm + qg * 2176;
    float* B1 = fsm + 4352 + qg * 2176;

    if (kh == 1) write_part(B0);
    else if (kh == 3) write_part(B1);
    __syncthreads();
    if (kh == 0) merge_part(B0);
    else if (kh == 2) merge_part(B1);
    __syncthreads();
    if (kh == 2) write_part(B0);
    __syncthreads();
    if (kh == 0) merge_part(B0);
    __syncthreads();                        // merge reads done before Os reuse

    // ---- epilogue: normalize + transpose to row-major via LDS ----
    ushort* Os = (ushort*)fsm;              // [64][68]
    if (kh == 0) {
        const float inv = 1.0f / lrow;
#pragma unroll
        for (int d2 = 0; d2 < 2; ++d2)
#pragma unroll
            for (int r = 0; r < 16; ++r) {
                const int d = d2 * 32 + (r & 3) + 8 * (r >> 2) + 4 * l5;
                Os[(qg * 32 + l32) * 68 + d] = f2bf(Oa[d2][r] * inv);
            }
    }
    __syncthreads();

    const int row = tid >> 3, cc = (tid & 7) * 8;
    const short8 v = *(const short8*)&Os[row * 68 + cc];
    *(short8*)&Ob[((size_t)b * N_SEQ + qt * 64 + row) * EMB + h * HD + cc] = v;
}

// ---------------------------------------------------------------------------
extern "C" void kernel_launch(void* const* d_in, const int* in_sizes, int n_in,
                              void* d_out, int out_size, void* d_ws, size_t ws_size,
                              hipStream_t stream)
{
    const float* x      = (const float*)d_in[0];
    const float* sinp   = (const float*)d_in[1];
    const float* cosp   = (const float*)d_in[2];
    const float* wq_w   = (const float*)d_in[3];
    const float* wq_b   = (const float*)d_in[4];
    const float* wk_w   = (const float*)d_in[5];
    const float* wk_b   = (const float*)d_in[6];
    const float* wv_w   = (const float*)d_in[7];
    const float* wv_b   = (const float*)d_in[8];
    const float* qn_w   = (const float*)d_in[9];
    const float* kn_w   = (const float*)d_in[10];
    const float* proj_w = (const float*)d_in[11];
    const float* proj_b = (const float*)d_in[12];
    float* out = (float*)d_out;

    // workspace layout (ushort elements) — ~39 MB
    ushort* Tq    = (ushort*)d_ws;            // 4096*1536
    ushort* xb    = Tq + 6291456;             // 4096*1024 (reused as Ob)
    ushort* Wqkv  = xb + 4194304;             // 1536*1024
    ushort* Wproj = Wqkv + 1572864;           // 1024*1024
    float*  bqkv  = (float*)(Wproj + 1048576);// 1536
    ushort* Qb    = (ushort*)(bqkv + 1536);   // 2*16*2048*64
    ushort* Kf    = Qb + 4194304;             // frag-order K, 1048576
    ushort* Vf    = Kf + 1048576;             // frag-order V^T, 1048576

    prep_kernel<<<6658, 256, 0, stream>>>(x, wq_w, wk_w, wv_w, proj_w,
                                          wq_b, wk_b, wv_b,
                                          xb, Wqkv, Wproj, bqkv);

    gemm_mfma_kernel<true><<<dim3(QKV_N / 128, M_TOT / 128), 256, 0, stream>>>(
        xb, Wqkv, bqkv, Tq, EMB, QKV_N);

    norm_rope_kernel<<<20480, 256, 0, stream>>>(Tq, qn_w, kn_w, sinp, cosp, Qb, Kf);

    transpose_v_kernel<<<dim3(32, 8), 256, 0, stream>>>(Tq, Vf);

    flash_mfma32_kernel<<<dim3(32, 32), 512, 0, stream>>>(Qb, Kf, Vf, xb);

    gemm_mfma_kernel<false><<<dim3(EMB / 128, M_TOT / 128), 256, 0, stream>>>(
        xb, Wproj, proj_b, out, EMB, EMB);
}

// Round 2
// 271.919 us; speedup vs baseline: 2.8082x; 2.8082x over previous
//
#include <hip/hip_runtime.h>
#include <hip/hip_bf16.h>
#include <math.h>

// GQA forward, round 7: round-5 skeleton + VALU-diet flash.
//  - flash: 256-thread blocks (4 waves = 2 qg x 2 k-halves), launch_bounds
//    (256,4) — per-wave state ~124 regs makes 4 waves/SIMD the hard cap
//    (round-6's (512,8) spilled: VGPR 32, FETCH 994MB, 595us).
//  - exp2-domain softmax (log2e folded into Q scale in norm_rope), defer-max
//    rescale skip (THR=11 log2), paired-fmax max tree, setprio around MFMA.
//  - gemm: round-5 proven reg->LDS staging (stride-40); gload_lds rewrite was
//    neutral at these tail-bound grids.

#define N_SEQ 2048
#define EMB   1024
#define NH    16
#define NKV   4
#define HD    64
#define BATCH 2
#define M_TOT 4096
#define QKV_N 1536

typedef __attribute__((ext_vector_type(8)))  short short8;   // 8 bf16
typedef __attribute__((ext_vector_type(4)))  float f32x4;
typedef __attribute__((ext_vector_type(16))) float f32x16;

__device__ __forceinline__ ushort f2bf(float f) {
    union { __hip_bfloat16 h; ushort u; } cv;
    cv.h = __float2bfloat16(f);
    return cv.u;
}
__device__ __forceinline__ float bf2f(ushort u) {
    union { __hip_bfloat16 h; ushort u; } cv;
    cv.u = u;
    return __bfloat162float(cv.h);
}
__device__ __forceinline__ uint pack2bf(float a, float b) {
    union { __hip_bfloat162 h; uint u; } cv;
    cv.h = __float22bfloat162_rn(float2{a, b});   // a -> low 16, b -> high 16
    return cv.u;
}

// ---------------------------------------------------------------------------
// Fused prep
// ---------------------------------------------------------------------------
__device__ __forceinline__ void cvt4(const float* __restrict__ s,
                                     ushort* __restrict__ d, long g, long gd) {
    const float4 v = ((const float4*)s)[g];
    ushort4 o;
    o.x = f2bf(v.x); o.y = f2bf(v.y); o.z = f2bf(v.z); o.w = f2bf(v.w);
    ((ushort4*)d)[gd] = o;
}

__global__ __launch_bounds__(256) void prep_kernel(
    const float* __restrict__ x,  const float* __restrict__ wq,
    const float* __restrict__ wk, const float* __restrict__ wv,
    const float* __restrict__ wp, const float* __restrict__ bq,
    const float* __restrict__ bk, const float* __restrict__ bv,
    ushort* __restrict__ xb, ushort* __restrict__ Wqkv,
    ushort* __restrict__ Wproj, float* __restrict__ bqkv)
{
    const long i = (long)blockIdx.x * 256 + threadIdx.x;
    if (i < 1048576) {
        cvt4(x, xb, i, i);
    } else if (i < 1310720) {
        const long g = i - 1048576;
        cvt4(wq, Wqkv, g, g);
    } else if (i < 1376256) {
        const long g = i - 1310720;
        cvt4(wk, Wqkv, g, 262144 + g);
    } else if (i < 1441792) {
        const long g = i - 1376256;
        cvt4(wv, Wqkv, g, 327680 + g);
    } else if (i < 1703936) {
        const long g = i - 1441792;
        cvt4(wp, Wproj, g, g);
    } else if (i < 1704320) {
        const long j = i - 1703936;
        float4 v;
        if (j < 256)      v = ((const float4*)bq)[j];
        else if (j < 320) v = ((const float4*)bk)[j - 256];
        else              v = ((const float4*)bv)[j - 320];
        ((float4*)bqkv)[j] = v;
    }
}

// ---------------------------------------------------------------------------
// bf16 MFMA GEMM (round-5 proven): C[m][n]=sum_k A[m][k]W[n][k]+b[n]
// ---------------------------------------------------------------------------
template <bool BF16OUT>
__global__ __launch_bounds__(256) void gemm_mfma_kernel(
    const ushort* __restrict__ A, const ushort* __restrict__ W,
    const float* __restrict__ bias, void* __restrict__ Cout,
    int K, int ldc)
{
    __shared__ ushort As[128 * 40];
    __shared__ ushort Bs[128 * 40];

    const int tid = threadIdx.x;
    const int m0 = blockIdx.y * 128, n0 = blockIdx.x * 128;
    const int w = tid >> 6, lane = tid & 63;
    const int quad = lane >> 4, l16 = lane & 15;
    const int wm = (w & 1) * 64, wn = (w >> 1) * 64;

    f32x4 acc[4][4] = {};

    float bb[4];
#pragma unroll
    for (int j = 0; j < 4; ++j) bb[j] = bias[n0 + wn + j * 16 + l16];

    const int r0 = tid >> 2;
    const int c0 = tid & 3;
    const ushort* Ap = A + (size_t)(m0 + r0) * K + c0 * 8;
    const ushort* Wp = W + (size_t)(n0 + r0) * K + c0 * 8;

    for (int k0 = 0; k0 < K; k0 += 32) {
        const short8 a0 = *(const short8*)(Ap + k0);
        const short8 a1 = *(const short8*)(Ap + (size_t)64 * K + k0);
        const short8 b0 = *(const short8*)(Wp + k0);
        const short8 b1 = *(const short8*)(Wp + (size_t)64 * K + k0);
        __syncthreads();
        *(short8*)&As[r0 * 40 + c0 * 8] = a0;
        *(short8*)&As[(r0 + 64) * 40 + c0 * 8] = a1;
        *(short8*)&Bs[r0 * 40 + c0 * 8] = b0;
        *(short8*)&Bs[(r0 + 64) * 40 + c0 * 8] = b1;
        __syncthreads();

        short8 aF[4], bF[4];
#pragma unroll
        for (int i = 0; i < 4; ++i)
            aF[i] = *(const short8*)&As[(wm + i * 16 + l16) * 40 + quad * 8];
#pragma unroll
        for (int j = 0; j < 4; ++j)
            bF[j] = *(const short8*)&Bs[(wn + j * 16 + l16) * 40 + quad * 8];
        __builtin_amdgcn_s_setprio(1);
#pragma unroll
        for (int i = 0; i < 4; ++i)
#pragma unroll
            for (int j = 0; j < 4; ++j)
                acc[i][j] = __builtin_amdgcn_mfma_f32_16x16x32_bf16(
                    aF[i], bF[j], acc[i][j], 0, 0, 0);
        __builtin_amdgcn_s_setprio(0);
    }

#pragma unroll
    for (int i = 0; i < 4; ++i) {
        const int rowb = m0 + wm + i * 16 + quad * 4;
#pragma unroll
        for (int j = 0; j < 4; ++j) {
            const int col = n0 + wn + j * 16 + l16;
#pragma unroll
            for (int r = 0; r < 4; ++r) {
                const float vv = acc[i][j][r] + bb[j];
                if (BF16OUT)
                    ((ushort*)Cout)[(size_t)(rowb + r) * ldc + col] = f2bf(vv);
                else
                    ((float*)Cout)[(size_t)(rowb + r) * ldc + col] = vv;
            }
        }
    }
}

// ---------------------------------------------------------------------------
// Fused RMSNorm + RoPE. Q scale folds log2(e): flash softmax runs in exp2
// domain. K -> fragment-order Kf (as round 5).
// ---------------------------------------------------------------------------
__global__ __launch_bounds__(256) void norm_rope_kernel(
    const ushort* __restrict__ Tq, const float* __restrict__ qn_w,
    const float* __restrict__ kn_w, const float* __restrict__ sinp,
    const float* __restrict__ cosp, ushort* __restrict__ Qb,
    ushort* __restrict__ Kf)
{
    const int gw = (int)(((long)blockIdx.x * 256 + threadIdx.x) >> 6);
    const int lane = threadIdx.x & 63;

    const bool isQ = (gw < 65536);
    const int vec = isQ ? gw : gw - 65536;
    const int hshift = isQ ? 4 : 2;
    const int colBase = isQ ? 0 : EMB;
    const float* nw = isQ ? qn_w : kn_w;
    const float outScale = isQ ? 0.125f * 1.44269504f : 1.0f;  // 1/sqrt(64)*log2e

    const int m = vec >> hshift;
    const int h = vec & ((1 << hshift) - 1);
    const int n = m & (N_SEQ - 1);
    const int b = m >> 11;

    const float t = bf2f(Tq[(size_t)m * QKV_N + colBase + h * HD + lane]);
    float s = t * t;
#pragma unroll
    for (int mask = 32; mask; mask >>= 1) s += __shfl_xor(s, mask, 64);
    const float r = rsqrtf(s * (1.0f / 64.0f) + 1e-6f);

    const float tn = t * r * nw[lane];
    const float partner = __shfl_xor(tn, 32, 64);
    const float rot = (lane < 32) ? -partner : partner;
    const float val = (tn * cosp[n * HD + lane] + rot * sinp[n * HD + lane]) * outScale;

    if (isQ) {
        Qb[((size_t)((b << 4) + h) * N_SEQ + n) * HD + lane] = f2bf(val);
    } else {
        const int kt = n >> 6, rr = n & 63, ss = rr >> 5, l32k = rr & 31;
        const int c = lane >> 4, l5k = (lane >> 3) & 1, j = lane & 7;
        Kf[((size_t)(b * NKV + h) * 32 + kt) * 4096
           + (ss * 4 + c) * 512 + l32k * 16 + l5k * 8 + j] = f2bf(val);
    }
}

// ---------------------------------------------------------------------------
// V -> fragment-order Vf (unchanged)
// ---------------------------------------------------------------------------
__global__ __launch_bounds__(256) void transpose_v_kernel(
    const ushort* __restrict__ Tq, ushort* __restrict__ Vf)
{
    __shared__ ushort L[64 * 72];
    const int kt = blockIdx.x;             // 0..31 (64 keys each)
    const int n0 = kt * 64;
    const int bkv = blockIdx.y;
    const int b = bkv >> 2, kv = bkv & 3;
    const int tid = threadIdx.x;

#pragma unroll
    for (int it = 0; it < 2; ++it) {
        const int j = tid + it * 256;
        const int r = j >> 3, c = j & 7;
        const short8 v = *(const short8*)&Tq[(size_t)(b * N_SEQ + n0 + r) * QKV_N
                                             + 1280 + kv * HD + c * 8];
        *(short8*)&L[r * 72 + c * 8] = v;
    }
    __syncthreads();
#pragma unroll
    for (int it = 0; it < 2; ++it) {
        const int j = tid + it * 256;
        const int d = j >> 3, c8 = j & 7;
        short8 o;
#pragma unroll
        for (int e = 0; e < 8; ++e) o[e] = (short)L[(c8 * 8 + e) * 72 + d];
        const int ss = c8 >> 2, tt = (c8 >> 1) & 1, l5v = c8 & 1;
        const int d2 = d >> 5, l32v = d & 31;
        *(short8*)&Vf[((size_t)bkv * 32 + kt) * 4096
                      + ((ss * 2 + tt) * 2 + d2) * 512 + l32v * 16 + l5v * 8] = o;
    }
}

// ---------------------------------------------------------------------------
// Barrier-free S^T-layout MFMA flash attention with in-block k-split x2.
// Grid (32 qt, 32 bh); block 256 = 4 waves: wave w = q-group (w&1, 32 rows)
// x k-half (w>>1, 16 k-tiles of 64 keys). exp2-domain softmax + defer-max.
// ---------------------------------------------------------------------------
__global__ __launch_bounds__(256, 4) void flash_mfma32_kernel(
    const ushort* __restrict__ Qb, const ushort* __restrict__ Kf,
    const ushort* __restrict__ Vf, ushort* __restrict__ Ob)
{
    __shared__ float fsm[4352];            // 2 x (2048 O + 64 m + 64 l) = 17.4KB

    const int qt = blockIdx.x;             // 0..31 (64 q-rows)
    const int bh = blockIdx.y;
    const int b = bh >> 4, h = bh & 15;
    const int kvh = h >> 2;
    const int tid = threadIdx.x;
    const int w = tid >> 6, lane = tid & 63;
    const int l32 = lane & 31, l5 = lane >> 5;
    const int qg = w & 1;                  // q-group within block
    const int kh = w >> 1;                 // k-half

    const ushort* Qg = Qb + ((size_t)bh * N_SEQ + qt * 64 + qg * 32) * HD;
    const size_t kvbase = (size_t)(b * NKV + kvh) * (32 * 4096);
    const ushort* Kp = Kf + kvbase;
    const ushort* Vp = Vf + kvbase;
    const int loff = l32 * 16 + l5 * 8;

    // Q^T B-frags: qF[c][j] = Q[q0+l32][c*16 + l5*8 + j]
    short8 qF[4];
#pragma unroll
    for (int c = 0; c < 4; ++c)
        qF[c] = *(const short8*)&Qg[(size_t)l32 * HD + c * 16 + l5 * 8];

    f32x16 Oa[2] = {};                     // O^T d-tiles (d 0-31, 32-63)
    float mrow = -3.0e38f, lrow = 0.0f;

    for (int i = 0; i < 16; ++i) {
        const int kt = kh * 16 + i;
        const ushort* Kt = Kp + kt * 4096;
        const ushort* Vt = Vp + kt * 4096;

        // direct global->reg fragment loads (coalesced, L2-hit)
        short8 kT[2][4];
#pragma unroll
        for (int s = 0; s < 2; ++s)
#pragma unroll
            for (int c = 0; c < 4; ++c)
                kT[s][c] = *(const short8*)&Kt[(s * 4 + c) * 512 + loff];
        short8 vT[2][2][2];
#pragma unroll
        for (int s = 0; s < 2; ++s)
#pragma unroll
            for (int t = 0; t < 2; ++t)
#pragma unroll
                for (int d2 = 0; d2 < 2; ++d2)
                    vT[s][t][d2] = *(const short8*)&Vt[((s * 2 + t) * 2 + d2) * 512 + loff];

        // S^T (32 keys x 32 q-rows) per key-subtile s
        f32x16 Sv[2] = {};
        __builtin_amdgcn_s_setprio(1);
#pragma unroll
        for (int s = 0; s < 2; ++s)
#pragma unroll
            for (int c = 0; c < 4; ++c)
                Sv[s] = __builtin_amdgcn_mfma_f32_32x32x16_bf16(kT[s][c], qF[c], Sv[s], 0, 0, 0);
        __builtin_amdgcn_s_setprio(0);

        // row max: paired-fmax tree (fusable to v_max3) + 1 partner shuffle
        float mx = fmaxf(Sv[0][0], Sv[0][1]);
#pragma unroll
        for (int r = 2; r < 16; r += 2) mx = fmaxf(mx, fmaxf(Sv[0][r], Sv[0][r + 1]));
#pragma unroll
        for (int r = 0; r < 16; r += 2) mx = fmaxf(mx, fmaxf(Sv[1][r], Sv[1][r + 1]));
        mx = fmaxf(mx, __shfl_xor(mx, 32, 64));

        // defer-max (T13): skip O/l rescale while growth <= 2^11
        if (!__all(mx <= mrow + 11.0f)) {
            const float mnew = fmaxf(mrow, mx);
            const float alpha = exp2f(mrow - mnew);
            mrow = mnew;
            lrow *= alpha;
#pragma unroll
            for (int t = 0; t < 2; ++t)
#pragma unroll
                for (int r = 0; r < 16; ++r) Oa[t][r] *= alpha;
        }

        float rs = 0.0f;
#pragma unroll
        for (int s = 0; s < 2; ++s)
#pragma unroll
            for (int r = 0; r < 16; ++r) {
                Sv[s][r] = exp2f(Sv[s][r] - mrow);
                rs += Sv[s][r];
            }
        rs += __shfl_xor(rs, 32, 64);
        lrow += rs;

        // pack P pairs: P2[s][2g+hh] = keys 8g+4*l5+2hh+{0,1} of subtile s
        uint P2[2][8];
#pragma unroll
        for (int s = 0; s < 2; ++s)
#pragma unroll
            for (int g = 0; g < 4; ++g)
#pragma unroll
                for (int hh = 0; hh < 2; ++hh)
                    P2[s][g * 2 + hh] =
                        pack2bf(Sv[s][4 * g + 2 * hh], Sv[s][4 * g + 2 * hh + 1]);

        // P^T B-frags in-register + PV mfma
        __builtin_amdgcn_s_setprio(1);
#pragma unroll
        for (int s = 0; s < 2; ++s)
#pragma unroll
            for (int t = 0; t < 2; ++t) {
                const uint snd0 = l5 ? P2[s][4 * t + 0] : P2[s][4 * t + 2];
                const uint snd1 = l5 ? P2[s][4 * t + 1] : P2[s][4 * t + 3];
                const uint kp0  = l5 ? P2[s][4 * t + 2] : P2[s][4 * t + 0];
                const uint kp1  = l5 ? P2[s][4 * t + 3] : P2[s][4 * t + 1];
                const uint rcv0 = __shfl_xor(snd0, 32, 64);
                const uint rcv1 = __shfl_xor(snd1, 32, 64);
                union { uint u[4]; short8 s8; } pb;
                pb.u[0] = l5 ? rcv0 : kp0;
                pb.u[1] = l5 ? rcv1 : kp1;
                pb.u[2] = l5 ? kp0 : rcv0;
                pb.u[3] = l5 ? kp1 : rcv1;
#pragma unroll
                for (int d2 = 0; d2 < 2; ++d2)
                    Oa[d2] = __builtin_amdgcn_mfma_f32_32x32x16_bf16(
                        vT[s][t][d2], pb.s8, Oa[d2], 0, 0, 0);
            }
        __builtin_amdgcn_s_setprio(0);
    }

    // ---- merge the two k-halves (wave pairs w, w+2 share q-rows) ----
    float* buf = fsm + qg * 2176;
    if (kh == 1) {
#pragma unroll
        for (int d2 = 0; d2 < 2; ++d2)
#pragma unroll
            for (int r = 0; r < 16; ++r)
                buf[(d2 * 16 + r) * 64 + lane] = Oa[d2][r];
        buf[2048 + lane] = mrow;
        buf[2112 + lane] = lrow;
    }
    __syncthreads();

    if (kh == 0) {
        const float mb = buf[2048 + lane];
        const float lb = buf[2112 + lane];
        const float M = fmaxf(mrow, mb);
        const float ea = exp2f(mrow - M), eb = exp2f(mb - M);
        lrow = lrow * ea + lb * eb;
#pragma unroll
        for (int d2 = 0; d2 < 2; ++d2)
#pragma unroll
            for (int r = 0; r < 16; ++r)
                Oa[d2][r] = Oa[d2][r] * ea + buf[(d2 * 16 + r) * 64 + lane] * eb;
    }
    __syncthreads();                        // merge reads done before Os reuse

    // ---- epilogue: normalize + transpose to row-major via LDS ----
    ushort* Os = (ushort*)fsm;              // [64][68]
    if (kh == 0) {
        const float inv = 1.0f / lrow;
#pragma unroll
        for (int d2 = 0; d2 < 2; ++d2)
#pragma unroll
            for (int r = 0; r < 16; ++r) {
                const int d = d2 * 32 + (r & 3) + 8 * (r >> 2) + 4 * l5;
                Os[(qg * 32 + l32) * 68 + d] = f2bf(Oa[d2][r] * inv);
            }
    }
    __syncthreads();

    const int row = tid >> 2, cc = (tid & 3) * 16;
#pragma unroll
    for (int i = 0; i < 2; ++i) {
        const short8 v = *(const short8*)&Os[row * 68 + cc + i * 8];
        *(short8*)&Ob[((size_t)b * N_SEQ + qt * 64 + row) * EMB + h * HD + cc + i * 8] = v;
    }
}

// ---------------------------------------------------------------------------
extern "C" void kernel_launch(void* const* d_in, const int* in_sizes, int n_in,
                              void* d_out, int out_size, void* d_ws, size_t ws_size,
                              hipStream_t stream)
{
    const float* x      = (const float*)d_in[0];
    const float* sinp   = (const float*)d_in[1];
    const float* cosp   = (const float*)d_in[2];
    const float* wq_w   = (const float*)d_in[3];
    const float* wq_b   = (const float*)d_in[4];
    const float* wk_w   = (const float*)d_in[5];
    const float* wk_b   = (const float*)d_in[6];
    const float* wv_w   = (const float*)d_in[7];
    const float* wv_b   = (const float*)d_in[8];
    const float* qn_w   = (const float*)d_in[9];
    const float* kn_w   = (const float*)d_in[10];
    const float* proj_w = (const float*)d_in[11];
    const float* proj_b = (const float*)d_in[12];
    float* out = (float*)d_out;

    // workspace layout (ushort elements) — ~39 MB
    ushort* Tq    = (ushort*)d_ws;            // 4096*1536
    ushort* xb    = Tq + 6291456;             // 4096*1024 (reused as Ob)
    ushort* Wqkv  = xb + 4194304;             // 1536*1024
    ushort* Wproj = Wqkv + 1572864;           // 1024*1024
    float*  bqkv  = (float*)(Wproj + 1048576);// 1536
    ushort* Qb    = (ushort*)(bqkv + 1536);   // 2*16*2048*64
    ushort* Kf    = Qb + 4194304;             // frag-order K, 1048576
    ushort* Vf    = Kf + 1048576;             // frag-order V^T, 1048576

    prep_kernel<<<6658, 256, 0, stream>>>(x, wq_w, wk_w, wv_w, proj_w,
                                          wq_b, wk_b, wv_b,
                                          xb, Wqkv, Wproj, bqkv);

    gemm_mfma_kernel<true><<<dim3(QKV_N / 128, M_TOT / 128), 256, 0, stream>>>(
        xb, Wqkv, bqkv, Tq, EMB, QKV_N);

    norm_rope_kernel<<<20480, 256, 0, stream>>>(Tq, qn_w, kn_w, sinp, cosp, Qb, Kf);

    transpose_v_kernel<<<dim3(32, 8), 256, 0, stream>>>(Tq, Vf);

    flash_mfma32_kernel<<<dim3(32, 32), 256, 0, stream>>>(Qb, Kf, Vf, xb);

    gemm_mfma_kernel<false><<<dim3(EMB / 128, M_TOT / 128), 256, 0, stream>>>(
        xb, Wproj, proj_b, out, EMB, EMB);
}

// Round 3
// 269.132 us; speedup vs baseline: 2.8373x; 1.0104x over previous
//
#include <hip/hip_runtime.h>
#include <hip/hip_bf16.h>
#include <math.h>

// GQA forward, round 8:
//  - flash: EXACT round-5 control flow (unconditional rescale, serial fmax —
//    the kernel sits at ~120/128 VGPR; round-7's defer-max branch tipped it
//    into spill: WRITE_SIZE 8->100MB, 117us). Only register-neutral deltas:
//    exp2-domain softmax (log2e folded into Q scale) + setprio around MFMA.
//  - gemm: retile 128x128 -> 128x64. qkv 384->768 blocks (3/CU), proj
//    256->512 (2/CU); 4-8 -> 12/8 waves per CU. Staging style unchanged.

#define N_SEQ 2048
#define EMB   1024
#define NH    16
#define NKV   4
#define HD    64
#define BATCH 2
#define M_TOT 4096
#define QKV_N 1536

typedef __attribute__((ext_vector_type(8)))  short short8;   // 8 bf16
typedef __attribute__((ext_vector_type(4)))  float f32x4;
typedef __attribute__((ext_vector_type(16))) float f32x16;

__device__ __forceinline__ ushort f2bf(float f) {
    union { __hip_bfloat16 h; ushort u; } cv;
    cv.h = __float2bfloat16(f);
    return cv.u;
}
__device__ __forceinline__ float bf2f(ushort u) {
    union { __hip_bfloat16 h; ushort u; } cv;
    cv.u = u;
    return __bfloat162float(cv.h);
}
__device__ __forceinline__ uint pack2bf(float a, float b) {
    union { __hip_bfloat162 h; uint u; } cv;
    cv.h = __float22bfloat162_rn(float2{a, b});   // a -> low 16, b -> high 16
    return cv.u;
}

// ---------------------------------------------------------------------------
// Fused prep (unchanged)
// ---------------------------------------------------------------------------
__device__ __forceinline__ void cvt4(const float* __restrict__ s,
                                     ushort* __restrict__ d, long g, long gd) {
    const float4 v = ((const float4*)s)[g];
    ushort4 o;
    o.x = f2bf(v.x); o.y = f2bf(v.y); o.z = f2bf(v.z); o.w = f2bf(v.w);
    ((ushort4*)d)[gd] = o;
}

__global__ __launch_bounds__(256) void prep_kernel(
    const float* __restrict__ x,  const float* __restrict__ wq,
    const float* __restrict__ wk, const float* __restrict__ wv,
    const float* __restrict__ wp, const float* __restrict__ bq,
    const float* __restrict__ bk, const float* __restrict__ bv,
    ushort* __restrict__ xb, ushort* __restrict__ Wqkv,
    ushort* __restrict__ Wproj, float* __restrict__ bqkv)
{
    const long i = (long)blockIdx.x * 256 + threadIdx.x;
    if (i < 1048576) {
        cvt4(x, xb, i, i);
    } else if (i < 1310720) {
        const long g = i - 1048576;
        cvt4(wq, Wqkv, g, g);
    } else if (i < 1376256) {
        const long g = i - 1310720;
        cvt4(wk, Wqkv, g, 262144 + g);
    } else if (i < 1441792) {
        const long g = i - 1376256;
        cvt4(wv, Wqkv, g, 327680 + g);
    } else if (i < 1703936) {
        const long g = i - 1441792;
        cvt4(wp, Wproj, g, g);
    } else if (i < 1704320) {
        const long j = i - 1703936;
        float4 v;
        if (j < 256)      v = ((const float4*)bq)[j];
        else if (j < 320) v = ((const float4*)bk)[j - 256];
        else              v = ((const float4*)bv)[j - 320];
        ((float4*)bqkv)[j] = v;
    }
}

// ---------------------------------------------------------------------------
// bf16 MFMA GEMM, 128x64 tile (4 waves; wave w = rows w*32..w*32+31, all 64
// cols). C[m][n] = sum_k A[m][k] W[n][k] + b[n]
// ---------------------------------------------------------------------------
template <bool BF16OUT>
__global__ __launch_bounds__(256) void gemm_mfma_kernel(
    const ushort* __restrict__ A, const ushort* __restrict__ W,
    const float* __restrict__ bias, void* __restrict__ Cout,
    int K, int ldc)
{
    __shared__ ushort As[128 * 40];
    __shared__ ushort Bs[64 * 40];

    const int tid = threadIdx.x;
    const int m0 = blockIdx.y * 128, n0 = blockIdx.x * 64;
    const int w = tid >> 6, lane = tid & 63;
    const int quad = lane >> 4, l16 = lane & 15;
    const int wm = w * 32;

    f32x4 acc[2][4] = {};

    float bb[4];
#pragma unroll
    for (int j = 0; j < 4; ++j) bb[j] = bias[n0 + j * 16 + l16];

    const int r0 = tid >> 2;       // 0..63
    const int c0 = tid & 3;
    const ushort* Ap = A + (size_t)(m0 + r0) * K + c0 * 8;
    const ushort* Wp = W + (size_t)(n0 + r0) * K + c0 * 8;

    for (int k0 = 0; k0 < K; k0 += 32) {
        const short8 a0 = *(const short8*)(Ap + k0);
        const short8 a1 = *(const short8*)(Ap + (size_t)64 * K + k0);
        const short8 b0 = *(const short8*)(Wp + k0);
        __syncthreads();
        *(short8*)&As[r0 * 40 + c0 * 8] = a0;
        *(short8*)&As[(r0 + 64) * 40 + c0 * 8] = a1;
        *(short8*)&Bs[r0 * 40 + c0 * 8] = b0;
        __syncthreads();

        short8 aF[2], bF[4];
#pragma unroll
        for (int i = 0; i < 2; ++i)
            aF[i] = *(const short8*)&As[(wm + i * 16 + l16) * 40 + quad * 8];
#pragma unroll
        for (int j = 0; j < 4; ++j)
            bF[j] = *(const short8*)&Bs[(j * 16 + l16) * 40 + quad * 8];
        __builtin_amdgcn_s_setprio(1);
#pragma unroll
        for (int i = 0; i < 2; ++i)
#pragma unroll
            for (int j = 0; j < 4; ++j)
                acc[i][j] = __builtin_amdgcn_mfma_f32_16x16x32_bf16(
                    aF[i], bF[j], acc[i][j], 0, 0, 0);
        __builtin_amdgcn_s_setprio(0);
    }

#pragma unroll
    for (int i = 0; i < 2; ++i) {
        const int rowb = m0 + wm + i * 16 + quad * 4;
#pragma unroll
        for (int j = 0; j < 4; ++j) {
            const int col = n0 + j * 16 + l16;
#pragma unroll
            for (int r = 0; r < 4; ++r) {
                const float vv = acc[i][j][r] + bb[j];
                if (BF16OUT)
                    ((ushort*)Cout)[(size_t)(rowb + r) * ldc + col] = f2bf(vv);
                else
                    ((float*)Cout)[(size_t)(rowb + r) * ldc + col] = vv;
            }
        }
    }
}

// ---------------------------------------------------------------------------
// Fused RMSNorm + RoPE. Q scale folds log2(e): flash softmax runs in exp2
// domain. K -> fragment-order Kf.
// ---------------------------------------------------------------------------
__global__ __launch_bounds__(256) void norm_rope_kernel(
    const ushort* __restrict__ Tq, const float* __restrict__ qn_w,
    const float* __restrict__ kn_w, const float* __restrict__ sinp,
    const float* __restrict__ cosp, ushort* __restrict__ Qb,
    ushort* __restrict__ Kf)
{
    const int gw = (int)(((long)blockIdx.x * 256 + threadIdx.x) >> 6);
    const int lane = threadIdx.x & 63;

    const bool isQ = (gw < 65536);
    const int vec = isQ ? gw : gw - 65536;
    const int hshift = isQ ? 4 : 2;
    const int colBase = isQ ? 0 : EMB;
    const float* nw = isQ ? qn_w : kn_w;
    const float outScale = isQ ? 0.125f * 1.44269504f : 1.0f;  // 1/sqrt(64)*log2e

    const int m = vec >> hshift;
    const int h = vec & ((1 << hshift) - 1);
    const int n = m & (N_SEQ - 1);
    const int b = m >> 11;

    const float t = bf2f(Tq[(size_t)m * QKV_N + colBase + h * HD + lane]);
    float s = t * t;
#pragma unroll
    for (int mask = 32; mask; mask >>= 1) s += __shfl_xor(s, mask, 64);
    const float r = rsqrtf(s * (1.0f / 64.0f) + 1e-6f);

    const float tn = t * r * nw[lane];
    const float partner = __shfl_xor(tn, 32, 64);
    const float rot = (lane < 32) ? -partner : partner;
    const float val = (tn * cosp[n * HD + lane] + rot * sinp[n * HD + lane]) * outScale;

    if (isQ) {
        Qb[((size_t)((b << 4) + h) * N_SEQ + n) * HD + lane] = f2bf(val);
    } else {
        const int kt = n >> 6, rr = n & 63, ss = rr >> 5, l32k = rr & 31;
        const int c = lane >> 4, l5k = (lane >> 3) & 1, j = lane & 7;
        Kf[((size_t)(b * NKV + h) * 32 + kt) * 4096
           + (ss * 4 + c) * 512 + l32k * 16 + l5k * 8 + j] = f2bf(val);
    }
}

// ---------------------------------------------------------------------------
// V -> fragment-order Vf (unchanged)
// ---------------------------------------------------------------------------
__global__ __launch_bounds__(256) void transpose_v_kernel(
    const ushort* __restrict__ Tq, ushort* __restrict__ Vf)
{
    __shared__ ushort L[64 * 72];
    const int kt = blockIdx.x;             // 0..31 (64 keys each)
    const int n0 = kt * 64;
    const int bkv = blockIdx.y;
    const int b = bkv >> 2, kv = bkv & 3;
    const int tid = threadIdx.x;

#pragma unroll
    for (int it = 0; it < 2; ++it) {
        const int j = tid + it * 256;
        const int r = j >> 3, c = j & 7;
        const short8 v = *(const short8*)&Tq[(size_t)(b * N_SEQ + n0 + r) * QKV_N
                                             + 1280 + kv * HD + c * 8];
        *(short8*)&L[r * 72 + c * 8] = v;
    }
    __syncthreads();
#pragma unroll
    for (int it = 0; it < 2; ++it) {
        const int j = tid + it * 256;
        const int d = j >> 3, c8 = j & 7;
        short8 o;
#pragma unroll
        for (int e = 0; e < 8; ++e) o[e] = (short)L[(c8 * 8 + e) * 72 + d];
        const int ss = c8 >> 2, tt = (c8 >> 1) & 1, l5v = c8 & 1;
        const int d2 = d >> 5, l32v = d & 31;
        *(short8*)&Vf[((size_t)bkv * 32 + kt) * 4096
                      + ((ss * 2 + tt) * 2 + d2) * 512 + l32v * 16 + l5v * 8] = o;
    }
}

// ---------------------------------------------------------------------------
// Barrier-free S^T-layout MFMA flash attention with in-block k-split x2.
// Round-5 control flow exactly; exp2-domain softmax + setprio only.
// ---------------------------------------------------------------------------
__global__ __launch_bounds__(256, 4) void flash_mfma32_kernel(
    const ushort* __restrict__ Qb, const ushort* __restrict__ Kf,
    const ushort* __restrict__ Vf, ushort* __restrict__ Ob)
{
    __shared__ float fsm[4352];            // 2 x (2048 O + 64 m + 64 l) = 17.4KB

    const int qt = blockIdx.x;             // 0..31 (64 q-rows)
    const int bh = blockIdx.y;
    const int b = bh >> 4, h = bh & 15;
    const int kvh = h >> 2;
    const int tid = threadIdx.x;
    const int w = tid >> 6, lane = tid & 63;
    const int l32 = lane & 31, l5 = lane >> 5;
    const int qg = w & 1;                  // q-group within block
    const int kh = w >> 1;                 // k-half

    const ushort* Qg = Qb + ((size_t)bh * N_SEQ + qt * 64 + qg * 32) * HD;
    const size_t kvbase = (size_t)(b * NKV + kvh) * (32 * 4096);
    const ushort* Kp = Kf + kvbase;
    const ushort* Vp = Vf + kvbase;
    const int loff = l32 * 16 + l5 * 8;

    // Q^T B-frags: qF[c][j] = Q[q0+l32][c*16 + l5*8 + j]
    short8 qF[4];
#pragma unroll
    for (int c = 0; c < 4; ++c)
        qF[c] = *(const short8*)&Qg[(size_t)l32 * HD + c * 16 + l5 * 8];

    f32x16 Oa[2] = {};                     // O^T d-tiles (d 0-31, 32-63)
    float mrow = -3.0e38f, lrow = 0.0f;

    for (int i = 0; i < 16; ++i) {
        const int kt = kh * 16 + i;
        const ushort* Kt = Kp + kt * 4096;
        const ushort* Vt = Vp + kt * 4096;

        // direct global->reg fragment loads (coalesced, L2-hit)
        short8 kT[2][4];
#pragma unroll
        for (int s = 0; s < 2; ++s)
#pragma unroll
            for (int c = 0; c < 4; ++c)
                kT[s][c] = *(const short8*)&Kt[(s * 4 + c) * 512 + loff];
        short8 vT[2][2][2];
#pragma unroll
        for (int s = 0; s < 2; ++s)
#pragma unroll
            for (int t = 0; t < 2; ++t)
#pragma unroll
                for (int d2 = 0; d2 < 2; ++d2)
                    vT[s][t][d2] = *(const short8*)&Vt[((s * 2 + t) * 2 + d2) * 512 + loff];

        // S^T (32 keys x 32 q-rows) per key-subtile s
        f32x16 Sv[2] = {};
        __builtin_amdgcn_s_setprio(1);
#pragma unroll
        for (int s = 0; s < 2; ++s)
#pragma unroll
            for (int c = 0; c < 4; ++c)
                Sv[s] = __builtin_amdgcn_mfma_f32_32x32x16_bf16(kT[s][c], qF[c], Sv[s], 0, 0, 0);
        __builtin_amdgcn_s_setprio(0);

        // online softmax (keys in-lane + 1 partner shuffle), exp2 domain
        float mx = -3.0e38f;
#pragma unroll
        for (int s = 0; s < 2; ++s)
#pragma unroll
            for (int r = 0; r < 16; ++r) mx = fmaxf(mx, Sv[s][r]);
        mx = fmaxf(mx, __shfl_xor(mx, 32, 64));
        const float mnew = fmaxf(mrow, mx);
        const float alpha = exp2f(mrow - mnew);
        mrow = mnew;
        float rs = 0.0f;
#pragma unroll
        for (int s = 0; s < 2; ++s)
#pragma unroll
            for (int r = 0; r < 16; ++r) {
                Sv[s][r] = exp2f(Sv[s][r] - mnew);
                rs += Sv[s][r];
            }
        rs += __shfl_xor(rs, 32, 64);
        lrow = lrow * alpha + rs;
#pragma unroll
        for (int t = 0; t < 2; ++t)
#pragma unroll
            for (int r = 0; r < 16; ++r) Oa[t][r] *= alpha;

        // pack P pairs: P2[s][2g+hh] = keys 8g+4*l5+2hh+{0,1} of subtile s
        uint P2[2][8];
#pragma unroll
        for (int s = 0; s < 2; ++s)
#pragma unroll
            for (int g = 0; g < 4; ++g)
#pragma unroll
                for (int hh = 0; hh < 2; ++hh)
                    P2[s][g * 2 + hh] =
                        pack2bf(Sv[s][4 * g + 2 * hh], Sv[s][4 * g + 2 * hh + 1]);

        // P^T B-frags in-register + PV mfma
        __builtin_amdgcn_s_setprio(1);
#pragma unroll
        for (int s = 0; s < 2; ++s)
#pragma unroll
            for (int t = 0; t < 2; ++t) {
                const uint snd0 = l5 ? P2[s][4 * t + 0] : P2[s][4 * t + 2];
                const uint snd1 = l5 ? P2[s][4 * t + 1] : P2[s][4 * t + 3];
                const uint kp0  = l5 ? P2[s][4 * t + 2] : P2[s][4 * t + 0];
                const uint kp1  = l5 ? P2[s][4 * t + 3] : P2[s][4 * t + 1];
                const uint rcv0 = __shfl_xor(snd0, 32, 64);
                const uint rcv1 = __shfl_xor(snd1, 32, 64);
                union { uint u[4]; short8 s8; } pb;
                pb.u[0] = l5 ? rcv0 : kp0;
                pb.u[1] = l5 ? rcv1 : kp1;
                pb.u[2] = l5 ? kp0 : rcv0;
                pb.u[3] = l5 ? kp1 : rcv1;
#pragma unroll
                for (int d2 = 0; d2 < 2; ++d2)
                    Oa[d2] = __builtin_amdgcn_mfma_f32_32x32x16_bf16(
                        vT[s][t][d2], pb.s8, Oa[d2], 0, 0, 0);
            }
        __builtin_amdgcn_s_setprio(0);
    }

    // ---- merge the two k-halves (wave pairs w, w+2 share q-rows) ----
    float* buf = fsm + qg * 2176;
    if (kh == 1) {
#pragma unroll
        for (int d2 = 0; d2 < 2; ++d2)
#pragma unroll
            for (int r = 0; r < 16; ++r)
                buf[(d2 * 16 + r) * 64 + lane] = Oa[d2][r];
        buf[2048 + lane] = mrow;
        buf[2112 + lane] = lrow;
    }
    __syncthreads();

    if (kh == 0) {
        const float mb = buf[2048 + lane];
        const float lb = buf[2112 + lane];
        const float M = fmaxf(mrow, mb);
        const float ea = exp2f(mrow - M), eb = exp2f(mb - M);
        lrow = lrow * ea + lb * eb;
#pragma unroll
        for (int d2 = 0; d2 < 2; ++d2)
#pragma unroll
            for (int r = 0; r < 16; ++r)
                Oa[d2][r] = Oa[d2][r] * ea + buf[(d2 * 16 + r) * 64 + lane] * eb;
    }
    __syncthreads();                        // merge reads done before Os reuse

    // ---- epilogue: normalize + transpose to row-major via LDS ----
    ushort* Os = (ushort*)fsm;              // [64][68]
    if (kh == 0) {
        const float inv = 1.0f / lrow;
#pragma unroll
        for (int d2 = 0; d2 < 2; ++d2)
#pragma unroll
            for (int r = 0; r < 16; ++r) {
                const int d = d2 * 32 + (r & 3) + 8 * (r >> 2) + 4 * l5;
                Os[(qg * 32 + l32) * 68 + d] = f2bf(Oa[d2][r] * inv);
            }
    }
    __syncthreads();

    const int row = tid >> 2, cc = (tid & 3) * 16;
#pragma unroll
    for (int i = 0; i < 2; ++i) {
        const short8 v = *(const short8*)&Os[row * 68 + cc + i * 8];
        *(short8*)&Ob[((size_t)b * N_SEQ + qt * 64 + row) * EMB + h * HD + cc + i * 8] = v;
    }
}

// ---------------------------------------------------------------------------
extern "C" void kernel_launch(void* const* d_in, const int* in_sizes, int n_in,
                              void* d_out, int out_size, void* d_ws, size_t ws_size,
                              hipStream_t stream)
{
    const float* x      = (const float*)d_in[0];
    const float* sinp   = (const float*)d_in[1];
    const float* cosp   = (const float*)d_in[2];
    const float* wq_w   = (const float*)d_in[3];
    const float* wq_b   = (const float*)d_in[4];
    const float* wk_w   = (const float*)d_in[5];
    const float* wk_b   = (const float*)d_in[6];
    const float* wv_w   = (const float*)d_in[7];
    const float* wv_b   = (const float*)d_in[8];
    const float* qn_w   = (const float*)d_in[9];
    const float* kn_w   = (const float*)d_in[10];
    const float* proj_w = (const float*)d_in[11];
    const float* proj_b = (const float*)d_in[12];
    float* out = (float*)d_out;

    // workspace layout (ushort elements) — ~39 MB
    ushort* Tq    = (ushort*)d_ws;            // 4096*1536
    ushort* xb    = Tq + 6291456;             // 4096*1024 (reused as Ob)
    ushort* Wqkv  = xb + 4194304;             // 1536*1024
    ushort* Wproj = Wqkv + 1572864;           // 1024*1024
    float*  bqkv  = (float*)(Wproj + 1048576);// 1536
    ushort* Qb    = (ushort*)(bqkv + 1536);   // 2*16*2048*64
    ushort* Kf    = Qb + 4194304;             // frag-order K, 1048576
    ushort* Vf    = Kf + 1048576;             // frag-order V^T, 1048576

    prep_kernel<<<6658, 256, 0, stream>>>(x, wq_w, wk_w, wv_w, proj_w,
                                          wq_b, wk_b, wv_b,
                                          xb, Wqkv, Wproj, bqkv);

    gemm_mfma_kernel<true><<<dim3(QKV_N / 64, M_TOT / 128), 256, 0, stream>>>(
        xb, Wqkv, bqkv, Tq, EMB, QKV_N);

    norm_rope_kernel<<<20480, 256, 0, stream>>>(Tq, qn_w, kn_w, sinp, cosp, Qb, Kf);

    transpose_v_kernel<<<dim3(32, 8), 256, 0, stream>>>(Tq, Vf);

    flash_mfma32_kernel<<<dim3(32, 32), 256, 0, stream>>>(Qb, Kf, Vf, xb);

    gemm_mfma_kernel<false><<<dim3(EMB / 64, M_TOT / 128), 256, 0, stream>>>(
        xb, Wproj, proj_b, out, EMB, EMB);
}

// Round 4
// 235.892 us; speedup vs baseline: 3.2371x; 1.1409x over previous
//
#include <hip/hip_runtime.h>
#include <hip/hip_bf16.h>
#include <math.h>

// GQA forward, round 9: flash recovery.
//  - flash: EXACT round-5 control flow, no setprio (it + libm exp2f caused
//    the r7/r8 spills: WRITE_SIZE 8->130MB). Single delta vs round 5:
//    __expf -> __builtin_amdgcn_exp2f (one v_exp_f32; log2e folded into Q
//    scale in norm_rope). Strictly fewer instructions than round 5.
//  - gemm: 128x64 retile kept (non-flash 155 -> 148.6us).

#define N_SEQ 2048
#define EMB   1024
#define NH    16
#define NKV   4
#define HD    64
#define BATCH 2
#define M_TOT 4096
#define QKV_N 1536

typedef __attribute__((ext_vector_type(8)))  short short8;   // 8 bf16
typedef __attribute__((ext_vector_type(4)))  float f32x4;
typedef __attribute__((ext_vector_type(16))) float f32x16;

__device__ __forceinline__ ushort f2bf(float f) {
    union { __hip_bfloat16 h; ushort u; } cv;
    cv.h = __float2bfloat16(f);
    return cv.u;
}
__device__ __forceinline__ float bf2f(ushort u) {
    union { __hip_bfloat16 h; ushort u; } cv;
    cv.u = u;
    return __bfloat162float(cv.h);
}
__device__ __forceinline__ uint pack2bf(float a, float b) {
    union { __hip_bfloat162 h; uint u; } cv;
    cv.h = __float22bfloat162_rn(float2{a, b});   // a -> low 16, b -> high 16
    return cv.u;
}

// ---------------------------------------------------------------------------
// Fused prep (unchanged)
// ---------------------------------------------------------------------------
__device__ __forceinline__ void cvt4(const float* __restrict__ s,
                                     ushort* __restrict__ d, long g, long gd) {
    const float4 v = ((const float4*)s)[g];
    ushort4 o;
    o.x = f2bf(v.x); o.y = f2bf(v.y); o.z = f2bf(v.z); o.w = f2bf(v.w);
    ((ushort4*)d)[gd] = o;
}

__global__ __launch_bounds__(256) void prep_kernel(
    const float* __restrict__ x,  const float* __restrict__ wq,
    const float* __restrict__ wk, const float* __restrict__ wv,
    const float* __restrict__ wp, const float* __restrict__ bq,
    const float* __restrict__ bk, const float* __restrict__ bv,
    ushort* __restrict__ xb, ushort* __restrict__ Wqkv,
    ushort* __restrict__ Wproj, float* __restrict__ bqkv)
{
    const long i = (long)blockIdx.x * 256 + threadIdx.x;
    if (i < 1048576) {
        cvt4(x, xb, i, i);
    } else if (i < 1310720) {
        const long g = i - 1048576;
        cvt4(wq, Wqkv, g, g);
    } else if (i < 1376256) {
        const long g = i - 1310720;
        cvt4(wk, Wqkv, g, 262144 + g);
    } else if (i < 1441792) {
        const long g = i - 1376256;
        cvt4(wv, Wqkv, g, 327680 + g);
    } else if (i < 1703936) {
        const long g = i - 1441792;
        cvt4(wp, Wproj, g, g);
    } else if (i < 1704320) {
        const long j = i - 1703936;
        float4 v;
        if (j < 256)      v = ((const float4*)bq)[j];
        else if (j < 320) v = ((const float4*)bk)[j - 256];
        else              v = ((const float4*)bv)[j - 320];
        ((float4*)bqkv)[j] = v;
    }
}

// ---------------------------------------------------------------------------
// bf16 MFMA GEMM, 128x64 tile (4 waves; wave w = rows w*32..w*32+31, all 64
// cols). C[m][n] = sum_k A[m][k] W[n][k] + b[n]
// ---------------------------------------------------------------------------
template <bool BF16OUT>
__global__ __launch_bounds__(256) void gemm_mfma_kernel(
    const ushort* __restrict__ A, const ushort* __restrict__ W,
    const float* __restrict__ bias, void* __restrict__ Cout,
    int K, int ldc)
{
    __shared__ ushort As[128 * 40];
    __shared__ ushort Bs[64 * 40];

    const int tid = threadIdx.x;
    const int m0 = blockIdx.y * 128, n0 = blockIdx.x * 64;
    const int w = tid >> 6, lane = tid & 63;
    const int quad = lane >> 4, l16 = lane & 15;
    const int wm = w * 32;

    f32x4 acc[2][4] = {};

    float bb[4];
#pragma unroll
    for (int j = 0; j < 4; ++j) bb[j] = bias[n0 + j * 16 + l16];

    const int r0 = tid >> 2;       // 0..63
    const int c0 = tid & 3;
    const ushort* Ap = A + (size_t)(m0 + r0) * K + c0 * 8;
    const ushort* Wp = W + (size_t)(n0 + r0) * K + c0 * 8;

    for (int k0 = 0; k0 < K; k0 += 32) {
        const short8 a0 = *(const short8*)(Ap + k0);
        const short8 a1 = *(const short8*)(Ap + (size_t)64 * K + k0);
        const short8 b0 = *(const short8*)(Wp + k0);
        __syncthreads();
        *(short8*)&As[r0 * 40 + c0 * 8] = a0;
        *(short8*)&As[(r0 + 64) * 40 + c0 * 8] = a1;
        *(short8*)&Bs[r0 * 40 + c0 * 8] = b0;
        __syncthreads();

        short8 aF[2], bF[4];
#pragma unroll
        for (int i = 0; i < 2; ++i)
            aF[i] = *(const short8*)&As[(wm + i * 16 + l16) * 40 + quad * 8];
#pragma unroll
        for (int j = 0; j < 4; ++j)
            bF[j] = *(const short8*)&Bs[(j * 16 + l16) * 40 + quad * 8];
        __builtin_amdgcn_s_setprio(1);
#pragma unroll
        for (int i = 0; i < 2; ++i)
#pragma unroll
            for (int j = 0; j < 4; ++j)
                acc[i][j] = __builtin_amdgcn_mfma_f32_16x16x32_bf16(
                    aF[i], bF[j], acc[i][j], 0, 0, 0);
        __builtin_amdgcn_s_setprio(0);
    }

#pragma unroll
    for (int i = 0; i < 2; ++i) {
        const int rowb = m0 + wm + i * 16 + quad * 4;
#pragma unroll
        for (int j = 0; j < 4; ++j) {
            const int col = n0 + j * 16 + l16;
#pragma unroll
            for (int r = 0; r < 4; ++r) {
                const float vv = acc[i][j][r] + bb[j];
                if (BF16OUT)
                    ((ushort*)Cout)[(size_t)(rowb + r) * ldc + col] = f2bf(vv);
                else
                    ((float*)Cout)[(size_t)(rowb + r) * ldc + col] = vv;
            }
        }
    }
}

// ---------------------------------------------------------------------------
// Fused RMSNorm + RoPE. Q scale folds log2(e): flash softmax runs in exp2
// domain. K -> fragment-order Kf.
// ---------------------------------------------------------------------------
__global__ __launch_bounds__(256) void norm_rope_kernel(
    const ushort* __restrict__ Tq, const float* __restrict__ qn_w,
    const float* __restrict__ kn_w, const float* __restrict__ sinp,
    const float* __restrict__ cosp, ushort* __restrict__ Qb,
    ushort* __restrict__ Kf)
{
    const int gw = (int)(((long)blockIdx.x * 256 + threadIdx.x) >> 6);
    const int lane = threadIdx.x & 63;

    const bool isQ = (gw < 65536);
    const int vec = isQ ? gw : gw - 65536;
    const int hshift = isQ ? 4 : 2;
    const int colBase = isQ ? 0 : EMB;
    const float* nw = isQ ? qn_w : kn_w;
    const float outScale = isQ ? 0.125f * 1.44269504f : 1.0f;  // 1/sqrt(64)*log2e

    const int m = vec >> hshift;
    const int h = vec & ((1 << hshift) - 1);
    const int n = m & (N_SEQ - 1);
    const int b = m >> 11;

    const float t = bf2f(Tq[(size_t)m * QKV_N + colBase + h * HD + lane]);
    float s = t * t;
#pragma unroll
    for (int mask = 32; mask; mask >>= 1) s += __shfl_xor(s, mask, 64);
    const float r = rsqrtf(s * (1.0f / 64.0f) + 1e-6f);

    const float tn = t * r * nw[lane];
    const float partner = __shfl_xor(tn, 32, 64);
    const float rot = (lane < 32) ? -partner : partner;
    const float val = (tn * cosp[n * HD + lane] + rot * sinp[n * HD + lane]) * outScale;

    if (isQ) {
        Qb[((size_t)((b << 4) + h) * N_SEQ + n) * HD + lane] = f2bf(val);
    } else {
        const int kt = n >> 6, rr = n & 63, ss = rr >> 5, l32k = rr & 31;
        const int c = lane >> 4, l5k = (lane >> 3) & 1, j = lane & 7;
        Kf[((size_t)(b * NKV + h) * 32 + kt) * 4096
           + (ss * 4 + c) * 512 + l32k * 16 + l5k * 8 + j] = f2bf(val);
    }
}

// ---------------------------------------------------------------------------
// V -> fragment-order Vf (unchanged)
// ---------------------------------------------------------------------------
__global__ __launch_bounds__(256) void transpose_v_kernel(
    const ushort* __restrict__ Tq, ushort* __restrict__ Vf)
{
    __shared__ ushort L[64 * 72];
    const int kt = blockIdx.x;             // 0..31 (64 keys each)
    const int n0 = kt * 64;
    const int bkv = blockIdx.y;
    const int b = bkv >> 2, kv = bkv & 3;
    const int tid = threadIdx.x;

#pragma unroll
    for (int it = 0; it < 2; ++it) {
        const int j = tid + it * 256;
        const int r = j >> 3, c = j & 7;
        const short8 v = *(const short8*)&Tq[(size_t)(b * N_SEQ + n0 + r) * QKV_N
                                             + 1280 + kv * HD + c * 8];
        *(short8*)&L[r * 72 + c * 8] = v;
    }
    __syncthreads();
#pragma unroll
    for (int it = 0; it < 2; ++it) {
        const int j = tid + it * 256;
        const int d = j >> 3, c8 = j & 7;
        short8 o;
#pragma unroll
        for (int e = 0; e < 8; ++e) o[e] = (short)L[(c8 * 8 + e) * 72 + d];
        const int ss = c8 >> 2, tt = (c8 >> 1) & 1, l5v = c8 & 1;
        const int d2 = d >> 5, l32v = d & 31;
        *(short8*)&Vf[((size_t)bkv * 32 + kt) * 4096
                      + ((ss * 2 + tt) * 2 + d2) * 512 + l32v * 16 + l5v * 8] = o;
    }
}

// ---------------------------------------------------------------------------
// Barrier-free S^T-layout MFMA flash attention with in-block k-split x2.
// Round-5 control flow exactly; only delta: raw v_exp_f32 via
// __builtin_amdgcn_exp2f (exp2 domain, log2e pre-folded into Q).
// ---------------------------------------------------------------------------
__global__ __launch_bounds__(256, 4) void flash_mfma32_kernel(
    const ushort* __restrict__ Qb, const ushort* __restrict__ Kf,
    const ushort* __restrict__ Vf, ushort* __restrict__ Ob)
{
    __shared__ float fsm[4352];            // 2 x (2048 O + 64 m + 64 l) = 17.4KB

    const int qt = blockIdx.x;             // 0..31 (64 q-rows)
    const int bh = blockIdx.y;
    const int b = bh >> 4, h = bh & 15;
    const int kvh = h >> 2;
    const int tid = threadIdx.x;
    const int w = tid >> 6, lane = tid & 63;
    const int l32 = lane & 31, l5 = lane >> 5;
    const int qg = w & 1;                  // q-group within block
    const int kh = w >> 1;                 // k-half

    const ushort* Qg = Qb + ((size_t)bh * N_SEQ + qt * 64 + qg * 32) * HD;
    const size_t kvbase = (size_t)(b * NKV + kvh) * (32 * 4096);
    const ushort* Kp = Kf + kvbase;
    const ushort* Vp = Vf + kvbase;
    const int loff = l32 * 16 + l5 * 8;

    // Q^T B-frags: qF[c][j] = Q[q0+l32][c*16 + l5*8 + j]
    short8 qF[4];
#pragma unroll
    for (int c = 0; c < 4; ++c)
        qF[c] = *(const short8*)&Qg[(size_t)l32 * HD + c * 16 + l5 * 8];

    f32x16 Oa[2] = {};                     // O^T d-tiles (d 0-31, 32-63)
    float mrow = -3.0e38f, lrow = 0.0f;

    for (int i = 0; i < 16; ++i) {
        const int kt = kh * 16 + i;
        const ushort* Kt = Kp + kt * 4096;
        const ushort* Vt = Vp + kt * 4096;

        // direct global->reg fragment loads (coalesced, L2-hit)
        short8 kT[2][4];
#pragma unroll
        for (int s = 0; s < 2; ++s)
#pragma unroll
            for (int c = 0; c < 4; ++c)
                kT[s][c] = *(const short8*)&Kt[(s * 4 + c) * 512 + loff];
        short8 vT[2][2][2];
#pragma unroll
        for (int s = 0; s < 2; ++s)
#pragma unroll
            for (int t = 0; t < 2; ++t)
#pragma unroll
                for (int d2 = 0; d2 < 2; ++d2)
                    vT[s][t][d2] = *(const short8*)&Vt[((s * 2 + t) * 2 + d2) * 512 + loff];

        // S^T (32 keys x 32 q-rows) per key-subtile s
        f32x16 Sv[2] = {};
#pragma unroll
        for (int s = 0; s < 2; ++s)
#pragma unroll
            for (int c = 0; c < 4; ++c)
                Sv[s] = __builtin_amdgcn_mfma_f32_32x32x16_bf16(kT[s][c], qF[c], Sv[s], 0, 0, 0);

        // online softmax (keys in-lane + 1 partner shuffle), exp2 domain
        float mx = -3.0e38f;
#pragma unroll
        for (int s = 0; s < 2; ++s)
#pragma unroll
            for (int r = 0; r < 16; ++r) mx = fmaxf(mx, Sv[s][r]);
        mx = fmaxf(mx, __shfl_xor(mx, 32, 64));
        const float mnew = fmaxf(mrow, mx);
        const float alpha = __builtin_amdgcn_exp2f(mrow - mnew);
        mrow = mnew;
        float rs = 0.0f;
#pragma unroll
        for (int s = 0; s < 2; ++s)
#pragma unroll
            for (int r = 0; r < 16; ++r) {
                Sv[s][r] = __builtin_amdgcn_exp2f(Sv[s][r] - mnew);
                rs += Sv[s][r];
            }
        rs += __shfl_xor(rs, 32, 64);
        lrow = lrow * alpha + rs;
#pragma unroll
        for (int t = 0; t < 2; ++t)
#pragma unroll
            for (int r = 0; r < 16; ++r) Oa[t][r] *= alpha;

        // pack P pairs: P2[s][2g+hh] = keys 8g+4*l5+2hh+{0,1} of subtile s
        uint P2[2][8];
#pragma unroll
        for (int s = 0; s < 2; ++s)
#pragma unroll
            for (int g = 0; g < 4; ++g)
#pragma unroll
                for (int hh = 0; hh < 2; ++hh)
                    P2[s][g * 2 + hh] =
                        pack2bf(Sv[s][4 * g + 2 * hh], Sv[s][4 * g + 2 * hh + 1]);

        // P^T B-frags in-register + PV mfma
#pragma unroll
        for (int s = 0; s < 2; ++s)
#pragma unroll
            for (int t = 0; t < 2; ++t) {
                const uint snd0 = l5 ? P2[s][4 * t + 0] : P2[s][4 * t + 2];
                const uint snd1 = l5 ? P2[s][4 * t + 1] : P2[s][4 * t + 3];
                const uint kp0  = l5 ? P2[s][4 * t + 2] : P2[s][4 * t + 0];
                const uint kp1  = l5 ? P2[s][4 * t + 3] : P2[s][4 * t + 1];
                const uint rcv0 = __shfl_xor(snd0, 32, 64);
                const uint rcv1 = __shfl_xor(snd1, 32, 64);
                union { uint u[4]; short8 s8; } pb;
                pb.u[0] = l5 ? rcv0 : kp0;
                pb.u[1] = l5 ? rcv1 : kp1;
                pb.u[2] = l5 ? kp0 : rcv0;
                pb.u[3] = l5 ? kp1 : rcv1;
#pragma unroll
                for (int d2 = 0; d2 < 2; ++d2)
                    Oa[d2] = __builtin_amdgcn_mfma_f32_32x32x16_bf16(
                        vT[s][t][d2], pb.s8, Oa[d2], 0, 0, 0);
            }
    }

    // ---- merge the two k-halves (wave pairs w, w+2 share q-rows) ----
    float* buf = fsm + qg * 2176;
    if (kh == 1) {
#pragma unroll
        for (int d2 = 0; d2 < 2; ++d2)
#pragma unroll
            for (int r = 0; r < 16; ++r)
                buf[(d2 * 16 + r) * 64 + lane] = Oa[d2][r];
        buf[2048 + lane] = mrow;
        buf[2112 + lane] = lrow;
    }
    __syncthreads();

    if (kh == 0) {
        const float mb = buf[2048 + lane];
        const float lb = buf[2112 + lane];
        const float M = fmaxf(mrow, mb);
        const float ea = __builtin_amdgcn_exp2f(mrow - M);
        const float eb = __builtin_amdgcn_exp2f(mb - M);
        lrow = lrow * ea + lb * eb;
#pragma unroll
        for (int d2 = 0; d2 < 2; ++d2)
#pragma unroll
            for (int r = 0; r < 16; ++r)
                Oa[d2][r] = Oa[d2][r] * ea + buf[(d2 * 16 + r) * 64 + lane] * eb;
    }
    __syncthreads();                        // merge reads done before Os reuse

    // ---- epilogue: normalize + transpose to row-major via LDS ----
    ushort* Os = (ushort*)fsm;              // [64][68]
    if (kh == 0) {
        const float inv = 1.0f / lrow;
#pragma unroll
        for (int d2 = 0; d2 < 2; ++d2)
#pragma unroll
            for (int r = 0; r < 16; ++r) {
                const int d = d2 * 32 + (r & 3) + 8 * (r >> 2) + 4 * l5;
                Os[(qg * 32 + l32) * 68 + d] = f2bf(Oa[d2][r] * inv);
            }
    }
    __syncthreads();

    const int row = tid >> 2, cc = (tid & 3) * 16;
#pragma unroll
    for (int i = 0; i < 2; ++i) {
        const short8 v = *(const short8*)&Os[row * 68 + cc + i * 8];
        *(short8*)&Ob[((size_t)b * N_SEQ + qt * 64 + row) * EMB + h * HD + cc + i * 8] = v;
    }
}

// ---------------------------------------------------------------------------
extern "C" void kernel_launch(void* const* d_in, const int* in_sizes, int n_in,
                              void* d_out, int out_size, void* d_ws, size_t ws_size,
                              hipStream_t stream)
{
    const float* x      = (const float*)d_in[0];
    const float* sinp   = (const float*)d_in[1];
    const float* cosp   = (const float*)d_in[2];
    const float* wq_w   = (const float*)d_in[3];
    const float* wq_b   = (const float*)d_in[4];
    const float* wk_w   = (const float*)d_in[5];
    const float* wk_b   = (const float*)d_in[6];
    const float* wv_w   = (const float*)d_in[7];
    const float* wv_b   = (const float*)d_in[8];
    const float* qn_w   = (const float*)d_in[9];
    const float* kn_w   = (const float*)d_in[10];
    const float* proj_w = (const float*)d_in[11];
    const float* proj_b = (const float*)d_in[12];
    float* out = (float*)d_out;

    // workspace layout (ushort elements) — ~39 MB
    ushort* Tq    = (ushort*)d_ws;            // 4096*1536
    ushort* xb    = Tq + 6291456;             // 4096*1024 (reused as Ob)
    ushort* Wqkv  = xb + 4194304;             // 1536*1024
    ushort* Wproj = Wqkv + 1572864;           // 1024*1024
    float*  bqkv  = (float*)(Wproj + 1048576);// 1536
    ushort* Qb    = (ushort*)(bqkv + 1536);   // 2*16*2048*64
    ushort* Kf    = Qb + 4194304;             // frag-order K, 1048576
    ushort* Vf    = Kf + 1048576;             // frag-order V^T, 1048576

    prep_kernel<<<6658, 256, 0, stream>>>(x, wq_w, wk_w, wv_w, proj_w,
                                          wq_b, wk_b, wv_b,
                                          xb, Wqkv, Wproj, bqkv);

    gemm_mfma_kernel<true><<<dim3(QKV_N / 64, M_TOT / 128), 256, 0, stream>>>(
        xb, Wqkv, bqkv, Tq, EMB, QKV_N);

    norm_rope_kernel<<<20480, 256, 0, stream>>>(Tq, qn_w, kn_w, sinp, cosp, Qb, Kf);

    transpose_v_kernel<<<dim3(32, 8), 256, 0, stream>>>(Tq, Vf);

    flash_mfma32_kernel<<<dim3(32, 32), 256, 0, stream>>>(Qb, Kf, Vf, xb);

    gemm_mfma_kernel<false><<<dim3(EMB / 64, M_TOT / 128), 256, 0, stream>>>(
        xb, Wproj, proj_b, out, EMB, EMB);
}

// Round 5
// 220.450 us; speedup vs baseline: 3.4639x; 1.0700x over previous
//
#include <hip/hip_runtime.h>
#include <hip/hip_bf16.h>
#include <math.h>

// GQA forward, round 10: recovery composition of proven-best pieces.
//  - flash: round-0 kernel VERBATIM (__expf, scale 0.125 in norm_rope, no
//    setprio, no defer-max). Session evidence: every in-loop modification
//    (branch r7, setprio+libm-exp2 r8, bare v_exp r9) regressed — the kernel
//    sits at ~120/128 VGPR and its softmax chain needs VALU filler.
//  - gemm: 128x64 retile (validated r3: non-flash 155.3 -> 148.7us).
//    qkv 768 blocks (3/CU), proj 512 (2/CU).

#define N_SEQ 2048
#define EMB   1024
#define NH    16
#define NKV   4
#define HD    64
#define BATCH 2
#define M_TOT 4096
#define QKV_N 1536

typedef __attribute__((ext_vector_type(8)))  short short8;   // 8 bf16
typedef __attribute__((ext_vector_type(4)))  float f32x4;
typedef __attribute__((ext_vector_type(16))) float f32x16;

__device__ __forceinline__ ushort f2bf(float f) {
    union { __hip_bfloat16 h; ushort u; } cv;
    cv.h = __float2bfloat16(f);
    return cv.u;
}
__device__ __forceinline__ float bf2f(ushort u) {
    union { __hip_bfloat16 h; ushort u; } cv;
    cv.u = u;
    return __bfloat162float(cv.h);
}
__device__ __forceinline__ uint pack2bf(float a, float b) {
    union { __hip_bfloat162 h; uint u; } cv;
    cv.h = __float22bfloat162_rn(float2{a, b});   // a -> low 16, b -> high 16
    return cv.u;
}

// ---------------------------------------------------------------------------
// Fused prep
// ---------------------------------------------------------------------------
__device__ __forceinline__ void cvt4(const float* __restrict__ s,
                                     ushort* __restrict__ d, long g, long gd) {
    const float4 v = ((const float4*)s)[g];
    ushort4 o;
    o.x = f2bf(v.x); o.y = f2bf(v.y); o.z = f2bf(v.z); o.w = f2bf(v.w);
    ((ushort4*)d)[gd] = o;
}

__global__ __launch_bounds__(256) void prep_kernel(
    const float* __restrict__ x,  const float* __restrict__ wq,
    const float* __restrict__ wk, const float* __restrict__ wv,
    const float* __restrict__ wp, const float* __restrict__ bq,
    const float* __restrict__ bk, const float* __restrict__ bv,
    ushort* __restrict__ xb, ushort* __restrict__ Wqkv,
    ushort* __restrict__ Wproj, float* __restrict__ bqkv)
{
    const long i = (long)blockIdx.x * 256 + threadIdx.x;
    if (i < 1048576) {
        cvt4(x, xb, i, i);
    } else if (i < 1310720) {
        const long g = i - 1048576;
        cvt4(wq, Wqkv, g, g);
    } else if (i < 1376256) {
        const long g = i - 1310720;
        cvt4(wk, Wqkv, g, 262144 + g);
    } else if (i < 1441792) {
        const long g = i - 1376256;
        cvt4(wv, Wqkv, g, 327680 + g);
    } else if (i < 1703936) {
        const long g = i - 1441792;
        cvt4(wp, Wproj, g, g);
    } else if (i < 1704320) {
        const long j = i - 1703936;
        float4 v;
        if (j < 256)      v = ((const float4*)bq)[j];
        else if (j < 320) v = ((const float4*)bk)[j - 256];
        else              v = ((const float4*)bv)[j - 320];
        ((float4*)bqkv)[j] = v;
    }
}

// ---------------------------------------------------------------------------
// bf16 MFMA GEMM, 128x64 tile (4 waves; wave w = rows w*32..w*32+31, all 64
// cols). C[m][n] = sum_k A[m][k] W[n][k] + b[n]
// ---------------------------------------------------------------------------
template <bool BF16OUT>
__global__ __launch_bounds__(256) void gemm_mfma_kernel(
    const ushort* __restrict__ A, const ushort* __restrict__ W,
    const float* __restrict__ bias, void* __restrict__ Cout,
    int K, int ldc)
{
    __shared__ ushort As[128 * 40];
    __shared__ ushort Bs[64 * 40];

    const int tid = threadIdx.x;
    const int m0 = blockIdx.y * 128, n0 = blockIdx.x * 64;
    const int w = tid >> 6, lane = tid & 63;
    const int quad = lane >> 4, l16 = lane & 15;
    const int wm = w * 32;

    f32x4 acc[2][4] = {};

    float bb[4];
#pragma unroll
    for (int j = 0; j < 4; ++j) bb[j] = bias[n0 + j * 16 + l16];

    const int r0 = tid >> 2;       // 0..63
    const int c0 = tid & 3;
    const ushort* Ap = A + (size_t)(m0 + r0) * K + c0 * 8;
    const ushort* Wp = W + (size_t)(n0 + r0) * K + c0 * 8;

    for (int k0 = 0; k0 < K; k0 += 32) {
        const short8 a0 = *(const short8*)(Ap + k0);
        const short8 a1 = *(const short8*)(Ap + (size_t)64 * K + k0);
        const short8 b0 = *(const short8*)(Wp + k0);
        __syncthreads();
        *(short8*)&As[r0 * 40 + c0 * 8] = a0;
        *(short8*)&As[(r0 + 64) * 40 + c0 * 8] = a1;
        *(short8*)&Bs[r0 * 40 + c0 * 8] = b0;
        __syncthreads();

        short8 aF[2], bF[4];
#pragma unroll
        for (int i = 0; i < 2; ++i)
            aF[i] = *(const short8*)&As[(wm + i * 16 + l16) * 40 + quad * 8];
#pragma unroll
        for (int j = 0; j < 4; ++j)
            bF[j] = *(const short8*)&Bs[(j * 16 + l16) * 40 + quad * 8];
        __builtin_amdgcn_s_setprio(1);
#pragma unroll
        for (int i = 0; i < 2; ++i)
#pragma unroll
            for (int j = 0; j < 4; ++j)
                acc[i][j] = __builtin_amdgcn_mfma_f32_16x16x32_bf16(
                    aF[i], bF[j], acc[i][j], 0, 0, 0);
        __builtin_amdgcn_s_setprio(0);
    }

#pragma unroll
    for (int i = 0; i < 2; ++i) {
        const int rowb = m0 + wm + i * 16 + quad * 4;
#pragma unroll
        for (int j = 0; j < 4; ++j) {
            const int col = n0 + j * 16 + l16;
#pragma unroll
            for (int r = 0; r < 4; ++r) {
                const float vv = acc[i][j][r] + bb[j];
                if (BF16OUT)
                    ((ushort*)Cout)[(size_t)(rowb + r) * ldc + col] = f2bf(vv);
                else
                    ((float*)Cout)[(size_t)(rowb + r) * ldc + col] = vv;
            }
        }
    }
}

// ---------------------------------------------------------------------------
// Fused RMSNorm + RoPE (round-0 verbatim). Q -> row-major Qb; K -> frag-order.
// ---------------------------------------------------------------------------
__global__ __launch_bounds__(256) void norm_rope_kernel(
    const ushort* __restrict__ Tq, const float* __restrict__ qn_w,
    const float* __restrict__ kn_w, const float* __restrict__ sinp,
    const float* __restrict__ cosp, ushort* __restrict__ Qb,
    ushort* __restrict__ Kf)
{
    const int gw = (int)(((long)blockIdx.x * 256 + threadIdx.x) >> 6);
    const int lane = threadIdx.x & 63;

    const bool isQ = (gw < 65536);
    const int vec = isQ ? gw : gw - 65536;
    const int hshift = isQ ? 4 : 2;
    const int colBase = isQ ? 0 : EMB;
    const float* nw = isQ ? qn_w : kn_w;
    const float outScale = isQ ? 0.125f : 1.0f;

    const int m = vec >> hshift;
    const int h = vec & ((1 << hshift) - 1);
    const int n = m & (N_SEQ - 1);
    const int b = m >> 11;

    const float t = bf2f(Tq[(size_t)m * QKV_N + colBase + h * HD + lane]);
    float s = t * t;
#pragma unroll
    for (int mask = 32; mask; mask >>= 1) s += __shfl_xor(s, mask, 64);
    const float r = rsqrtf(s * (1.0f / 64.0f) + 1e-6f);

    const float tn = t * r * nw[lane];
    const float partner = __shfl_xor(tn, 32, 64);
    const float rot = (lane < 32) ? -partner : partner;
    const float val = (tn * cosp[n * HD + lane] + rot * sinp[n * HD + lane]) * outScale;

    if (isQ) {
        Qb[((size_t)((b << 4) + h) * N_SEQ + n) * HD + lane] = f2bf(val);
    } else {
        const int kt = n >> 6, rr = n & 63, ss = rr >> 5, l32k = rr & 31;
        const int c = lane >> 4, l5k = (lane >> 3) & 1, j = lane & 7;
        Kf[((size_t)(b * NKV + h) * 32 + kt) * 4096
           + (ss * 4 + c) * 512 + l32k * 16 + l5k * 8 + j] = f2bf(val);
    }
}

// ---------------------------------------------------------------------------
// V -> fragment-order Vf (unchanged)
// ---------------------------------------------------------------------------
__global__ __launch_bounds__(256) void transpose_v_kernel(
    const ushort* __restrict__ Tq, ushort* __restrict__ Vf)
{
    __shared__ ushort L[64 * 72];
    const int kt = blockIdx.x;             // 0..31 (64 keys each)
    const int n0 = kt * 64;
    const int bkv = blockIdx.y;
    const int b = bkv >> 2, kv = bkv & 3;
    const int tid = threadIdx.x;

#pragma unroll
    for (int it = 0; it < 2; ++it) {
        const int j = tid + it * 256;
        const int r = j >> 3, c = j & 7;
        const short8 v = *(const short8*)&Tq[(size_t)(b * N_SEQ + n0 + r) * QKV_N
                                             + 1280 + kv * HD + c * 8];
        *(short8*)&L[r * 72 + c * 8] = v;
    }
    __syncthreads();
#pragma unroll
    for (int it = 0; it < 2; ++it) {
        const int j = tid + it * 256;
        const int d = j >> 3, c8 = j & 7;
        short8 o;
#pragma unroll
        for (int e = 0; e < 8; ++e) o[e] = (short)L[(c8 * 8 + e) * 72 + d];
        const int ss = c8 >> 2, tt = (c8 >> 1) & 1, l5v = c8 & 1;
        const int d2 = d >> 5, l32v = d & 31;
        *(short8*)&Vf[((size_t)bkv * 32 + kt) * 4096
                      + ((ss * 2 + tt) * 2 + d2) * 512 + l32v * 16 + l5v * 8] = o;
    }
}

// ---------------------------------------------------------------------------
// Barrier-free S^T-layout MFMA flash attention with in-block k-split.
// Round-0 kernel verbatim.
// ---------------------------------------------------------------------------
__global__ __launch_bounds__(256, 4) void flash_mfma32_kernel(
    const ushort* __restrict__ Qb, const ushort* __restrict__ Kf,
    const ushort* __restrict__ Vf, ushort* __restrict__ Ob)
{
    __shared__ float fsm[4352];            // 2 x (2048 O + 64 m + 64 l) = 17.4KB

    const int qt = blockIdx.x;             // 0..31 (64 q-rows)
    const int bh = blockIdx.y;
    const int b = bh >> 4, h = bh & 15;
    const int kvh = h >> 2;
    const int tid = threadIdx.x;
    const int w = tid >> 6, lane = tid & 63;
    const int l32 = lane & 31, l5 = lane >> 5;
    const int qg = w & 1;                  // q-group within block
    const int kh = w >> 1;                 // k-half

    const ushort* Qg = Qb + ((size_t)bh * N_SEQ + qt * 64 + qg * 32) * HD;
    const size_t kvbase = (size_t)(b * NKV + kvh) * (32 * 4096);
    const ushort* Kp = Kf + kvbase;
    const ushort* Vp = Vf + kvbase;
    const int loff = l32 * 16 + l5 * 8;

    // Q^T B-frags: qF[c][j] = Q[q0+l32][c*16 + l5*8 + j]
    short8 qF[4];
#pragma unroll
    for (int c = 0; c < 4; ++c)
        qF[c] = *(const short8*)&Qg[(size_t)l32 * HD + c * 16 + l5 * 8];

    f32x16 Oa[2] = {};                     // O^T d-tiles (d 0-31, 32-63)
    float mrow = -3.0e38f, lrow = 0.0f;

    for (int i = 0; i < 16; ++i) {
        const int kt = kh * 16 + i;
        const ushort* Kt = Kp + kt * 4096;
        const ushort* Vt = Vp + kt * 4096;

        // direct global->reg fragment loads (coalesced, L2-hit)
        short8 kT[2][4];
#pragma unroll
        for (int s = 0; s < 2; ++s)
#pragma unroll
            for (int c = 0; c < 4; ++c)
                kT[s][c] = *(const short8*)&Kt[(s * 4 + c) * 512 + loff];
        short8 vT[2][2][2];
#pragma unroll
        for (int s = 0; s < 2; ++s)
#pragma unroll
            for (int t = 0; t < 2; ++t)
#pragma unroll
                for (int d2 = 0; d2 < 2; ++d2)
                    vT[s][t][d2] = *(const short8*)&Vt[((s * 2 + t) * 2 + d2) * 512 + loff];

        // S^T (32 keys x 32 q-rows) per key-subtile s
        f32x16 Sv[2] = {};
#pragma unroll
        for (int s = 0; s < 2; ++s)
#pragma unroll
            for (int c = 0; c < 4; ++c)
                Sv[s] = __builtin_amdgcn_mfma_f32_32x32x16_bf16(kT[s][c], qF[c], Sv[s], 0, 0, 0);

        // online softmax (keys in-lane + 1 partner shuffle)
        float mx = -3.0e38f;
#pragma unroll
        for (int s = 0; s < 2; ++s)
#pragma unroll
            for (int r = 0; r < 16; ++r) mx = fmaxf(mx, Sv[s][r]);
        mx = fmaxf(mx, __shfl_xor(mx, 32, 64));
        const float mnew = fmaxf(mrow, mx);
        const float alpha = __expf(mrow - mnew);
        mrow = mnew;
        float rs = 0.0f;
#pragma unroll
        for (int s = 0; s < 2; ++s)
#pragma unroll
            for (int r = 0; r < 16; ++r) {
                Sv[s][r] = __expf(Sv[s][r] - mnew);
                rs += Sv[s][r];
            }
        rs += __shfl_xor(rs, 32, 64);
        lrow = lrow * alpha + rs;
#pragma unroll
        for (int t = 0; t < 2; ++t)
#pragma unroll
            for (int r = 0; r < 16; ++r) Oa[t][r] *= alpha;

        // pack P pairs: P2[s][2g+hh] = keys 8g+4*l5+2hh+{0,1} of subtile s
        uint P2[2][8];
#pragma unroll
        for (int s = 0; s < 2; ++s)
#pragma unroll
            for (int g = 0; g < 4; ++g)
#pragma unroll
                for (int hh = 0; hh < 2; ++hh)
                    P2[s][g * 2 + hh] =
                        pack2bf(Sv[s][4 * g + 2 * hh], Sv[s][4 * g + 2 * hh + 1]);

        // P^T B-frags in-register + PV mfma
#pragma unroll
        for (int s = 0; s < 2; ++s)
#pragma unroll
            for (int t = 0; t < 2; ++t) {
                const uint snd0 = l5 ? P2[s][4 * t + 0] : P2[s][4 * t + 2];
                const uint snd1 = l5 ? P2[s][4 * t + 1] : P2[s][4 * t + 3];
                const uint kp0  = l5 ? P2[s][4 * t + 2] : P2[s][4 * t + 0];
                const uint kp1  = l5 ? P2[s][4 * t + 3] : P2[s][4 * t + 1];
                const uint rcv0 = __shfl_xor(snd0, 32, 64);
                const uint rcv1 = __shfl_xor(snd1, 32, 64);
                union { uint u[4]; short8 s8; } pb;
                pb.u[0] = l5 ? rcv0 : kp0;
                pb.u[1] = l5 ? rcv1 : kp1;
                pb.u[2] = l5 ? kp0 : rcv0;
                pb.u[3] = l5 ? kp1 : rcv1;
#pragma unroll
                for (int d2 = 0; d2 < 2; ++d2)
                    Oa[d2] = __builtin_amdgcn_mfma_f32_32x32x16_bf16(
                        vT[s][t][d2], pb.s8, Oa[d2], 0, 0, 0);
            }
    }

    // ---- merge the two k-halves (wave pairs w, w+2 share q-rows) ----
    float* buf = fsm + qg * 2176;
    if (kh == 1) {
#pragma unroll
        for (int d2 = 0; d2 < 2; ++d2)
#pragma unroll
            for (int r = 0; r < 16; ++r)
                buf[(d2 * 16 + r) * 64 + lane] = Oa[d2][r];
        buf[2048 + lane] = mrow;
        buf[2112 + lane] = lrow;
    }
    __syncthreads();

    if (kh == 0) {
        const float mb = buf[2048 + lane];
        const float lb = buf[2112 + lane];
        const float M = fmaxf(mrow, mb);
        const float ea = __expf(mrow - M), eb = __expf(mb - M);
        lrow = lrow * ea + lb * eb;
#pragma unroll
        for (int d2 = 0; d2 < 2; ++d2)
#pragma unroll
            for (int r = 0; r < 16; ++r)
                Oa[d2][r] = Oa[d2][r] * ea + buf[(d2 * 16 + r) * 64 + lane] * eb;
    }
    __syncthreads();                        // merge reads done before Os reuse

    // ---- epilogue: normalize + transpose to row-major via LDS ----
    ushort* Os = (ushort*)fsm;              // [64][68]
    if (kh == 0) {
        const float inv = 1.0f / lrow;
#pragma unroll
        for (int d2 = 0; d2 < 2; ++d2)
#pragma unroll
            for (int r = 0; r < 16; ++r) {
                const int d = d2 * 32 + (r & 3) + 8 * (r >> 2) + 4 * l5;
                Os[(qg * 32 + l32) * 68 + d] = f2bf(Oa[d2][r] * inv);
            }
    }
    __syncthreads();

    const int row = tid >> 2, cc = (tid & 3) * 16;
#pragma unroll
    for (int i = 0; i < 2; ++i) {
        const short8 v = *(const short8*)&Os[row * 68 + cc + i * 8];
        *(short8*)&Ob[((size_t)b * N_SEQ + qt * 64 + row) * EMB + h * HD + cc + i * 8] = v;
    }
}

// ---------------------------------------------------------------------------
extern "C" void kernel_launch(void* const* d_in, const int* in_sizes, int n_in,
                              void* d_out, int out_size, void* d_ws, size_t ws_size,
                              hipStream_t stream)
{
    const float* x      = (const float*)d_in[0];
    const float* sinp   = (const float*)d_in[1];
    const float* cosp   = (const float*)d_in[2];
    const float* wq_w   = (const float*)d_in[3];
    const float* wq_b   = (const float*)d_in[4];
    const float* wk_w   = (const float*)d_in[5];
    const float* wk_b   = (const float*)d_in[6];
    const float* wv_w   = (const float*)d_in[7];
    const float* wv_b   = (const float*)d_in[8];
    const float* qn_w   = (const float*)d_in[9];
    const float* kn_w   = (const float*)d_in[10];
    const float* proj_w = (const float*)d_in[11];
    const float* proj_b = (const float*)d_in[12];
    float* out = (float*)d_out;

    // workspace layout (ushort elements) — ~39 MB
    ushort* Tq    = (ushort*)d_ws;            // 4096*1536
    ushort* xb    = Tq + 6291456;             // 4096*1024 (reused as Ob)
    ushort* Wqkv  = xb + 4194304;             // 1536*1024
    ushort* Wproj = Wqkv + 1572864;           // 1024*1024
    float*  bqkv  = (float*)(Wproj + 1048576);// 1536
    ushort* Qb    = (ushort*)(bqkv + 1536);   // 2*16*2048*64
    ushort* Kf    = Qb + 4194304;             // frag-order K, 1048576
    ushort* Vf    = Kf + 1048576;             // frag-order V^T, 1048576

    prep_kernel<<<6658, 256, 0, stream>>>(x, wq_w, wk_w, wv_w, proj_w,
                                          wq_b, wk_b, wv_b,
                                          xb, Wqkv, Wproj, bqkv);

    gemm_mfma_kernel<true><<<dim3(QKV_N / 64, M_TOT / 128), 256, 0, stream>>>(
        xb, Wqkv, bqkv, Tq, EMB, QKV_N);

    norm_rope_kernel<<<20480, 256, 0, stream>>>(Tq, qn_w, kn_w, sinp, cosp, Qb, Kf);

    transpose_v_kernel<<<dim3(32, 8), 256, 0, stream>>>(Tq, Vf);

    flash_mfma32_kernel<<<dim3(32, 32), 256, 0, stream>>>(Qb, Kf, Vf, xb);

    gemm_mfma_kernel<false><<<dim3(EMB / 64, M_TOT / 128), 256, 0, stream>>>(
        xb, Wproj, proj_b, out, EMB, EMB);
}

// Round 6
// 208.242 us; speedup vs baseline: 3.6669x; 1.0586x over previous
//
#include <hip/hip_runtime.h>
#include <hip/hip_bf16.h>
#include <math.h>

// GQA forward, round 11: fuse RMSNorm+RoPE into the QKV GEMM epilogue.
//  - 128x64 tile => each column-tile is exactly one head; a row's 64 head
//    cols live in one quad (16 lanes x 4 regs): RMSNorm = 4 squares + 4
//    shfl_xor; RoPE partner d<->d+-32 = j<->j+-2 (register-local).
//    Q -> Qb (row-major, pre-scaled 0.125), K -> Kf (fragment order),
//    V -> Tq (row-major, for transpose_v). norm_rope_kernel ELIMINATED.
//  - flash: round-0 VERBATIM (frozen: every in-loop edit regressed).
//  - proj gemm / prep / transpose_v: unchanged.

#define N_SEQ 2048
#define EMB   1024
#define NH    16
#define NKV   4
#define HD    64
#define BATCH 2
#define M_TOT 4096
#define QKV_N 1536

typedef __attribute__((ext_vector_type(8)))  short short8;   // 8 bf16
typedef __attribute__((ext_vector_type(4)))  float f32x4;
typedef __attribute__((ext_vector_type(16))) float f32x16;

__device__ __forceinline__ ushort f2bf(float f) {
    union { __hip_bfloat16 h; ushort u; } cv;
    cv.h = __float2bfloat16(f);
    return cv.u;
}
__device__ __forceinline__ float bf2f(ushort u) {
    union { __hip_bfloat16 h; ushort u; } cv;
    cv.u = u;
    return __bfloat162float(cv.h);
}
__device__ __forceinline__ uint pack2bf(float a, float b) {
    union { __hip_bfloat162 h; uint u; } cv;
    cv.h = __float22bfloat162_rn(float2{a, b});   // a -> low 16, b -> high 16
    return cv.u;
}

// ---------------------------------------------------------------------------
// Fused prep (unchanged)
// ---------------------------------------------------------------------------
__device__ __forceinline__ void cvt4(const float* __restrict__ s,
                                     ushort* __restrict__ d, long g, long gd) {
    const float4 v = ((const float4*)s)[g];
    ushort4 o;
    o.x = f2bf(v.x); o.y = f2bf(v.y); o.z = f2bf(v.z); o.w = f2bf(v.w);
    ((ushort4*)d)[gd] = o;
}

__global__ __launch_bounds__(256) void prep_kernel(
    const float* __restrict__ x,  const float* __restrict__ wq,
    const float* __restrict__ wk, const float* __restrict__ wv,
    const float* __restrict__ wp, const float* __restrict__ bq,
    const float* __restrict__ bk, const float* __restrict__ bv,
    ushort* __restrict__ xb, ushort* __restrict__ Wqkv,
    ushort* __restrict__ Wproj, float* __restrict__ bqkv)
{
    const long i = (long)blockIdx.x * 256 + threadIdx.x;
    if (i < 1048576) {
        cvt4(x, xb, i, i);
    } else if (i < 1310720) {
        const long g = i - 1048576;
        cvt4(wq, Wqkv, g, g);
    } else if (i < 1376256) {
        const long g = i - 1310720;
        cvt4(wk, Wqkv, g, 262144 + g);
    } else if (i < 1441792) {
        const long g = i - 1376256;
        cvt4(wv, Wqkv, g, 327680 + g);
    } else if (i < 1703936) {
        const long g = i - 1441792;
        cvt4(wp, Wproj, g, g);
    } else if (i < 1704320) {
        const long j = i - 1703936;
        float4 v;
        if (j < 256)      v = ((const float4*)bq)[j];
        else if (j < 320) v = ((const float4*)bk)[j - 256];
        else              v = ((const float4*)bv)[j - 320];
        ((float4*)bqkv)[j] = v;
    }
}

// ---------------------------------------------------------------------------
// QKV GEMM + fused RMSNorm/RoPE epilogue. 128x64 tile, 4 waves.
// n0 <  1024 : Q head (n0>>6)      -> Qb row-major, scale 0.125
// n0 in [1024,1280): K kv-head     -> Kf fragment order
// n0 >= 1280 : V                   -> Tq row-major (transpose_v reads it)
// ---------------------------------------------------------------------------
__global__ __launch_bounds__(256) void gemm_qkv_fused(
    const ushort* __restrict__ A, const ushort* __restrict__ W,
    const float* __restrict__ bias,
    const float* __restrict__ qn_w, const float* __restrict__ kn_w,
    const float* __restrict__ sinp, const float* __restrict__ cosp,
    ushort* __restrict__ Qb, ushort* __restrict__ Kf,
    ushort* __restrict__ Tq)
{
    __shared__ ushort As[128 * 40];
    __shared__ ushort Bs[64 * 40];

    const int tid = threadIdx.x;
    const int m0 = blockIdx.y * 128, n0 = blockIdx.x * 64;
    const int w = tid >> 6, lane = tid & 63;
    const int quad = lane >> 4, l16 = lane & 15;
    const int wm = w * 32;
    const int K = EMB;

    f32x4 acc[2][4] = {};

    float bb[4];
#pragma unroll
    for (int j = 0; j < 4; ++j) bb[j] = bias[n0 + j * 16 + l16];

    const int r0 = tid >> 2;       // 0..63
    const int c0 = tid & 3;
    const ushort* Ap = A + (size_t)(m0 + r0) * K + c0 * 8;
    const ushort* Wp = W + (size_t)(n0 + r0) * K + c0 * 8;

    for (int k0 = 0; k0 < K; k0 += 32) {
        const short8 a0 = *(const short8*)(Ap + k0);
        const short8 a1 = *(const short8*)(Ap + (size_t)64 * K + k0);
        const short8 b0 = *(const short8*)(Wp + k0);
        __syncthreads();
        *(short8*)&As[r0 * 40 + c0 * 8] = a0;
        *(short8*)&As[(r0 + 64) * 40 + c0 * 8] = a1;
        *(short8*)&Bs[r0 * 40 + c0 * 8] = b0;
        __syncthreads();

        short8 aF[2], bF[4];
#pragma unroll
        for (int i = 0; i < 2; ++i)
            aF[i] = *(const short8*)&As[(wm + i * 16 + l16) * 40 + quad * 8];
#pragma unroll
        for (int j = 0; j < 4; ++j)
            bF[j] = *(const short8*)&Bs[(j * 16 + l16) * 40 + quad * 8];
        __builtin_amdgcn_s_setprio(1);
#pragma unroll
        for (int i = 0; i < 2; ++i)
#pragma unroll
            for (int j = 0; j < 4; ++j)
                acc[i][j] = __builtin_amdgcn_mfma_f32_16x16x32_bf16(
                    aF[i], bF[j], acc[i][j], 0, 0, 0);
        __builtin_amdgcn_s_setprio(0);
    }

    if (n0 < 1280) {
        // ---- fused RMSNorm + RoPE epilogue (Q or K head tile) ----
        const bool isQ = (n0 < 1024);
        const float* nw = isQ ? qn_w : kn_w;
        const float oscale = isQ ? 0.125f : 1.0f;
        float nwv[4];
#pragma unroll
        for (int j = 0; j < 4; ++j) nwv[j] = nw[j * 16 + l16];

#pragma unroll
        for (int i = 0; i < 2; ++i) {
#pragma unroll
            for (int r = 0; r < 4; ++r) {
                const int m = m0 + wm + i * 16 + quad * 4 + r;
                const int n = m & (N_SEQ - 1);
                const int bI = m >> 11;

                float v4[4];
                float ssum = 0.0f;
#pragma unroll
                for (int j = 0; j < 4; ++j) {
                    v4[j] = acc[i][j][r] + bb[j];
                    ssum += v4[j] * v4[j];
                }
                // quad-level reduce (16 lanes share this row)
                ssum += __shfl_xor(ssum, 1, 64);
                ssum += __shfl_xor(ssum, 2, 64);
                ssum += __shfl_xor(ssum, 4, 64);
                ssum += __shfl_xor(ssum, 8, 64);
                const float rinv = rsqrtf(ssum * (1.0f / 64.0f) + 1e-6f);

                float tn[4], val[4];
#pragma unroll
                for (int j = 0; j < 4; ++j) tn[j] = v4[j] * rinv * nwv[j];
#pragma unroll
                for (int j = 0; j < 4; ++j) {
                    const int d = j * 16 + l16;
                    const float rot = (j < 2) ? -tn[j + 2] : tn[j - 2];
                    val[j] = (tn[j] * cosp[n * HD + d] + rot * sinp[n * HD + d]) * oscale;
                }

                if (isQ) {
                    const size_t qrow =
                        ((size_t)((bI << 4) + (n0 >> 6)) * N_SEQ + n) * HD;
#pragma unroll
                    for (int j = 0; j < 4; ++j)
                        Qb[qrow + j * 16 + l16] = f2bf(val[j]);
                } else {
                    const int kvh = (n0 >> 6) - 16;
                    const int kt = n >> 6, rr = n & 63;
                    const int ss2 = rr >> 5, l32k = rr & 31;
                    const size_t kb =
                        ((size_t)(bI * NKV + kvh) * 32 + kt) * 4096 + l32k * 16 + l16;
#pragma unroll
                    for (int j = 0; j < 4; ++j)
                        Kf[kb + (ss2 * 4 + j) * 512] = f2bf(val[j]);
                }
            }
        }
    } else {
        // ---- V tile: plain row-major store into Tq ----
#pragma unroll
        for (int i = 0; i < 2; ++i) {
            const int rowb = m0 + wm + i * 16 + quad * 4;
#pragma unroll
            for (int j = 0; j < 4; ++j) {
                const int col = n0 + j * 16 + l16;
#pragma unroll
                for (int r = 0; r < 4; ++r) {
                    const float vv = acc[i][j][r] + bb[j];
                    Tq[(size_t)(rowb + r) * QKV_N + col] = f2bf(vv);
                }
            }
        }
    }
}

// ---------------------------------------------------------------------------
// bf16 MFMA GEMM, 128x64 tile (proj). C[m][n] = sum_k A[m][k] W[n][k] + b[n]
// ---------------------------------------------------------------------------
template <bool BF16OUT>
__global__ __launch_bounds__(256) void gemm_mfma_kernel(
    const ushort* __restrict__ A, const ushort* __restrict__ W,
    const float* __restrict__ bias, void* __restrict__ Cout,
    int K, int ldc)
{
    __shared__ ushort As[128 * 40];
    __shared__ ushort Bs[64 * 40];

    const int tid = threadIdx.x;
    const int m0 = blockIdx.y * 128, n0 = blockIdx.x * 64;
    const int w = tid >> 6, lane = tid & 63;
    const int quad = lane >> 4, l16 = lane & 15;
    const int wm = w * 32;

    f32x4 acc[2][4] = {};

    float bb[4];
#pragma unroll
    for (int j = 0; j < 4; ++j) bb[j] = bias[n0 + j * 16 + l16];

    const int r0 = tid >> 2;       // 0..63
    const int c0 = tid & 3;
    const ushort* Ap = A + (size_t)(m0 + r0) * K + c0 * 8;
    const ushort* Wp = W + (size_t)(n0 + r0) * K + c0 * 8;

    for (int k0 = 0; k0 < K; k0 += 32) {
        const short8 a0 = *(const short8*)(Ap + k0);
        const short8 a1 = *(const short8*)(Ap + (size_t)64 * K + k0);
        const short8 b0 = *(const short8*)(Wp + k0);
        __syncthreads();
        *(short8*)&As[r0 * 40 + c0 * 8] = a0;
        *(short8*)&As[(r0 + 64) * 40 + c0 * 8] = a1;
        *(short8*)&Bs[r0 * 40 + c0 * 8] = b0;
        __syncthreads();

        short8 aF[2], bF[4];
#pragma unroll
        for (int i = 0; i < 2; ++i)
            aF[i] = *(const short8*)&As[(wm + i * 16 + l16) * 40 + quad * 8];
#pragma unroll
        for (int j = 0; j < 4; ++j)
            bF[j] = *(const short8*)&Bs[(j * 16 + l16) * 40 + quad * 8];
        __builtin_amdgcn_s_setprio(1);
#pragma unroll
        for (int i = 0; i < 2; ++i)
#pragma unroll
            for (int j = 0; j < 4; ++j)
                acc[i][j] = __builtin_amdgcn_mfma_f32_16x16x32_bf16(
                    aF[i], bF[j], acc[i][j], 0, 0, 0);
        __builtin_amdgcn_s_setprio(0);
    }

#pragma unroll
    for (int i = 0; i < 2; ++i) {
        const int rowb = m0 + wm + i * 16 + quad * 4;
#pragma unroll
        for (int j = 0; j < 4; ++j) {
            const int col = n0 + j * 16 + l16;
#pragma unroll
            for (int r = 0; r < 4; ++r) {
                const float vv = acc[i][j][r] + bb[j];
                if (BF16OUT)
                    ((ushort*)Cout)[(size_t)(rowb + r) * ldc + col] = f2bf(vv);
                else
                    ((float*)Cout)[(size_t)(rowb + r) * ldc + col] = vv;
            }
        }
    }
}

// ---------------------------------------------------------------------------
// V -> fragment-order Vf (unchanged; reads V columns of Tq)
// ---------------------------------------------------------------------------
__global__ __launch_bounds__(256) void transpose_v_kernel(
    const ushort* __restrict__ Tq, ushort* __restrict__ Vf)
{
    __shared__ ushort L[64 * 72];
    const int kt = blockIdx.x;             // 0..31 (64 keys each)
    const int n0 = kt * 64;
    const int bkv = blockIdx.y;
    const int b = bkv >> 2, kv = bkv & 3;
    const int tid = threadIdx.x;

#pragma unroll
    for (int it = 0; it < 2; ++it) {
        const int j = tid + it * 256;
        const int r = j >> 3, c = j & 7;
        const short8 v = *(const short8*)&Tq[(size_t)(b * N_SEQ + n0 + r) * QKV_N
                                             + 1280 + kv * HD + c * 8];
        *(short8*)&L[r * 72 + c * 8] = v;
    }
    __syncthreads();
#pragma unroll
    for (int it = 0; it < 2; ++it) {
        const int j = tid + it * 256;
        const int d = j >> 3, c8 = j & 7;
        short8 o;
#pragma unroll
        for (int e = 0; e < 8; ++e) o[e] = (short)L[(c8 * 8 + e) * 72 + d];
        const int ss = c8 >> 2, tt = (c8 >> 1) & 1, l5v = c8 & 1;
        const int d2 = d >> 5, l32v = d & 31;
        *(short8*)&Vf[((size_t)bkv * 32 + kt) * 4096
                      + ((ss * 2 + tt) * 2 + d2) * 512 + l32v * 16 + l5v * 8] = o;
    }
}

// ---------------------------------------------------------------------------
// Barrier-free S^T-layout MFMA flash attention with in-block k-split.
// Round-0 kernel verbatim (FROZEN).
// ---------------------------------------------------------------------------
__global__ __launch_bounds__(256, 4) void flash_mfma32_kernel(
    const ushort* __restrict__ Qb, const ushort* __restrict__ Kf,
    const ushort* __restrict__ Vf, ushort* __restrict__ Ob)
{
    __shared__ float fsm[4352];            // 2 x (2048 O + 64 m + 64 l) = 17.4KB

    const int qt = blockIdx.x;             // 0..31 (64 q-rows)
    const int bh = blockIdx.y;
    const int b = bh >> 4, h = bh & 15;
    const int kvh = h >> 2;
    const int tid = threadIdx.x;
    const int w = tid >> 6, lane = tid & 63;
    const int l32 = lane & 31, l5 = lane >> 5;
    const int qg = w & 1;                  // q-group within block
    const int kh = w >> 1;                 // k-half

    const ushort* Qg = Qb + ((size_t)bh * N_SEQ + qt * 64 + qg * 32) * HD;
    const size_t kvbase = (size_t)(b * NKV + kvh) * (32 * 4096);
    const ushort* Kp = Kf + kvbase;
    const ushort* Vp = Vf + kvbase;
    const int loff = l32 * 16 + l5 * 8;

    // Q^T B-frags: qF[c][j] = Q[q0+l32][c*16 + l5*8 + j]
    short8 qF[4];
#pragma unroll
    for (int c = 0; c < 4; ++c)
        qF[c] = *(const short8*)&Qg[(size_t)l32 * HD + c * 16 + l5 * 8];

    f32x16 Oa[2] = {};                     // O^T d-tiles (d 0-31, 32-63)
    float mrow = -3.0e38f, lrow = 0.0f;

    for (int i = 0; i < 16; ++i) {
        const int kt = kh * 16 + i;
        const ushort* Kt = Kp + kt * 4096;
        const ushort* Vt = Vp + kt * 4096;

        // direct global->reg fragment loads (coalesced, L2-hit)
        short8 kT[2][4];
#pragma unroll
        for (int s = 0; s < 2; ++s)
#pragma unroll
            for (int c = 0; c < 4; ++c)
                kT[s][c] = *(const short8*)&Kt[(s * 4 + c) * 512 + loff];
        short8 vT[2][2][2];
#pragma unroll
        for (int s = 0; s < 2; ++s)
#pragma unroll
            for (int t = 0; t < 2; ++t)
#pragma unroll
                for (int d2 = 0; d2 < 2; ++d2)
                    vT[s][t][d2] = *(const short8*)&Vt[((s * 2 + t) * 2 + d2) * 512 + loff];

        // S^T (32 keys x 32 q-rows) per key-subtile s
        f32x16 Sv[2] = {};
#pragma unroll
        for (int s = 0; s < 2; ++s)
#pragma unroll
            for (int c = 0; c < 4; ++c)
                Sv[s] = __builtin_amdgcn_mfma_f32_32x32x16_bf16(kT[s][c], qF[c], Sv[s], 0, 0, 0);

        // online softmax (keys in-lane + 1 partner shuffle)
        float mx = -3.0e38f;
#pragma unroll
        for (int s = 0; s < 2; ++s)
#pragma unroll
            for (int r = 0; r < 16; ++r) mx = fmaxf(mx, Sv[s][r]);
        mx = fmaxf(mx, __shfl_xor(mx, 32, 64));
        const float mnew = fmaxf(mrow, mx);
        const float alpha = __expf(mrow - mnew);
        mrow = mnew;
        float rs = 0.0f;
#pragma unroll
        for (int s = 0; s < 2; ++s)
#pragma unroll
            for (int r = 0; r < 16; ++r) {
                Sv[s][r] = __expf(Sv[s][r] - mnew);
                rs += Sv[s][r];
            }
        rs += __shfl_xor(rs, 32, 64);
        lrow = lrow * alpha + rs;
#pragma unroll
        for (int t = 0; t < 2; ++t)
#pragma unroll
            for (int r = 0; r < 16; ++r) Oa[t][r] *= alpha;

        // pack P pairs: P2[s][2g+hh] = keys 8g+4*l5+2hh+{0,1} of subtile s
        uint P2[2][8];
#pragma unroll
        for (int s = 0; s < 2; ++s)
#pragma unroll
            for (int g = 0; g < 4; ++g)
#pragma unroll
                for (int hh = 0; hh < 2; ++hh)
                    P2[s][g * 2 + hh] =
                        pack2bf(Sv[s][4 * g + 2 * hh], Sv[s][4 * g + 2 * hh + 1]);

        // P^T B-frags in-register + PV mfma
#pragma unroll
        for (int s = 0; s < 2; ++s)
#pragma unroll
            for (int t = 0; t < 2; ++t) {
                const uint snd0 = l5 ? P2[s][4 * t + 0] : P2[s][4 * t + 2];
                const uint snd1 = l5 ? P2[s][4 * t + 1] : P2[s][4 * t + 3];
                const uint kp0  = l5 ? P2[s][4 * t + 2] : P2[s][4 * t + 0];
                const uint kp1  = l5 ? P2[s][4 * t + 3] : P2[s][4 * t + 1];
                const uint rcv0 = __shfl_xor(snd0, 32, 64);
                const uint rcv1 = __shfl_xor(snd1, 32, 64);
                union { uint u[4]; short8 s8; } pb;
                pb.u[0] = l5 ? rcv0 : kp0;
                pb.u[1] = l5 ? rcv1 : kp1;
                pb.u[2] = l5 ? kp0 : rcv0;
                pb.u[3] = l5 ? kp1 : rcv1;
#pragma unroll
                for (int d2 = 0; d2 < 2; ++d2)
                    Oa[d2] = __builtin_amdgcn_mfma_f32_32x32x16_bf16(
                        vT[s][t][d2], pb.s8, Oa[d2], 0, 0, 0);
            }
    }

    // ---- merge the two k-halves (wave pairs w, w+2 share q-rows) ----
    float* buf = fsm + qg * 2176;
    if (kh == 1) {
#pragma unroll
        for (int d2 = 0; d2 < 2; ++d2)
#pragma unroll
            for (int r = 0; r < 16; ++r)
                buf[(d2 * 16 + r) * 64 + lane] = Oa[d2][r];
        buf[2048 + lane] = mrow;
        buf[2112 + lane] = lrow;
    }
    __syncthreads();

    if (kh == 0) {
        const float mb = buf[2048 + lane];
        const float lb = buf[2112 + lane];
        const float M = fmaxf(mrow, mb);
        const float ea = __expf(mrow - M), eb = __expf(mb - M);
        lrow = lrow * ea + lb * eb;
#pragma unroll
        for (int d2 = 0; d2 < 2; ++d2)
#pragma unroll
            for (int r = 0; r < 16; ++r)
                Oa[d2][r] = Oa[d2][r] * ea + buf[(d2 * 16 + r) * 64 + lane] * eb;
    }
    __syncthreads();                        // merge reads done before Os reuse

    // ---- epilogue: normalize + transpose to row-major via LDS ----
    ushort* Os = (ushort*)fsm;              // [64][68]
    if (kh == 0) {
        const float inv = 1.0f / lrow;
#pragma unroll
        for (int d2 = 0; d2 < 2; ++d2)
#pragma unroll
            for (int r = 0; r < 16; ++r) {
                const int d = d2 * 32 + (r & 3) + 8 * (r >> 2) + 4 * l5;
                Os[(qg * 32 + l32) * 68 + d] = f2bf(Oa[d2][r] * inv);
            }
    }
    __syncthreads();

    const int row = tid >> 2, cc = (tid & 3) * 16;
#pragma unroll
    for (int i = 0; i < 2; ++i) {
        const short8 v = *(const short8*)&Os[row * 68 + cc + i * 8];
        *(short8*)&Ob[((size_t)b * N_SEQ + qt * 64 + row) * EMB + h * HD + cc + i * 8] = v;
    }
}

// ---------------------------------------------------------------------------
extern "C" void kernel_launch(void* const* d_in, const int* in_sizes, int n_in,
                              void* d_out, int out_size, void* d_ws, size_t ws_size,
                              hipStream_t stream)
{
    const float* x      = (const float*)d_in[0];
    const float* sinp   = (const float*)d_in[1];
    const float* cosp   = (const float*)d_in[2];
    const float* wq_w   = (const float*)d_in[3];
    const float* wq_b   = (const float*)d_in[4];
    const float* wk_w   = (const float*)d_in[5];
    const float* wk_b   = (const float*)d_in[6];
    const float* wv_w   = (const float*)d_in[7];
    const float* wv_b   = (const float*)d_in[8];
    const float* qn_w   = (const float*)d_in[9];
    const float* kn_w   = (const float*)d_in[10];
    const float* proj_w = (const float*)d_in[11];
    const float* proj_b = (const float*)d_in[12];
    float* out = (float*)d_out;

    // workspace layout (ushort elements) — ~39 MB
    ushort* Tq    = (ushort*)d_ws;            // 4096*1536 (only V cols used now)
    ushort* xb    = Tq + 6291456;             // 4096*1024 (reused as Ob)
    ushort* Wqkv  = xb + 4194304;             // 1536*1024
    ushort* Wproj = Wqkv + 1572864;           // 1024*1024
    float*  bqkv  = (float*)(Wproj + 1048576);// 1536
    ushort* Qb    = (ushort*)(bqkv + 1536);   // 2*16*2048*64
    ushort* Kf    = Qb + 4194304;             // frag-order K, 1048576
    ushort* Vf    = Kf + 1048576;             // frag-order V^T, 1048576

    prep_kernel<<<6658, 256, 0, stream>>>(x, wq_w, wk_w, wv_w, proj_w,
                                          wq_b, wk_b, wv_b,
                                          xb, Wqkv, Wproj, bqkv);

    gemm_qkv_fused<<<dim3(QKV_N / 64, M_TOT / 128), 256, 0, stream>>>(
        xb, Wqkv, bqkv, qn_w, kn_w, sinp, cosp, Qb, Kf, Tq);

    transpose_v_kernel<<<dim3(32, 8), 256, 0, stream>>>(Tq, Vf);

    flash_mfma32_kernel<<<dim3(32, 32), 256, 0, stream>>>(Qb, Kf, Vf, xb);

    gemm_mfma_kernel<false><<<dim3(EMB / 64, M_TOT / 128), 256, 0, stream>>>(
        xb, Wproj, proj_b, out, EMB, EMB);
}

// Round 7
// 206.043 us; speedup vs baseline: 3.7061x; 1.0107x over previous
//
#include <hip/hip_runtime.h>
#include <hip/hip_bf16.h>
#include <math.h>

// GQA forward, round 12: fuse the V transpose into the QKV GEMM epilogue.
//  - V column-tile (64 cols) = one kv head; 128-row m-tile = two 64-key Vf
//    chunks; wave pair {0,1}/{2,3} owns keys [0,64)/[64,128). Per half:
//    barrier -> owning waves write acc to LDS L[64][68] (reuses As) ->
//    barrier -> 256 threads gather transposed short8s, coalesced store to
//    Vf. transpose_v_kernel + Tq buffer ELIMINATED (2MB write + 2MB read).
//  - Q/K epilogues (RMSNorm+RoPE fused, r11), flash (r0 verbatim, FROZEN),
//    prep, proj gemm: unchanged.

#define N_SEQ 2048
#define EMB   1024
#define NH    16
#define NKV   4
#define HD    64
#define BATCH 2
#define M_TOT 4096
#define QKV_N 1536

typedef __attribute__((ext_vector_type(8)))  short short8;   // 8 bf16
typedef __attribute__((ext_vector_type(4)))  float f32x4;
typedef __attribute__((ext_vector_type(16))) float f32x16;

__device__ __forceinline__ ushort f2bf(float f) {
    union { __hip_bfloat16 h; ushort u; } cv;
    cv.h = __float2bfloat16(f);
    return cv.u;
}
__device__ __forceinline__ float bf2f(ushort u) {
    union { __hip_bfloat16 h; ushort u; } cv;
    cv.u = u;
    return __bfloat162float(cv.h);
}
__device__ __forceinline__ uint pack2bf(float a, float b) {
    union { __hip_bfloat162 h; uint u; } cv;
    cv.h = __float22bfloat162_rn(float2{a, b});   // a -> low 16, b -> high 16
    return cv.u;
}

// ---------------------------------------------------------------------------
// Fused prep (unchanged)
// ---------------------------------------------------------------------------
__device__ __forceinline__ void cvt4(const float* __restrict__ s,
                                     ushort* __restrict__ d, long g, long gd) {
    const float4 v = ((const float4*)s)[g];
    ushort4 o;
    o.x = f2bf(v.x); o.y = f2bf(v.y); o.z = f2bf(v.z); o.w = f2bf(v.w);
    ((ushort4*)d)[gd] = o;
}

__global__ __launch_bounds__(256) void prep_kernel(
    const float* __restrict__ x,  const float* __restrict__ wq,
    const float* __restrict__ wk, const float* __restrict__ wv,
    const float* __restrict__ wp, const float* __restrict__ bq,
    const float* __restrict__ bk, const float* __restrict__ bv,
    ushort* __restrict__ xb, ushort* __restrict__ Wqkv,
    ushort* __restrict__ Wproj, float* __restrict__ bqkv)
{
    const long i = (long)blockIdx.x * 256 + threadIdx.x;
    if (i < 1048576) {
        cvt4(x, xb, i, i);
    } else if (i < 1310720) {
        const long g = i - 1048576;
        cvt4(wq, Wqkv, g, g);
    } else if (i < 1376256) {
        const long g = i - 1310720;
        cvt4(wk, Wqkv, g, 262144 + g);
    } else if (i < 1441792) {
        const long g = i - 1376256;
        cvt4(wv, Wqkv, g, 327680 + g);
    } else if (i < 1703936) {
        const long g = i - 1441792;
        cvt4(wp, Wproj, g, g);
    } else if (i < 1704320) {
        const long j = i - 1703936;
        float4 v;
        if (j < 256)      v = ((const float4*)bq)[j];
        else if (j < 320) v = ((const float4*)bk)[j - 256];
        else              v = ((const float4*)bv)[j - 320];
        ((float4*)bqkv)[j] = v;
    }
}

// ---------------------------------------------------------------------------
// QKV GEMM + fused epilogues. 128x64 tile, 4 waves.
// n0 <  1024 : Q head (n0>>6)      -> Qb row-major, scale 0.125 (RMSNorm+RoPE)
// n0 in [1024,1280): K kv-head     -> Kf fragment order (RMSNorm+RoPE)
// n0 >= 1280 : V kv-head           -> Vf fragment order (LDS transpose)
// ---------------------------------------------------------------------------
__global__ __launch_bounds__(256) void gemm_qkv_fused(
    const ushort* __restrict__ A, const ushort* __restrict__ W,
    const float* __restrict__ bias,
    const float* __restrict__ qn_w, const float* __restrict__ kn_w,
    const float* __restrict__ sinp, const float* __restrict__ cosp,
    ushort* __restrict__ Qb, ushort* __restrict__ Kf,
    ushort* __restrict__ Vf)
{
    __shared__ ushort As[128 * 40];
    __shared__ ushort Bs[64 * 40];

    const int tid = threadIdx.x;
    const int m0 = blockIdx.y * 128, n0 = blockIdx.x * 64;
    const int w = tid >> 6, lane = tid & 63;
    const int quad = lane >> 4, l16 = lane & 15;
    const int wm = w * 32;
    const int K = EMB;

    f32x4 acc[2][4] = {};

    float bb[4];
#pragma unroll
    for (int j = 0; j < 4; ++j) bb[j] = bias[n0 + j * 16 + l16];

    const int r0 = tid >> 2;       // 0..63
    const int c0 = tid & 3;
    const ushort* Ap = A + (size_t)(m0 + r0) * K + c0 * 8;
    const ushort* Wp = W + (size_t)(n0 + r0) * K + c0 * 8;

    for (int k0 = 0; k0 < K; k0 += 32) {
        const short8 a0 = *(const short8*)(Ap + k0);
        const short8 a1 = *(const short8*)(Ap + (size_t)64 * K + k0);
        const short8 b0 = *(const short8*)(Wp + k0);
        __syncthreads();
        *(short8*)&As[r0 * 40 + c0 * 8] = a0;
        *(short8*)&As[(r0 + 64) * 40 + c0 * 8] = a1;
        *(short8*)&Bs[r0 * 40 + c0 * 8] = b0;
        __syncthreads();

        short8 aF[2], bF[4];
#pragma unroll
        for (int i = 0; i < 2; ++i)
            aF[i] = *(const short8*)&As[(wm + i * 16 + l16) * 40 + quad * 8];
#pragma unroll
        for (int j = 0; j < 4; ++j)
            bF[j] = *(const short8*)&Bs[(j * 16 + l16) * 40 + quad * 8];
        __builtin_amdgcn_s_setprio(1);
#pragma unroll
        for (int i = 0; i < 2; ++i)
#pragma unroll
            for (int j = 0; j < 4; ++j)
                acc[i][j] = __builtin_amdgcn_mfma_f32_16x16x32_bf16(
                    aF[i], bF[j], acc[i][j], 0, 0, 0);
        __builtin_amdgcn_s_setprio(0);
    }

    if (n0 < 1280) {
        // ---- fused RMSNorm + RoPE epilogue (Q or K head tile) ----
        const bool isQ = (n0 < 1024);
        const float* nw = isQ ? qn_w : kn_w;
        const float oscale = isQ ? 0.125f : 1.0f;
        float nwv[4];
#pragma unroll
        for (int j = 0; j < 4; ++j) nwv[j] = nw[j * 16 + l16];

#pragma unroll
        for (int i = 0; i < 2; ++i) {
#pragma unroll
            for (int r = 0; r < 4; ++r) {
                const int m = m0 + wm + i * 16 + quad * 4 + r;
                const int n = m & (N_SEQ - 1);
                const int bI = m >> 11;

                float v4[4];
                float ssum = 0.0f;
#pragma unroll
                for (int j = 0; j < 4; ++j) {
                    v4[j] = acc[i][j][r] + bb[j];
                    ssum += v4[j] * v4[j];
                }
                // quad-level reduce (16 lanes share this row)
                ssum += __shfl_xor(ssum, 1, 64);
                ssum += __shfl_xor(ssum, 2, 64);
                ssum += __shfl_xor(ssum, 4, 64);
                ssum += __shfl_xor(ssum, 8, 64);
                const float rinv = rsqrtf(ssum * (1.0f / 64.0f) + 1e-6f);

                float tn[4], val[4];
#pragma unroll
                for (int j = 0; j < 4; ++j) tn[j] = v4[j] * rinv * nwv[j];
#pragma unroll
                for (int j = 0; j < 4; ++j) {
                    const int d = j * 16 + l16;
                    const float rot = (j < 2) ? -tn[j + 2] : tn[j - 2];
                    val[j] = (tn[j] * cosp[n * HD + d] + rot * sinp[n * HD + d]) * oscale;
                }

                if (isQ) {
                    const size_t qrow =
                        ((size_t)((bI << 4) + (n0 >> 6)) * N_SEQ + n) * HD;
#pragma unroll
                    for (int j = 0; j < 4; ++j)
                        Qb[qrow + j * 16 + l16] = f2bf(val[j]);
                } else {
                    const int kvh = (n0 >> 6) - 16;
                    const int kt = n >> 6, rr = n & 63;
                    const int ss2 = rr >> 5, l32k = rr & 31;
                    const size_t kb =
                        ((size_t)(bI * NKV + kvh) * 32 + kt) * 4096 + l32k * 16 + l16;
#pragma unroll
                    for (int j = 0; j < 4; ++j)
                        Kf[kb + (ss2 * 4 + j) * 512] = f2bf(val[j]);
                }
            }
        }
    } else {
        // ---- V tile: in-block LDS transpose -> fragment-order Vf ----
        // Tile = 128 keys (two 64-key kt chunks) x 64 d (one kv head).
        // Half h: waves 2h,2h+1 own keys [h*64, h*64+64).
        const int kvv = (n0 - 1280) >> 6;
        const int bI = m0 >> 11;          // m-tile never straddles a batch
        const int kt0 = (m0 & (N_SEQ - 1)) >> 6;
        ushort* L = As;                    // reuse: [64][68] = 8704B <= 10240B

        // out-gather coords (uniform per thread across both halves)
        const int c = tid >> 5;            // (s*2+t)*2+d2
        const int l32v = tid & 31;
        const int row0 = (c >> 2) * 32 + ((c >> 1) & 1) * 16;  // s*32+t*16
        const int dcol = (c & 1) * 32 + l32v;                  // d2*32+l32v

#pragma unroll
        for (int h = 0; h < 2; ++h) {
            __syncthreads();               // K-loop / prev-half reads done
            if ((w >> 1) == h) {
                const int kl0 = wm - h * 64;   // 0 or 32 within the half
#pragma unroll
                for (int i = 0; i < 2; ++i)
#pragma unroll
                    for (int r = 0; r < 4; ++r) {
                        const int kl = kl0 + i * 16 + quad * 4 + r;
#pragma unroll
                        for (int j = 0; j < 4; ++j)
                            L[kl * 68 + j * 16 + l16] = f2bf(acc[i][j][r] + bb[j]);
                    }
            }
            __syncthreads();
            short8 o0, o1;
#pragma unroll
            for (int e = 0; e < 8; ++e) o0[e] = (short)L[(row0 + e) * 68 + dcol];
#pragma unroll
            for (int e = 0; e < 8; ++e) o1[e] = (short)L[(row0 + 8 + e) * 68 + dcol];
            const size_t vb = ((size_t)(bI * NKV + kvv) * 32 + kt0 + h) * 4096
                              + c * 512 + l32v * 16;
            *(short8*)&Vf[vb] = o0;
            *(short8*)&Vf[vb + 8] = o1;
        }
    }
}

// ---------------------------------------------------------------------------
// bf16 MFMA GEMM, 128x64 tile (proj). C[m][n] = sum_k A[m][k] W[n][k] + b[n]
// ---------------------------------------------------------------------------
template <bool BF16OUT>
__global__ __launch_bounds__(256) void gemm_mfma_kernel(
    const ushort* __restrict__ A, const ushort* __restrict__ W,
    const float* __restrict__ bias, void* __restrict__ Cout,
    int K, int ldc)
{
    __shared__ ushort As[128 * 40];
    __shared__ ushort Bs[64 * 40];

    const int tid = threadIdx.x;
    const int m0 = blockIdx.y * 128, n0 = blockIdx.x * 64;
    const int w = tid >> 6, lane = tid & 63;
    const int quad = lane >> 4, l16 = lane & 15;
    const int wm = w * 32;

    f32x4 acc[2][4] = {};

    float bb[4];
#pragma unroll
    for (int j = 0; j < 4; ++j) bb[j] = bias[n0 + j * 16 + l16];

    const int r0 = tid >> 2;       // 0..63
    const int c0 = tid & 3;
    const ushort* Ap = A + (size_t)(m0 + r0) * K + c0 * 8;
    const ushort* Wp = W + (size_t)(n0 + r0) * K + c0 * 8;

    for (int k0 = 0; k0 < K; k0 += 32) {
        const short8 a0 = *(const short8*)(Ap + k0);
        const short8 a1 = *(const short8*)(Ap + (size_t)64 * K + k0);
        const short8 b0 = *(const short8*)(Wp + k0);
        __syncthreads();
        *(short8*)&As[r0 * 40 + c0 * 8] = a0;
        *(short8*)&As[(r0 + 64) * 40 + c0 * 8] = a1;
        *(short8*)&Bs[r0 * 40 + c0 * 8] = b0;
        __syncthreads();

        short8 aF[2], bF[4];
#pragma unroll
        for (int i = 0; i < 2; ++i)
            aF[i] = *(const short8*)&As[(wm + i * 16 + l16) * 40 + quad * 8];
#pragma unroll
        for (int j = 0; j < 4; ++j)
            bF[j] = *(const short8*)&Bs[(j * 16 + l16) * 40 + quad * 8];
        __builtin_amdgcn_s_setprio(1);
#pragma unroll
        for (int i = 0; i < 2; ++i)
#pragma unroll
            for (int j = 0; j < 4; ++j)
                acc[i][j] = __builtin_amdgcn_mfma_f32_16x16x32_bf16(
                    aF[i], bF[j], acc[i][j], 0, 0, 0);
        __builtin_amdgcn_s_setprio(0);
    }

#pragma unroll
    for (int i = 0; i < 2; ++i) {
        const int rowb = m0 + wm + i * 16 + quad * 4;
#pragma unroll
        for (int j = 0; j < 4; ++j) {
            const int col = n0 + j * 16 + l16;
#pragma unroll
            for (int r = 0; r < 4; ++r) {
                const float vv = acc[i][j][r] + bb[j];
                if (BF16OUT)
                    ((ushort*)Cout)[(size_t)(rowb + r) * ldc + col] = f2bf(vv);
                else
                    ((float*)Cout)[(size_t)(rowb + r) * ldc + col] = vv;
            }
        }
    }
}

// ---------------------------------------------------------------------------
// Barrier-free S^T-layout MFMA flash attention with in-block k-split.
// Round-0 kernel verbatim (FROZEN).
// ---------------------------------------------------------------------------
__global__ __launch_bounds__(256, 4) void flash_mfma32_kernel(
    const ushort* __restrict__ Qb, const ushort* __restrict__ Kf,
    const ushort* __restrict__ Vf, ushort* __restrict__ Ob)
{
    __shared__ float fsm[4352];            // 2 x (2048 O + 64 m + 64 l) = 17.4KB

    const int qt = blockIdx.x;             // 0..31 (64 q-rows)
    const int bh = blockIdx.y;
    const int b = bh >> 4, h = bh & 15;
    const int kvh = h >> 2;
    const int tid = threadIdx.x;
    const int w = tid >> 6, lane = tid & 63;
    const int l32 = lane & 31, l5 = lane >> 5;
    const int qg = w & 1;                  // q-group within block
    const int kh = w >> 1;                 // k-half

    const ushort* Qg = Qb + ((size_t)bh * N_SEQ + qt * 64 + qg * 32) * HD;
    const size_t kvbase = (size_t)(b * NKV + kvh) * (32 * 4096);
    const ushort* Kp = Kf + kvbase;
    const ushort* Vp = Vf + kvbase;
    const int loff = l32 * 16 + l5 * 8;

    // Q^T B-frags: qF[c][j] = Q[q0+l32][c*16 + l5*8 + j]
    short8 qF[4];
#pragma unroll
    for (int c = 0; c < 4; ++c)
        qF[c] = *(const short8*)&Qg[(size_t)l32 * HD + c * 16 + l5 * 8];

    f32x16 Oa[2] = {};                     // O^T d-tiles (d 0-31, 32-63)
    float mrow = -3.0e38f, lrow = 0.0f;

    for (int i = 0; i < 16; ++i) {
        const int kt = kh * 16 + i;
        const ushort* Kt = Kp + kt * 4096;
        const ushort* Vt = Vp + kt * 4096;

        // direct global->reg fragment loads (coalesced, L2-hit)
        short8 kT[2][4];
#pragma unroll
        for (int s = 0; s < 2; ++s)
#pragma unroll
            for (int c = 0; c < 4; ++c)
                kT[s][c] = *(const short8*)&Kt[(s * 4 + c) * 512 + loff];
        short8 vT[2][2][2];
#pragma unroll
        for (int s = 0; s < 2; ++s)
#pragma unroll
            for (int t = 0; t < 2; ++t)
#pragma unroll
                for (int d2 = 0; d2 < 2; ++d2)
                    vT[s][t][d2] = *(const short8*)&Vt[((s * 2 + t) * 2 + d2) * 512 + loff];

        // S^T (32 keys x 32 q-rows) per key-subtile s
        f32x16 Sv[2] = {};
#pragma unroll
        for (int s = 0; s < 2; ++s)
#pragma unroll
            for (int c = 0; c < 4; ++c)
                Sv[s] = __builtin_amdgcn_mfma_f32_32x32x16_bf16(kT[s][c], qF[c], Sv[s], 0, 0, 0);

        // online softmax (keys in-lane + 1 partner shuffle)
        float mx = -3.0e38f;
#pragma unroll
        for (int s = 0; s < 2; ++s)
#pragma unroll
            for (int r = 0; r < 16; ++r) mx = fmaxf(mx, Sv[s][r]);
        mx = fmaxf(mx, __shfl_xor(mx, 32, 64));
        const float mnew = fmaxf(mrow, mx);
        const float alpha = __expf(mrow - mnew);
        mrow = mnew;
        float rs = 0.0f;
#pragma unroll
        for (int s = 0; s < 2; ++s)
#pragma unroll
            for (int r = 0; r < 16; ++r) {
                Sv[s][r] = __expf(Sv[s][r] - mnew);
                rs += Sv[s][r];
            }
        rs += __shfl_xor(rs, 32, 64);
        lrow = lrow * alpha + rs;
#pragma unroll
        for (int t = 0; t < 2; ++t)
#pragma unroll
            for (int r = 0; r < 16; ++r) Oa[t][r] *= alpha;

        // pack P pairs: P2[s][2g+hh] = keys 8g+4*l5+2hh+{0,1} of subtile s
        uint P2[2][8];
#pragma unroll
        for (int s = 0; s < 2; ++s)
#pragma unroll
            for (int g = 0; g < 4; ++g)
#pragma unroll
                for (int hh = 0; hh < 2; ++hh)
                    P2[s][g * 2 + hh] =
                        pack2bf(Sv[s][4 * g + 2 * hh], Sv[s][4 * g + 2 * hh + 1]);

        // P^T B-frags in-register + PV mfma
#pragma unroll
        for (int s = 0; s < 2; ++s)
#pragma unroll
            for (int t = 0; t < 2; ++t) {
                const uint snd0 = l5 ? P2[s][4 * t + 0] : P2[s][4 * t + 2];
                const uint snd1 = l5 ? P2[s][4 * t + 1] : P2[s][4 * t + 3];
                const uint kp0  = l5 ? P2[s][4 * t + 2] : P2[s][4 * t + 0];
                const uint kp1  = l5 ? P2[s][4 * t + 3] : P2[s][4 * t + 1];
                const uint rcv0 = __shfl_xor(snd0, 32, 64);
                const uint rcv1 = __shfl_xor(snd1, 32, 64);
                union { uint u[4]; short8 s8; } pb;
                pb.u[0] = l5 ? rcv0 : kp0;
                pb.u[1] = l5 ? rcv1 : kp1;
                pb.u[2] = l5 ? kp0 : rcv0;
                pb.u[3] = l5 ? kp1 : rcv1;
#pragma unroll
                for (int d2 = 0; d2 < 2; ++d2)
                    Oa[d2] = __builtin_amdgcn_mfma_f32_32x32x16_bf16(
                        vT[s][t][d2], pb.s8, Oa[d2], 0, 0, 0);
            }
    }

    // ---- merge the two k-halves (wave pairs w, w+2 share q-rows) ----
    float* buf = fsm + qg * 2176;
    if (kh == 1) {
#pragma unroll
        for (int d2 = 0; d2 < 2; ++d2)
#pragma unroll
            for (int r = 0; r < 16; ++r)
                buf[(d2 * 16 + r) * 64 + lane] = Oa[d2][r];
        buf[2048 + lane] = mrow;
        buf[2112 + lane] = lrow;
    }
    __syncthreads();

    if (kh == 0) {
        const float mb = buf[2048 + lane];
        const float lb = buf[2112 + lane];
        const float M = fmaxf(mrow, mb);
        const float ea = __expf(mrow - M), eb = __expf(mb - M);
        lrow = lrow * ea + lb * eb;
#pragma unroll
        for (int d2 = 0; d2 < 2; ++d2)
#pragma unroll
            for (int r = 0; r < 16; ++r)
                Oa[d2][r] = Oa[d2][r] * ea + buf[(d2 * 16 + r) * 64 + lane] * eb;
    }
    __syncthreads();                        // merge reads done before Os reuse

    // ---- epilogue: normalize + transpose to row-major via LDS ----
    ushort* Os = (ushort*)fsm;              // [64][68]
    if (kh == 0) {
        const float inv = 1.0f / lrow;
#pragma unroll
        for (int d2 = 0; d2 < 2; ++d2)
#pragma unroll
            for (int r = 0; r < 16; ++r) {
                const int d = d2 * 32 + (r & 3) + 8 * (r >> 2) + 4 * l5;
                Os[(qg * 32 + l32) * 68 + d] = f2bf(Oa[d2][r] * inv);
            }
    }
    __syncthreads();

    const int row = tid >> 2, cc = (tid & 3) * 16;
#pragma unroll
    for (int i = 0; i < 2; ++i) {
        const short8 v = *(const short8*)&Os[row * 68 + cc + i * 8];
        *(short8*)&Ob[((size_t)b * N_SEQ + qt * 64 + row) * EMB + h * HD + cc + i * 8] = v;
    }
}

// ---------------------------------------------------------------------------
extern "C" void kernel_launch(void* const* d_in, const int* in_sizes, int n_in,
                              void* d_out, int out_size, void* d_ws, size_t ws_size,
                              hipStream_t stream)
{
    const float* x      = (const float*)d_in[0];
    const float* sinp   = (const float*)d_in[1];
    const float* cosp   = (const float*)d_in[2];
    const float* wq_w   = (const float*)d_in[3];
    const float* wq_b   = (const float*)d_in[4];
    const float* wk_w   = (const float*)d_in[5];
    const float* wk_b   = (const float*)d_in[6];
    const float* wv_w   = (const float*)d_in[7];
    const float* wv_b   = (const float*)d_in[8];
    const float* qn_w   = (const float*)d_in[9];
    const float* kn_w   = (const float*)d_in[10];
    const float* proj_w = (const float*)d_in[11];
    const float* proj_b = (const float*)d_in[12];
    float* out = (float*)d_out;

    // workspace layout (ushort elements) — Tq slot retained but unused
    ushort* Tq    = (ushort*)d_ws;            // (unused after r12 fusion)
    ushort* xb    = Tq + 6291456;             // 4096*1024 (reused as Ob)
    ushort* Wqkv  = xb + 4194304;             // 1536*1024
    ushort* Wproj = Wqkv + 1572864;           // 1024*1024
    float*  bqkv  = (float*)(Wproj + 1048576);// 1536
    ushort* Qb    = (ushort*)(bqkv + 1536);   // 2*16*2048*64
    ushort* Kf    = Qb + 4194304;             // frag-order K, 1048576
    ushort* Vf    = Kf + 1048576;             // frag-order V^T, 1048576

    prep_kernel<<<6658, 256, 0, stream>>>(x, wq_w, wk_w, wv_w, proj_w,
                                          wq_b, wk_b, wv_b,
                                          xb, Wqkv, Wproj, bqkv);

    gemm_qkv_fused<<<dim3(QKV_N / 64, M_TOT / 128), 256, 0, stream>>>(
        xb, Wqkv, bqkv, qn_w, kn_w, sinp, cosp, Qb, Kf, Vf);

    flash_mfma32_kernel<<<dim3(32, 32), 256, 0, stream>>>(Qb, Kf, Vf, xb);

    gemm_mfma_kernel<false><<<dim3(EMB / 64, M_TOT / 128), 256, 0, stream>>>(
        xb, Wproj, proj_b, out, EMB, EMB);
}

// Round 8
// 204.450 us; speedup vs baseline: 3.7350x; 1.0078x over previous
//
#include <hip/hip_runtime.h>
#include <hip/hip_bf16.h>
#include <math.h>

// GQA forward, round 13: global_load_lds staging for both GEMMs.
//  - GEMM K-loop: reg->LDS staging replaced by 3x global_load_lds width=16
//    (m97 ladder step, +69% measured on 128-tile GEMM; correctness of this
//    staging proven in r1). Linear LDS [row][32] (64B rows), wave-uniform
//    dest + lane*16; fragment reads at stride 32 (bank conflicts accepted,
//    m97 precedent). Same 2-barrier loop, same 128x64 tile, same epilogues.
//  - qkv_fused keeps RMSNorm+RoPE (r11) and V-transpose (r12) epilogues;
//    As/Bs now views into one 6144-short block so the V LDS scratch fits.
//  - flash (r0 verbatim, FROZEN) and prep unchanged.

#define N_SEQ 2048
#define EMB   1024
#define NH    16
#define NKV   4
#define HD    64
#define BATCH 2
#define M_TOT 4096
#define QKV_N 1536

typedef __attribute__((ext_vector_type(8)))  short short8;   // 8 bf16
typedef __attribute__((ext_vector_type(4)))  float f32x4;
typedef __attribute__((ext_vector_type(16))) float f32x16;

__device__ __forceinline__ ushort f2bf(float f) {
    union { __hip_bfloat16 h; ushort u; } cv;
    cv.h = __float2bfloat16(f);
    return cv.u;
}
__device__ __forceinline__ float bf2f(ushort u) {
    union { __hip_bfloat16 h; ushort u; } cv;
    cv.u = u;
    return __bfloat162float(cv.h);
}
__device__ __forceinline__ uint pack2bf(float a, float b) {
    union { __hip_bfloat162 h; uint u; } cv;
    cv.h = __float22bfloat162_rn(float2{a, b});   // a -> low 16, b -> high 16
    return cv.u;
}

// async global->LDS, 16B per lane. LDS base must be wave-uniform; HW writes
// base + lane*16; global address is per-lane. (proven in r1)
__device__ __forceinline__ void g2lds16(const ushort* g, ushort* l) {
    __builtin_amdgcn_global_load_lds(
        (const __attribute__((address_space(1))) unsigned int*)g,
        (__attribute__((address_space(3))) unsigned int*)l, 16, 0, 0);
}

// ---------------------------------------------------------------------------
// Fused prep (unchanged)
// ---------------------------------------------------------------------------
__device__ __forceinline__ void cvt4(const float* __restrict__ s,
                                     ushort* __restrict__ d, long g, long gd) {
    const float4 v = ((const float4*)s)[g];
    ushort4 o;
    o.x = f2bf(v.x); o.y = f2bf(v.y); o.z = f2bf(v.z); o.w = f2bf(v.w);
    ((ushort4*)d)[gd] = o;
}

__global__ __launch_bounds__(256) void prep_kernel(
    const float* __restrict__ x,  const float* __restrict__ wq,
    const float* __restrict__ wk, const float* __restrict__ wv,
    const float* __restrict__ wp, const float* __restrict__ bq,
    const float* __restrict__ bk, const float* __restrict__ bv,
    ushort* __restrict__ xb, ushort* __restrict__ Wqkv,
    ushort* __restrict__ Wproj, float* __restrict__ bqkv)
{
    const long i = (long)blockIdx.x * 256 + threadIdx.x;
    if (i < 1048576) {
        cvt4(x, xb, i, i);
    } else if (i < 1310720) {
        const long g = i - 1048576;
        cvt4(wq, Wqkv, g, g);
    } else if (i < 1376256) {
        const long g = i - 1310720;
        cvt4(wk, Wqkv, g, 262144 + g);
    } else if (i < 1441792) {
        const long g = i - 1376256;
        cvt4(wv, Wqkv, g, 327680 + g);
    } else if (i < 1703936) {
        const long g = i - 1441792;
        cvt4(wp, Wproj, g, g);
    } else if (i < 1704320) {
        const long j = i - 1703936;
        float4 v;
        if (j < 256)      v = ((const float4*)bq)[j];
        else if (j < 320) v = ((const float4*)bk)[j - 256];
        else              v = ((const float4*)bv)[j - 320];
        ((float4*)bqkv)[j] = v;
    }
}

// ---------------------------------------------------------------------------
// QKV GEMM + fused epilogues. 128x64 tile, 4 waves, gload_lds staging.
// n0 <  1024 : Q head (n0>>6)      -> Qb row-major, scale 0.125 (RMSNorm+RoPE)
// n0 in [1024,1280): K kv-head     -> Kf fragment order (RMSNorm+RoPE)
// n0 >= 1280 : V kv-head           -> Vf fragment order (LDS transpose)
// ---------------------------------------------------------------------------
__global__ __launch_bounds__(256) void gemm_qkv_fused(
    const ushort* __restrict__ A, const ushort* __restrict__ W,
    const float* __restrict__ bias,
    const float* __restrict__ qn_w, const float* __restrict__ kn_w,
    const float* __restrict__ sinp, const float* __restrict__ cosp,
    ushort* __restrict__ Qb, ushort* __restrict__ Kf,
    ushort* __restrict__ Vf)
{
    __shared__ ushort SMEM[6144];          // As[128*32] + Bs[64*32]; V scratch
    ushort* As = SMEM;                     // [128][32], 64B rows
    ushort* Bs = SMEM + 4096;              // [64][32]

    const int tid = threadIdx.x;
    const int m0 = blockIdx.y * 128, n0 = blockIdx.x * 64;
    const int w = tid >> 6, lane = tid & 63;
    const int quad = lane >> 4, l16 = lane & 15;
    const int wm = w * 32;
    const int K = EMB;

    f32x4 acc[2][4] = {};

    float bb[4];
#pragma unroll
    for (int j = 0; j < 4; ++j) bb[j] = bias[n0 + j * 16 + l16];

    // staging map: thread covers global row r0 = tid>>2, 16B chunk tid&3;
    // LDS dest = base + lane*16B (wave-uniform base = w*512 shorts).
    const int r0 = tid >> 2;       // 0..63
    const int c8 = (tid & 3) * 8;
    const ushort* Ap = A + (size_t)(m0 + r0) * K + c8;
    const ushort* Wp = W + (size_t)(n0 + r0) * K + c8;
    ushort* AsW = As + w * 512;
    ushort* BsW = Bs + w * 512;

    for (int k0 = 0; k0 < K; k0 += 32) {
        __syncthreads();                   // prev tile's ds_reads done
        g2lds16(Ap + k0, AsW);
        g2lds16(Ap + (size_t)64 * K + k0, AsW + 2048);
        g2lds16(Wp + k0, BsW);
        __syncthreads();                   // vmcnt(0) drain -> LDS visible

        short8 aF[2], bF[4];
#pragma unroll
        for (int i = 0; i < 2; ++i)
            aF[i] = *(const short8*)&As[(wm + i * 16 + l16) * 32 + quad * 8];
#pragma unroll
        for (int j = 0; j < 4; ++j)
            bF[j] = *(const short8*)&Bs[(j * 16 + l16) * 32 + quad * 8];
        __builtin_amdgcn_s_setprio(1);
#pragma unroll
        for (int i = 0; i < 2; ++i)
#pragma unroll
            for (int j = 0; j < 4; ++j)
                acc[i][j] = __builtin_amdgcn_mfma_f32_16x16x32_bf16(
                    aF[i], bF[j], acc[i][j], 0, 0, 0);
        __builtin_amdgcn_s_setprio(0);
    }

    if (n0 < 1280) {
        // ---- fused RMSNorm + RoPE epilogue (Q or K head tile) ----
        const bool isQ = (n0 < 1024);
        const float* nw = isQ ? qn_w : kn_w;
        const float oscale = isQ ? 0.125f : 1.0f;
        float nwv[4];
#pragma unroll
        for (int j = 0; j < 4; ++j) nwv[j] = nw[j * 16 + l16];

#pragma unroll
        for (int i = 0; i < 2; ++i) {
#pragma unroll
            for (int r = 0; r < 4; ++r) {
                const int m = m0 + wm + i * 16 + quad * 4 + r;
                const int n = m & (N_SEQ - 1);
                const int bI = m >> 11;

                float v4[4];
                float ssum = 0.0f;
#pragma unroll
                for (int j = 0; j < 4; ++j) {
                    v4[j] = acc[i][j][r] + bb[j];
                    ssum += v4[j] * v4[j];
                }
                // quad-level reduce (16 lanes share this row)
                ssum += __shfl_xor(ssum, 1, 64);
                ssum += __shfl_xor(ssum, 2, 64);
                ssum += __shfl_xor(ssum, 4, 64);
                ssum += __shfl_xor(ssum, 8, 64);
                const float rinv = rsqrtf(ssum * (1.0f / 64.0f) + 1e-6f);

                float tn[4], val[4];
#pragma unroll
                for (int j = 0; j < 4; ++j) tn[j] = v4[j] * rinv * nwv[j];
#pragma unroll
                for (int j = 0; j < 4; ++j) {
                    const int d = j * 16 + l16;
                    const float rot = (j < 2) ? -tn[j + 2] : tn[j - 2];
                    val[j] = (tn[j] * cosp[n * HD + d] + rot * sinp[n * HD + d]) * oscale;
                }

                if (isQ) {
                    const size_t qrow =
                        ((size_t)((bI << 4) + (n0 >> 6)) * N_SEQ + n) * HD;
#pragma unroll
                    for (int j = 0; j < 4; ++j)
                        Qb[qrow + j * 16 + l16] = f2bf(val[j]);
                } else {
                    const int kvh = (n0 >> 6) - 16;
                    const int kt = n >> 6, rr = n & 63;
                    const int ss2 = rr >> 5, l32k = rr & 31;
                    const size_t kb =
                        ((size_t)(bI * NKV + kvh) * 32 + kt) * 4096 + l32k * 16 + l16;
#pragma unroll
                    for (int j = 0; j < 4; ++j)
                        Kf[kb + (ss2 * 4 + j) * 512] = f2bf(val[j]);
                }
            }
        }
    } else {
        // ---- V tile: in-block LDS transpose -> fragment-order Vf ----
        const int kvv = (n0 - 1280) >> 6;
        const int bI = m0 >> 11;          // m-tile never straddles a batch
        const int kt0 = (m0 & (N_SEQ - 1)) >> 6;
        ushort* L = SMEM;                  // [64][68] = 4352 shorts <= 6144

        const int c = tid >> 5;            // (s*2+t)*2+d2
        const int l32v = tid & 31;
        const int row0 = (c >> 2) * 32 + ((c >> 1) & 1) * 16;  // s*32+t*16
        const int dcol = (c & 1) * 32 + l32v;                  // d2*32+l32v

#pragma unroll
        for (int h = 0; h < 2; ++h) {
            __syncthreads();               // K-loop / prev-half reads done
            if ((w >> 1) == h) {
                const int kl0 = wm - h * 64;   // 0 or 32 within the half
#pragma unroll
                for (int i = 0; i < 2; ++i)
#pragma unroll
                    for (int r = 0; r < 4; ++r) {
                        const int kl = kl0 + i * 16 + quad * 4 + r;
#pragma unroll
                        for (int j = 0; j < 4; ++j)
                            L[kl * 68 + j * 16 + l16] = f2bf(acc[i][j][r] + bb[j]);
                    }
            }
            __syncthreads();
            short8 o0, o1;
#pragma unroll
            for (int e = 0; e < 8; ++e) o0[e] = (short)L[(row0 + e) * 68 + dcol];
#pragma unroll
            for (int e = 0; e < 8; ++e) o1[e] = (short)L[(row0 + 8 + e) * 68 + dcol];
            const size_t vb = ((size_t)(bI * NKV + kvv) * 32 + kt0 + h) * 4096
                              + c * 512 + l32v * 16;
            *(short8*)&Vf[vb] = o0;
            *(short8*)&Vf[vb + 8] = o1;
        }
    }
}

// ---------------------------------------------------------------------------
// bf16 MFMA GEMM, 128x64 tile (proj), gload_lds staging.
// C[m][n] = sum_k A[m][k] W[n][k] + b[n]
// ---------------------------------------------------------------------------
template <bool BF16OUT>
__global__ __launch_bounds__(256) void gemm_mfma_kernel(
    const ushort* __restrict__ A, const ushort* __restrict__ W,
    const float* __restrict__ bias, void* __restrict__ Cout,
    int K, int ldc)
{
    __shared__ ushort As[128 * 32];
    __shared__ ushort Bs[64 * 32];

    const int tid = threadIdx.x;
    const int m0 = blockIdx.y * 128, n0 = blockIdx.x * 64;
    const int w = tid >> 6, lane = tid & 63;
    const int quad = lane >> 4, l16 = lane & 15;
    const int wm = w * 32;

    f32x4 acc[2][4] = {};

    float bb[4];
#pragma unroll
    for (int j = 0; j < 4; ++j) bb[j] = bias[n0 + j * 16 + l16];

    const int r0 = tid >> 2;       // 0..63
    const int c8 = (tid & 3) * 8;
    const ushort* Ap = A + (size_t)(m0 + r0) * K + c8;
    const ushort* Wp = W + (size_t)(n0 + r0) * K + c8;
    ushort* AsW = As + w * 512;
    ushort* BsW = Bs + w * 512;

    for (int k0 = 0; k0 < K; k0 += 32) {
        __syncthreads();                   // prev tile's ds_reads done
        g2lds16(Ap + k0, AsW);
        g2lds16(Ap + (size_t)64 * K + k0, AsW + 2048);
        g2lds16(Wp + k0, BsW);
        __syncthreads();                   // vmcnt(0) drain -> LDS visible

        short8 aF[2], bF[4];
#pragma unroll
        for (int i = 0; i < 2; ++i)
            aF[i] = *(const short8*)&As[(wm + i * 16 + l16) * 32 + quad * 8];
#pragma unroll
        for (int j = 0; j < 4; ++j)
            bF[j] = *(const short8*)&Bs[(j * 16 + l16) * 32 + quad * 8];
        __builtin_amdgcn_s_setprio(1);
#pragma unroll
        for (int i = 0; i < 2; ++i)
#pragma unroll
            for (int j = 0; j < 4; ++j)
                acc[i][j] = __builtin_amdgcn_mfma_f32_16x16x32_bf16(
                    aF[i], bF[j], acc[i][j], 0, 0, 0);
        __builtin_amdgcn_s_setprio(0);
    }

#pragma unroll
    for (int i = 0; i < 2; ++i) {
        const int rowb = m0 + wm + i * 16 + quad * 4;
#pragma unroll
        for (int j = 0; j < 4; ++j) {
            const int col = n0 + j * 16 + l16;
#pragma unroll
            for (int r = 0; r < 4; ++r) {
                const float vv = acc[i][j][r] + bb[j];
                if (BF16OUT)
                    ((ushort*)Cout)[(size_t)(rowb + r) * ldc + col] = f2bf(vv);
                else
                    ((float*)Cout)[(size_t)(rowb + r) * ldc + col] = vv;
            }
        }
    }
}

// ---------------------------------------------------------------------------
// Barrier-free S^T-layout MFMA flash attention with in-block k-split.
// Round-0 kernel verbatim (FROZEN).
// ---------------------------------------------------------------------------
__global__ __launch_bounds__(256, 4) void flash_mfma32_kernel(
    const ushort* __restrict__ Qb, const ushort* __restrict__ Kf,
    const ushort* __restrict__ Vf, ushort* __restrict__ Ob)
{
    __shared__ float fsm[4352];            // 2 x (2048 O + 64 m + 64 l) = 17.4KB

    const int qt = blockIdx.x;             // 0..31 (64 q-rows)
    const int bh = blockIdx.y;
    const int b = bh >> 4, h = bh & 15;
    const int kvh = h >> 2;
    const int tid = threadIdx.x;
    const int w = tid >> 6, lane = tid & 63;
    const int l32 = lane & 31, l5 = lane >> 5;
    const int qg = w & 1;                  // q-group within block
    const int kh = w >> 1;                 // k-half

    const ushort* Qg = Qb + ((size_t)bh * N_SEQ + qt * 64 + qg * 32) * HD;
    const size_t kvbase = (size_t)(b * NKV + kvh) * (32 * 4096);
    const ushort* Kp = Kf + kvbase;
    const ushort* Vp = Vf + kvbase;
    const int loff = l32 * 16 + l5 * 8;

    // Q^T B-frags: qF[c][j] = Q[q0+l32][c*16 + l5*8 + j]
    short8 qF[4];
#pragma unroll
    for (int c = 0; c < 4; ++c)
        qF[c] = *(const short8*)&Qg[(size_t)l32 * HD + c * 16 + l5 * 8];

    f32x16 Oa[2] = {};                     // O^T d-tiles (d 0-31, 32-63)
    float mrow = -3.0e38f, lrow = 0.0f;

    for (int i = 0; i < 16; ++i) {
        const int kt = kh * 16 + i;
        const ushort* Kt = Kp + kt * 4096;
        const ushort* Vt = Vp + kt * 4096;

        // direct global->reg fragment loads (coalesced, L2-hit)
        short8 kT[2][4];
#pragma unroll
        for (int s = 0; s < 2; ++s)
#pragma unroll
            for (int c = 0; c < 4; ++c)
                kT[s][c] = *(const short8*)&Kt[(s * 4 + c) * 512 + loff];
        short8 vT[2][2][2];
#pragma unroll
        for (int s = 0; s < 2; ++s)
#pragma unroll
            for (int t = 0; t < 2; ++t)
#pragma unroll
                for (int d2 = 0; d2 < 2; ++d2)
                    vT[s][t][d2] = *(const short8*)&Vt[((s * 2 + t) * 2 + d2) * 512 + loff];

        // S^T (32 keys x 32 q-rows) per key-subtile s
        f32x16 Sv[2] = {};
#pragma unroll
        for (int s = 0; s < 2; ++s)
#pragma unroll
            for (int c = 0; c < 4; ++c)
                Sv[s] = __builtin_amdgcn_mfma_f32_32x32x16_bf16(kT[s][c], qF[c], Sv[s], 0, 0, 0);

        // online softmax (keys in-lane + 1 partner shuffle)
        float mx = -3.0e38f;
#pragma unroll
        for (int s = 0; s < 2; ++s)
#pragma unroll
            for (int r = 0; r < 16; ++r) mx = fmaxf(mx, Sv[s][r]);
        mx = fmaxf(mx, __shfl_xor(mx, 32, 64));
        const float mnew = fmaxf(mrow, mx);
        const float alpha = __expf(mrow - mnew);
        mrow = mnew;
        float rs = 0.0f;
#pragma unroll
        for (int s = 0; s < 2; ++s)
#pragma unroll
            for (int r = 0; r < 16; ++r) {
                Sv[s][r] = __expf(Sv[s][r] - mnew);
                rs += Sv[s][r];
            }
        rs += __shfl_xor(rs, 32, 64);
        lrow = lrow * alpha + rs;
#pragma unroll
        for (int t = 0; t < 2; ++t)
#pragma unroll
            for (int r = 0; r < 16; ++r) Oa[t][r] *= alpha;

        // pack P pairs: P2[s][2g+hh] = keys 8g+4*l5+2hh+{0,1} of subtile s
        uint P2[2][8];
#pragma unroll
        for (int s = 0; s < 2; ++s)
#pragma unroll
            for (int g = 0; g < 4; ++g)
#pragma unroll
                for (int hh = 0; hh < 2; ++hh)
                    P2[s][g * 2 + hh] =
                        pack2bf(Sv[s][4 * g + 2 * hh], Sv[s][4 * g + 2 * hh + 1]);

        // P^T B-frags in-register + PV mfma
#pragma unroll
        for (int s = 0; s < 2; ++s)
#pragma unroll
            for (int t = 0; t < 2; ++t) {
                const uint snd0 = l5 ? P2[s][4 * t + 0] : P2[s][4 * t + 2];
                const uint snd1 = l5 ? P2[s][4 * t + 1] : P2[s][4 * t + 3];
                const uint kp0  = l5 ? P2[s][4 * t + 2] : P2[s][4 * t + 0];
                const uint kp1  = l5 ? P2[s][4 * t + 3] : P2[s][4 * t + 1];
                const uint rcv0 = __shfl_xor(snd0, 32, 64);
                const uint rcv1 = __shfl_xor(snd1, 32, 64);
                union { uint u[4]; short8 s8; } pb;
                pb.u[0] = l5 ? rcv0 : kp0;
                pb.u[1] = l5 ? rcv1 : kp1;
                pb.u[2] = l5 ? kp0 : rcv0;
                pb.u[3] = l5 ? kp1 : rcv1;
#pragma unroll
                for (int d2 = 0; d2 < 2; ++d2)
                    Oa[d2] = __builtin_amdgcn_mfma_f32_32x32x16_bf16(
                        vT[s][t][d2], pb.s8, Oa[d2], 0, 0, 0);
            }
    }

    // ---- merge the two k-halves (wave pairs w, w+2 share q-rows) ----
    float* buf = fsm + qg * 2176;
    if (kh == 1) {
#pragma unroll
        for (int d2 = 0; d2 < 2; ++d2)
#pragma unroll
            for (int r = 0; r < 16; ++r)
                buf[(d2 * 16 + r) * 64 + lane] = Oa[d2][r];
        buf[2048 + lane] = mrow;
        buf[2112 + lane] = lrow;
    }
    __syncthreads();

    if (kh == 0) {
        const float mb = buf[2048 + lane];
        const float lb = buf[2112 + lane];
        const float M = fmaxf(mrow, mb);
        const float ea = __expf(mrow - M), eb = __expf(mb - M);
        lrow = lrow * ea + lb * eb;
#pragma unroll
        for (int d2 = 0; d2 < 2; ++d2)
#pragma unroll
            for (int r = 0; r < 16; ++r)
                Oa[d2][r] = Oa[d2][r] * ea + buf[(d2 * 16 + r) * 64 + lane] * eb;
    }
    __syncthreads();                        // merge reads done before Os reuse

    // ---- epilogue: normalize + transpose to row-major via LDS ----
    ushort* Os = (ushort*)fsm;              // [64][68]
    if (kh == 0) {
        const float inv = 1.0f / lrow;
#pragma unroll
        for (int d2 = 0; d2 < 2; ++d2)
#pragma unroll
            for (int r = 0; r < 16; ++r) {
                const int d = d2 * 32 + (r & 3) + 8 * (r >> 2) + 4 * l5;
                Os[(qg * 32 + l32) * 68 + d] = f2bf(Oa[d2][r] * inv);
            }
    }
    __syncthreads();

    const int row = tid >> 2, cc = (tid & 3) * 16;
#pragma unroll
    for (int i = 0; i < 2; ++i) {
        const short8 v = *(const short8*)&Os[row * 68 + cc + i * 8];
        *(short8*)&Ob[((size_t)b * N_SEQ + qt * 64 + row) * EMB + h * HD + cc + i * 8] = v;
    }
}

// ---------------------------------------------------------------------------
extern "C" void kernel_launch(void* const* d_in, const int* in_sizes, int n_in,
                              void* d_out, int out_size, void* d_ws, size_t ws_size,
                              hipStream_t stream)
{
    const float* x      = (const float*)d_in[0];
    const float* sinp   = (const float*)d_in[1];
    const float* cosp   = (const float*)d_in[2];
    const float* wq_w   = (const float*)d_in[3];
    const float* wq_b   = (const float*)d_in[4];
    const float* wk_w   = (const float*)d_in[5];
    const float* wk_b   = (const float*)d_in[6];
    const float* wv_w   = (const float*)d_in[7];
    const float* wv_b   = (const float*)d_in[8];
    const float* qn_w   = (const float*)d_in[9];
    const float* kn_w   = (const float*)d_in[10];
    const float* proj_w = (const float*)d_in[11];
    const float* proj_b = (const float*)d_in[12];
    float* out = (float*)d_out;

    // workspace layout (ushort elements) — Tq slot retained but unused
    ushort* Tq    = (ushort*)d_ws;            // (unused after r12 fusion)
    ushort* xb    = Tq + 6291456;             // 4096*1024 (reused as Ob)
    ushort* Wqkv  = xb + 4194304;             // 1536*1024
    ushort* Wproj = Wqkv + 1572864;           // 1024*1024
    float*  bqkv  = (float*)(Wproj + 1048576);// 1536
    ushort* Qb    = (ushort*)(bqkv + 1536);   // 2*16*2048*64
    ushort* Kf    = Qb + 4194304;             // frag-order K, 1048576
    ushort* Vf    = Kf + 1048576;             // frag-order V^T, 1048576

    prep_kernel<<<6658, 256, 0, stream>>>(x, wq_w, wk_w, wv_w, proj_w,
                                          wq_b, wk_b, wv_b,
                                          xb, Wqkv, Wproj, bqkv);

    gemm_qkv_fused<<<dim3(QKV_N / 64, M_TOT / 128), 256, 0, stream>>>(
        xb, Wqkv, bqkv, qn_w, kn_w, sinp, cosp, Qb, Kf, Vf);

    flash_mfma32_kernel<<<dim3(32, 32), 256, 0, stream>>>(Qb, Kf, Vf, xb);

    gemm_mfma_kernel<false><<<dim3(EMB / 64, M_TOT / 128), 256, 0, stream>>>(
        xb, Wproj, proj_b, out, EMB, EMB);
}

// Round 9
// 199.184 us; speedup vs baseline: 3.8337x; 1.0264x over previous
//
#include <hip/hip_runtime.h>
#include <hip/hip_bf16.h>
#include <math.h>

// GQA forward, round 14: 2-phase double-buffered GEMM pipeline (T3 minimum).
//  - r13 verdict: gload_lds staging neutral => GEMMs latency/barrier-bound.
//    Fix: double-buffer LDS, STAGE(t+1) issued BEFORE compute(t), ONE
//    barrier per K-slice (64 -> 32 barriers); load latency hidden under
//    6 ds_read + 8 MFMA. Compute phase byte-identical to r13.
//  - flash (r0 verbatim, FROZEN), prep, all epilogues unchanged.

#define N_SEQ 2048
#define EMB   1024
#define NH    16
#define NKV   4
#define HD    64
#define BATCH 2
#define M_TOT 4096
#define QKV_N 1536

typedef __attribute__((ext_vector_type(8)))  short short8;   // 8 bf16
typedef __attribute__((ext_vector_type(4)))  float f32x4;
typedef __attribute__((ext_vector_type(16))) float f32x16;

__device__ __forceinline__ ushort f2bf(float f) {
    union { __hip_bfloat16 h; ushort u; } cv;
    cv.h = __float2bfloat16(f);
    return cv.u;
}
__device__ __forceinline__ float bf2f(ushort u) {
    union { __hip_bfloat16 h; ushort u; } cv;
    cv.u = u;
    return __bfloat162float(cv.h);
}
__device__ __forceinline__ uint pack2bf(float a, float b) {
    union { __hip_bfloat162 h; uint u; } cv;
    cv.h = __float22bfloat162_rn(float2{a, b});   // a -> low 16, b -> high 16
    return cv.u;
}

// async global->LDS, 16B per lane. LDS base must be wave-uniform; HW writes
// base + lane*16; global address is per-lane.
__device__ __forceinline__ void g2lds16(const ushort* g, ushort* l) {
    __builtin_amdgcn_global_load_lds(
        (const __attribute__((address_space(1))) unsigned int*)g,
        (__attribute__((address_space(3))) unsigned int*)l, 16, 0, 0);
}

// stage one 32-wide K-slice (A 128 rows, W 64 rows) into a buffer
__device__ __forceinline__ void stage3(const ushort* Ap, const ushort* Wp,
                                       int K, ushort* AsW, ushort* BsW, int kk)
{
    g2lds16(Ap + kk, AsW);
    g2lds16(Ap + (size_t)64 * K + kk, AsW + 2048);
    g2lds16(Wp + kk, BsW);
}

// one 32-wide K-slice of MFMA from a buffer (identical to r13 compute)
__device__ __forceinline__ void mfma_phase(const ushort* __restrict__ Asb,
                                           const ushort* __restrict__ Bsb,
                                           int wm, int l16, int quad,
                                           f32x4 (&acc)[2][4])
{
    short8 aF[2], bF[4];
#pragma unroll
    for (int i = 0; i < 2; ++i)
        aF[i] = *(const short8*)&Asb[(wm + i * 16 + l16) * 32 + quad * 8];
#pragma unroll
    for (int j = 0; j < 4; ++j)
        bF[j] = *(const short8*)&Bsb[(j * 16 + l16) * 32 + quad * 8];
    __builtin_amdgcn_s_setprio(1);
#pragma unroll
    for (int i = 0; i < 2; ++i)
#pragma unroll
        for (int j = 0; j < 4; ++j)
            acc[i][j] = __builtin_amdgcn_mfma_f32_16x16x32_bf16(
                aF[i], bF[j], acc[i][j], 0, 0, 0);
    __builtin_amdgcn_s_setprio(0);
}

// ---------------------------------------------------------------------------
// Fused prep (unchanged)
// ---------------------------------------------------------------------------
__device__ __forceinline__ void cvt4(const float* __restrict__ s,
                                     ushort* __restrict__ d, long g, long gd) {
    const float4 v = ((const float4*)s)[g];
    ushort4 o;
    o.x = f2bf(v.x); o.y = f2bf(v.y); o.z = f2bf(v.z); o.w = f2bf(v.w);
    ((ushort4*)d)[gd] = o;
}

__global__ __launch_bounds__(256) void prep_kernel(
    const float* __restrict__ x,  const float* __restrict__ wq,
    const float* __restrict__ wk, const float* __restrict__ wv,
    const float* __restrict__ wp, const float* __restrict__ bq,
    const float* __restrict__ bk, const float* __restrict__ bv,
    ushort* __restrict__ xb, ushort* __restrict__ Wqkv,
    ushort* __restrict__ Wproj, float* __restrict__ bqkv)
{
    const long i = (long)blockIdx.x * 256 + threadIdx.x;
    if (i < 1048576) {
        cvt4(x, xb, i, i);
    } else if (i < 1310720) {
        const long g = i - 1048576;
        cvt4(wq, Wqkv, g, g);
    } else if (i < 1376256) {
        const long g = i - 1310720;
        cvt4(wk, Wqkv, g, 262144 + g);
    } else if (i < 1441792) {
        const long g = i - 1376256;
        cvt4(wv, Wqkv, g, 327680 + g);
    } else if (i < 1703936) {
        const long g = i - 1441792;
        cvt4(wp, Wproj, g, g);
    } else if (i < 1704320) {
        const long j = i - 1703936;
        float4 v;
        if (j < 256)      v = ((const float4*)bq)[j];
        else if (j < 320) v = ((const float4*)bk)[j - 256];
        else              v = ((const float4*)bv)[j - 320];
        ((float4*)bqkv)[j] = v;
    }
}

// ---------------------------------------------------------------------------
// QKV GEMM + fused epilogues. 128x64 tile, 4 waves, 2-phase dbuf pipeline.
// n0 <  1024 : Q head (n0>>6)      -> Qb row-major, scale 0.125 (RMSNorm+RoPE)
// n0 in [1024,1280): K kv-head     -> Kf fragment order (RMSNorm+RoPE)
// n0 >= 1280 : V kv-head           -> Vf fragment order (LDS transpose)
// ---------------------------------------------------------------------------
__global__ __launch_bounds__(256) void gemm_qkv_fused(
    const ushort* __restrict__ A, const ushort* __restrict__ W,
    const float* __restrict__ bias,
    const float* __restrict__ qn_w, const float* __restrict__ kn_w,
    const float* __restrict__ sinp, const float* __restrict__ cosp,
    ushort* __restrict__ Qb, ushort* __restrict__ Kf,
    ushort* __restrict__ Vf)
{
    __shared__ ushort SMEM[12288];         // 2 x (As[128*32] + Bs[64*32]) = 24KB
    ushort* As0 = SMEM;
    ushort* Bs0 = SMEM + 4096;
    ushort* As1 = SMEM + 6144;
    ushort* Bs1 = SMEM + 10240;

    const int tid = threadIdx.x;
    const int m0 = blockIdx.y * 128, n0 = blockIdx.x * 64;
    const int w = tid >> 6, lane = tid & 63;
    const int quad = lane >> 4, l16 = lane & 15;
    const int wm = w * 32;
    const int K = EMB;

    f32x4 acc[2][4] = {};

    float bb[4];
#pragma unroll
    for (int j = 0; j < 4; ++j) bb[j] = bias[n0 + j * 16 + l16];

    const int r0 = tid >> 2;       // 0..63
    const int c8 = (tid & 3) * 8;
    const ushort* Ap = A + (size_t)(m0 + r0) * K + c8;
    const ushort* Wp = W + (size_t)(n0 + r0) * K + c8;
    ushort* As0W = As0 + w * 512;
    ushort* Bs0W = Bs0 + w * 512;
    ushort* As1W = As1 + w * 512;
    ushort* Bs1W = Bs1 + w * 512;

    stage3(Ap, Wp, K, As0W, Bs0W, 0);
    for (int k0 = 0; k0 < K; k0 += 64) {
        __syncthreads();                   // buf0 valid; buf1 free
        stage3(Ap, Wp, K, As1W, Bs1W, k0 + 32);
        mfma_phase(As0, Bs0, wm, l16, quad, acc);
        __syncthreads();                   // buf1 valid; buf0 free
        if (k0 + 64 < K) stage3(Ap, Wp, K, As0W, Bs0W, k0 + 64);
        mfma_phase(As1, Bs1, wm, l16, quad, acc);
    }

    if (n0 < 1280) {
        // ---- fused RMSNorm + RoPE epilogue (Q or K head tile) ----
        const bool isQ = (n0 < 1024);
        const float* nw = isQ ? qn_w : kn_w;
        const float oscale = isQ ? 0.125f : 1.0f;
        float nwv[4];
#pragma unroll
        for (int j = 0; j < 4; ++j) nwv[j] = nw[j * 16 + l16];

#pragma unroll
        for (int i = 0; i < 2; ++i) {
#pragma unroll
            for (int r = 0; r < 4; ++r) {
                const int m = m0 + wm + i * 16 + quad * 4 + r;
                const int n = m & (N_SEQ - 1);
                const int bI = m >> 11;

                float v4[4];
                float ssum = 0.0f;
#pragma unroll
                for (int j = 0; j < 4; ++j) {
                    v4[j] = acc[i][j][r] + bb[j];
                    ssum += v4[j] * v4[j];
                }
                // quad-level reduce (16 lanes share this row)
                ssum += __shfl_xor(ssum, 1, 64);
                ssum += __shfl_xor(ssum, 2, 64);
                ssum += __shfl_xor(ssum, 4, 64);
                ssum += __shfl_xor(ssum, 8, 64);
                const float rinv = rsqrtf(ssum * (1.0f / 64.0f) + 1e-6f);

                float tn[4], val[4];
#pragma unroll
                for (int j = 0; j < 4; ++j) tn[j] = v4[j] * rinv * nwv[j];
#pragma unroll
                for (int j = 0; j < 4; ++j) {
                    const int d = j * 16 + l16;
                    const float rot = (j < 2) ? -tn[j + 2] : tn[j - 2];
                    val[j] = (tn[j] * cosp[n * HD + d] + rot * sinp[n * HD + d]) * oscale;
                }

                if (isQ) {
                    const size_t qrow =
                        ((size_t)((bI << 4) + (n0 >> 6)) * N_SEQ + n) * HD;
#pragma unroll
                    for (int j = 0; j < 4; ++j)
                        Qb[qrow + j * 16 + l16] = f2bf(val[j]);
                } else {
                    const int kvh = (n0 >> 6) - 16;
                    const int kt = n >> 6, rr = n & 63;
                    const int ss2 = rr >> 5, l32k = rr & 31;
                    const size_t kb =
                        ((size_t)(bI * NKV + kvh) * 32 + kt) * 4096 + l32k * 16 + l16;
#pragma unroll
                    for (int j = 0; j < 4; ++j)
                        Kf[kb + (ss2 * 4 + j) * 512] = f2bf(val[j]);
                }
            }
        }
    } else {
        // ---- V tile: in-block LDS transpose -> fragment-order Vf ----
        const int kvv = (n0 - 1280) >> 6;
        const int bI = m0 >> 11;          // m-tile never straddles a batch
        const int kt0 = (m0 & (N_SEQ - 1)) >> 6;
        ushort* L = SMEM;                  // [64][68] = 4352 shorts <= 12288

        const int c = tid >> 5;            // (s*2+t)*2+d2
        const int l32v = tid & 31;
        const int row0 = (c >> 2) * 32 + ((c >> 1) & 1) * 16;  // s*32+t*16
        const int dcol = (c & 1) * 32 + l32v;                  // d2*32+l32v

#pragma unroll
        for (int h = 0; h < 2; ++h) {
            __syncthreads();               // K-loop / prev-half reads done
            if ((w >> 1) == h) {
                const int kl0 = wm - h * 64;   // 0 or 32 within the half
#pragma unroll
                for (int i = 0; i < 2; ++i)
#pragma unroll
                    for (int r = 0; r < 4; ++r) {
                        const int kl = kl0 + i * 16 + quad * 4 + r;
#pragma unroll
                        for (int j = 0; j < 4; ++j)
                            L[kl * 68 + j * 16 + l16] = f2bf(acc[i][j][r] + bb[j]);
                    }
            }
            __syncthreads();
            short8 o0, o1;
#pragma unroll
            for (int e = 0; e < 8; ++e) o0[e] = (short)L[(row0 + e) * 68 + dcol];
#pragma unroll
            for (int e = 0; e < 8; ++e) o1[e] = (short)L[(row0 + 8 + e) * 68 + dcol];
            const size_t vb = ((size_t)(bI * NKV + kvv) * 32 + kt0 + h) * 4096
                              + c * 512 + l32v * 16;
            *(short8*)&Vf[vb] = o0;
            *(short8*)&Vf[vb + 8] = o1;
        }
    }
}

// ---------------------------------------------------------------------------
// bf16 MFMA GEMM, 128x64 tile (proj), 2-phase dbuf pipeline.
// C[m][n] = sum_k A[m][k] W[n][k] + b[n]
// ---------------------------------------------------------------------------
template <bool BF16OUT>
__global__ __launch_bounds__(256) void gemm_mfma_kernel(
    const ushort* __restrict__ A, const ushort* __restrict__ W,
    const float* __restrict__ bias, void* __restrict__ Cout,
    int K, int ldc)
{
    __shared__ ushort SMEM[12288];
    ushort* As0 = SMEM;
    ushort* Bs0 = SMEM + 4096;
    ushort* As1 = SMEM + 6144;
    ushort* Bs1 = SMEM + 10240;

    const int tid = threadIdx.x;
    const int m0 = blockIdx.y * 128, n0 = blockIdx.x * 64;
    const int w = tid >> 6, lane = tid & 63;
    const int quad = lane >> 4, l16 = lane & 15;
    const int wm = w * 32;

    f32x4 acc[2][4] = {};

    float bb[4];
#pragma unroll
    for (int j = 0; j < 4; ++j) bb[j] = bias[n0 + j * 16 + l16];

    const int r0 = tid >> 2;       // 0..63
    const int c8 = (tid & 3) * 8;
    const ushort* Ap = A + (size_t)(m0 + r0) * K + c8;
    const ushort* Wp = W + (size_t)(n0 + r0) * K + c8;
    ushort* As0W = As0 + w * 512;
    ushort* Bs0W = Bs0 + w * 512;
    ushort* As1W = As1 + w * 512;
    ushort* Bs1W = Bs1 + w * 512;

    stage3(Ap, Wp, K, As0W, Bs0W, 0);
    for (int k0 = 0; k0 < K; k0 += 64) {
        __syncthreads();                   // buf0 valid; buf1 free
        stage3(Ap, Wp, K, As1W, Bs1W, k0 + 32);
        mfma_phase(As0, Bs0, wm, l16, quad, acc);
        __syncthreads();                   // buf1 valid; buf0 free
        if (k0 + 64 < K) stage3(Ap, Wp, K, As0W, Bs0W, k0 + 64);
        mfma_phase(As1, Bs1, wm, l16, quad, acc);
    }

#pragma unroll
    for (int i = 0; i < 2; ++i) {
        const int rowb = m0 + wm + i * 16 + quad * 4;
#pragma unroll
        for (int j = 0; j < 4; ++j) {
            const int col = n0 + j * 16 + l16;
#pragma unroll
            for (int r = 0; r < 4; ++r) {
                const float vv = acc[i][j][r] + bb[j];
                if (BF16OUT)
                    ((ushort*)Cout)[(size_t)(rowb + r) * ldc + col] = f2bf(vv);
                else
                    ((float*)Cout)[(size_t)(rowb + r) * ldc + col] = vv;
            }
        }
    }
}

// ---------------------------------------------------------------------------
// Barrier-free S^T-layout MFMA flash attention with in-block k-split.
// Round-0 kernel verbatim (FROZEN).
// ---------------------------------------------------------------------------
__global__ __launch_bounds__(256, 4) void flash_mfma32_kernel(
    const ushort* __restrict__ Qb, const ushort* __restrict__ Kf,
    const ushort* __restrict__ Vf, ushort* __restrict__ Ob)
{
    __shared__ float fsm[4352];            // 2 x (2048 O + 64 m + 64 l) = 17.4KB

    const int qt = blockIdx.x;             // 0..31 (64 q-rows)
    const int bh = blockIdx.y;
    const int b = bh >> 4, h = bh & 15;
    const int kvh = h >> 2;
    const int tid = threadIdx.x;
    const int w = tid >> 6, lane = tid & 63;
    const int l32 = lane & 31, l5 = lane >> 5;
    const int qg = w & 1;                  // q-group within block
    const int kh = w >> 1;                 // k-half

    const ushort* Qg = Qb + ((size_t)bh * N_SEQ + qt * 64 + qg * 32) * HD;
    const size_t kvbase = (size_t)(b * NKV + kvh) * (32 * 4096);
    const ushort* Kp = Kf + kvbase;
    const ushort* Vp = Vf + kvbase;
    const int loff = l32 * 16 + l5 * 8;

    // Q^T B-frags: qF[c][j] = Q[q0+l32][c*16 + l5*8 + j]
    short8 qF[4];
#pragma unroll
    for (int c = 0; c < 4; ++c)
        qF[c] = *(const short8*)&Qg[(size_t)l32 * HD + c * 16 + l5 * 8];

    f32x16 Oa[2] = {};                     // O^T d-tiles (d 0-31, 32-63)
    float mrow = -3.0e38f, lrow = 0.0f;

    for (int i = 0; i < 16; ++i) {
        const int kt = kh * 16 + i;
        const ushort* Kt = Kp + kt * 4096;
        const ushort* Vt = Vp + kt * 4096;

        // direct global->reg fragment loads (coalesced, L2-hit)
        short8 kT[2][4];
#pragma unroll
        for (int s = 0; s < 2; ++s)
#pragma unroll
            for (int c = 0; c < 4; ++c)
                kT[s][c] = *(const short8*)&Kt[(s * 4 + c) * 512 + loff];
        short8 vT[2][2][2];
#pragma unroll
        for (int s = 0; s < 2; ++s)
#pragma unroll
            for (int t = 0; t < 2; ++t)
#pragma unroll
                for (int d2 = 0; d2 < 2; ++d2)
                    vT[s][t][d2] = *(const short8*)&Vt[((s * 2 + t) * 2 + d2) * 512 + loff];

        // S^T (32 keys x 32 q-rows) per key-subtile s
        f32x16 Sv[2] = {};
#pragma unroll
        for (int s = 0; s < 2; ++s)
#pragma unroll
            for (int c = 0; c < 4; ++c)
                Sv[s] = __builtin_amdgcn_mfma_f32_32x32x16_bf16(kT[s][c], qF[c], Sv[s], 0, 0, 0);

        // online softmax (keys in-lane + 1 partner shuffle)
        float mx = -3.0e38f;
#pragma unroll
        for (int s = 0; s < 2; ++s)
#pragma unroll
            for (int r = 0; r < 16; ++r) mx = fmaxf(mx, Sv[s][r]);
        mx = fmaxf(mx, __shfl_xor(mx, 32, 64));
        const float mnew = fmaxf(mrow, mx);
        const float alpha = __expf(mrow - mnew);
        mrow = mnew;
        float rs = 0.0f;
#pragma unroll
        for (int s = 0; s < 2; ++s)
#pragma unroll
            for (int r = 0; r < 16; ++r) {
                Sv[s][r] = __expf(Sv[s][r] - mnew);
                rs += Sv[s][r];
            }
        rs += __shfl_xor(rs, 32, 64);
        lrow = lrow * alpha + rs;
#pragma unroll
        for (int t = 0; t < 2; ++t)
#pragma unroll
            for (int r = 0; r < 16; ++r) Oa[t][r] *= alpha;

        // pack P pairs: P2[s][2g+hh] = keys 8g+4*l5+2hh+{0,1} of subtile s
        uint P2[2][8];
#pragma unroll
        for (int s = 0; s < 2; ++s)
#pragma unroll
            for (int g = 0; g < 4; ++g)
#pragma unroll
                for (int hh = 0; hh < 2; ++hh)
                    P2[s][g * 2 + hh] =
                        pack2bf(Sv[s][4 * g + 2 * hh], Sv[s][4 * g + 2 * hh + 1]);

        // P^T B-frags in-register + PV mfma
#pragma unroll
        for (int s = 0; s < 2; ++s)
#pragma unroll
            for (int t = 0; t < 2; ++t) {
                const uint snd0 = l5 ? P2[s][4 * t + 0] : P2[s][4 * t + 2];
                const uint snd1 = l5 ? P2[s][4 * t + 1] : P2[s][4 * t + 3];
                const uint kp0  = l5 ? P2[s][4 * t + 2] : P2[s][4 * t + 0];
                const uint kp1  = l5 ? P2[s][4 * t + 3] : P2[s][4 * t + 1];
                const uint rcv0 = __shfl_xor(snd0, 32, 64);
                const uint rcv1 = __shfl_xor(snd1, 32, 64);
                union { uint u[4]; short8 s8; } pb;
                pb.u[0] = l5 ? rcv0 : kp0;
                pb.u[1] = l5 ? rcv1 : kp1;
                pb.u[2] = l5 ? kp0 : rcv0;
                pb.u[3] = l5 ? kp1 : rcv1;
#pragma unroll
                for (int d2 = 0; d2 < 2; ++d2)
                    Oa[d2] = __builtin_amdgcn_mfma_f32_32x32x16_bf16(
                        vT[s][t][d2], pb.s8, Oa[d2], 0, 0, 0);
            }
    }

    // ---- merge the two k-halves (wave pairs w, w+2 share q-rows) ----
    float* buf = fsm + qg * 2176;
    if (kh == 1) {
#pragma unroll
        for (int d2 = 0; d2 < 2; ++d2)
#pragma unroll
            for (int r = 0; r < 16; ++r)
                buf[(d2 * 16 + r) * 64 + lane] = Oa[d2][r];
        buf[2048 + lane] = mrow;
        buf[2112 + lane] = lrow;
    }
    __syncthreads();

    if (kh == 0) {
        const float mb = buf[2048 + lane];
        const float lb = buf[2112 + lane];
        const float M = fmaxf(mrow, mb);
        const float ea = __expf(mrow - M), eb = __expf(mb - M);
        lrow = lrow * ea + lb * eb;
#pragma unroll
        for (int d2 = 0; d2 < 2; ++d2)
#pragma unroll
            for (int r = 0; r < 16; ++r)
                Oa[d2][r] = Oa[d2][r] * ea + buf[(d2 * 16 + r) * 64 + lane] * eb;
    }
    __syncthreads();                        // merge reads done before Os reuse

    // ---- epilogue: normalize + transpose to row-major via LDS ----
    ushort* Os = (ushort*)fsm;              // [64][68]
    if (kh == 0) {
        const float inv = 1.0f / lrow;
#pragma unroll
        for (int d2 = 0; d2 < 2; ++d2)
#pragma unroll
            for (int r = 0; r < 16; ++r) {
                const int d = d2 * 32 + (r & 3) + 8 * (r >> 2) + 4 * l5;
                Os[(qg * 32 + l32) * 68 + d] = f2bf(Oa[d2][r] * inv);
            }
    }
    __syncthreads();

    const int row = tid >> 2, cc = (tid & 3) * 16;
#pragma unroll
    for (int i = 0; i < 2; ++i) {
        const short8 v = *(const short8*)&Os[row * 68 + cc + i * 8];
        *(short8*)&Ob[((size_t)b * N_SEQ + qt * 64 + row) * EMB + h * HD + cc + i * 8] = v;
    }
}

// ---------------------------------------------------------------------------
extern "C" void kernel_launch(void* const* d_in, const int* in_sizes, int n_in,
                              void* d_out, int out_size, void* d_ws, size_t ws_size,
                              hipStream_t stream)
{
    const float* x      = (const float*)d_in[0];
    const float* sinp   = (const float*)d_in[1];
    const float* cosp   = (const float*)d_in[2];
    const float* wq_w   = (const float*)d_in[3];
    const float* wq_b   = (const float*)d_in[4];
    const float* wk_w   = (const float*)d_in[5];
    const float* wk_b   = (const float*)d_in[6];
    const float* wv_w   = (const float*)d_in[7];
    const float* wv_b   = (const float*)d_in[8];
    const float* qn_w   = (const float*)d_in[9];
    const float* kn_w   = (const float*)d_in[10];
    const float* proj_w = (const float*)d_in[11];
    const float* proj_b = (const float*)d_in[12];
    float* out = (float*)d_out;

    // workspace layout (ushort elements) — Tq slot retained but unused
    ushort* Tq    = (ushort*)d_ws;            // (unused after r12 fusion)
    ushort* xb    = Tq + 6291456;             // 4096*1024 (reused as Ob)
    ushort* Wqkv  = xb + 4194304;             // 1536*1024
    ushort* Wproj = Wqkv + 1572864;           // 1024*1024
    float*  bqkv  = (float*)(Wproj + 1048576);// 1536
    ushort* Qb    = (ushort*)(bqkv + 1536);   // 2*16*2048*64
    ushort* Kf    = Qb + 4194304;             // frag-order K, 1048576
    ushort* Vf    = Kf + 1048576;             // frag-order V^T, 1048576

    prep_kernel<<<6658, 256, 0, stream>>>(x, wq_w, wk_w, wv_w, proj_w,
                                          wq_b, wk_b, wv_b,
                                          xb, Wqkv, Wproj, bqkv);

    gemm_qkv_fused<<<dim3(QKV_N / 64, M_TOT / 128), 256, 0, stream>>>(
        xb, Wqkv, bqkv, qn_w, kn_w, sinp, cosp, Qb, Kf, Vf);

    flash_mfma32_kernel<<<dim3(32, 32), 256, 0, stream>>>(Qb, Kf, Vf, xb);

    gemm_mfma_kernel<false><<<dim3(EMB / 64, M_TOT / 128), 256, 0, stream>>>(
        xb, Wproj, proj_b, out, EMB, EMB);
}